// Round 8
// baseline (722.816 us; speedup 1.0000x reference)
//
#include <hip/hip_runtime.h>

#define N_NODES 20000
#define N_EDGES 320000
#define N_GRAPH 256

// ------------------------- templated tiled fp32 GEMM -------------------------
// zstride==0: direct C = op(A@B + bias). zstride>0 (split-K): block z plain-stores
// its partial to C + z*zstride (summed later by bias_sum_kernel).
// A-tile k-major in LDS; B-fragment split in two stride-4 groups (2-way = free).
// Single LDS buffer + register prefetch of tile k+1 (measured best: R5/R7 ~81us;
// LDS double-buffer variant measured SLOWER: VGPR 188, occ 10%, 135us).
// BK=32: halves barrier count vs BK=16 at +16 prefetch VGPR.
template<int BM, int BN, int TM, int TN>
__launch_bounds__(256)
__global__ void gemm_t(const float* __restrict__ A, int lda,
                       const float* __restrict__ B, int ldb,
                       float* __restrict__ C, int ldc, int zstride,
                       const float* __restrict__ bias,
                       int Nr, int K, int M, int do_relu, int kchunk) {
  constexpr int BK = 32;
  constexpr int LDA = BM + 4;
  constexpr int KQ4 = BK / 4;  // float4 slots per A row
  __shared__ __align__(16) float As[BK][LDA];
  __shared__ __align__(16) float Bs[BK][BN];
  const int tid = threadIdx.x;
  const int row0 = blockIdx.y * BM, col0 = blockIdx.x * BN;
  constexpr int NX = BN / TN;
  const int tx = tid % NX, ty = tid / NX;
  float acc[TM][TN] = {};
  const int klo = blockIdx.z * kchunk;
  const int khi = min(klo + kchunk, K);

  constexpr int AIT = BM * KQ4 / 256;
  constexpr int BIT = BK * (BN / 4) / 256;
  float4 pa[AIT], pb[BIT];

  auto load_tile = [&](int k0) {
#pragma unroll
    for (int it = 0; it < AIT; ++it) {
      const int s = it * 256 + tid;
      const int row = s / KQ4, kq = (s % KQ4) << 2;
      float4 av = make_float4(0.f, 0.f, 0.f, 0.f);
      const int gr = row0 + row, gk = k0 + kq;
      if (gr < Nr) {
        const float* Ap = A + (size_t)gr * lda + gk;
        if (gk + 3 < khi) { av.x = Ap[0]; av.y = Ap[1]; av.z = Ap[2]; av.w = Ap[3]; }
        else {
          if (gk     < khi) av.x = Ap[0];
          if (gk + 1 < khi) av.y = Ap[1];
          if (gk + 2 < khi) av.z = Ap[2];
        }
      }
      pa[it] = av;
    }
#pragma unroll
    for (int it = 0; it < BIT; ++it) {
      const int s = it * 256 + tid;
      const int kr = s / (BN / 4), c = (s % (BN / 4)) << 2;
      float4 bv = make_float4(0.f, 0.f, 0.f, 0.f);
      const int gk = k0 + kr, gc = col0 + c;
      if (gk < khi) {
        const float* Bp = B + (size_t)gk * ldb + gc;
        if (gc + 3 < M) { bv.x = Bp[0]; bv.y = Bp[1]; bv.z = Bp[2]; bv.w = Bp[3]; }
        else {
          if (gc     < M) bv.x = Bp[0];
          if (gc + 1 < M) bv.y = Bp[1];
          if (gc + 2 < M) bv.z = Bp[2];
        }
      }
      pb[it] = bv;
    }
  };

  load_tile(klo);
  for (int k0 = klo; k0 < khi; k0 += BK) {
#pragma unroll
    for (int it = 0; it < AIT; ++it) {
      const int s = it * 256 + tid;
      const int row = s / KQ4, kq = (s % KQ4) << 2;
      As[kq    ][row] = pa[it].x;
      As[kq + 1][row] = pa[it].y;
      As[kq + 2][row] = pa[it].z;
      As[kq + 3][row] = pa[it].w;
    }
#pragma unroll
    for (int it = 0; it < BIT; ++it) {
      const int s = it * 256 + tid;
      const int kr = s / (BN / 4), c = (s % (BN / 4)) << 2;
      *(float4*)&Bs[kr][c] = pb[it];
    }
    __syncthreads();
    if (k0 + BK < khi) load_tile(k0 + BK);  // overlap next-tile fetch with compute
#pragma unroll
    for (int kk = 0; kk < BK; ++kk) {
      float ar[TM], br[TN];
#pragma unroll
      for (int i = 0; i < TM; i += 4)
        *(float4*)&ar[i] = *(const float4*)&As[kk][ty * TM + i];
      if constexpr (TN == 8) {
        *(float4*)&br[0] = *(const float4*)&Bs[kk][tx * 4];
        *(float4*)&br[4] = *(const float4*)&Bs[kk][BN / 2 + tx * 4];
      } else {
        *(float4*)&br[0] = *(const float4*)&Bs[kk][tx * TN];
      }
#pragma unroll
      for (int i = 0; i < TM; ++i)
#pragma unroll
        for (int j = 0; j < TN; ++j)
          acc[i][j] += ar[i] * br[j];
    }
    __syncthreads();
  }

  float* Cz = C + (size_t)blockIdx.z * zstride;
#pragma unroll
  for (int i = 0; i < TM; ++i) {
    const int r = row0 + ty * TM + i;
    if (r >= Nr) continue;
    float* Crow = Cz + (size_t)r * ldc;
#pragma unroll
    for (int g = 0; g < TN / 4; ++g) {
      const int c = col0 + (TN == 8 ? g * (BN / 2) : 0) + tx * 4;
      if (c + 3 < M) {
        float4 v;
        v.x = acc[i][g * 4 + 0]; v.y = acc[i][g * 4 + 1];
        v.z = acc[i][g * 4 + 2]; v.w = acc[i][g * 4 + 3];
        if (bias) { v.x += bias[c]; v.y += bias[c + 1]; v.z += bias[c + 2]; v.w += bias[c + 3]; }
        if (do_relu) {
          v.x = fmaxf(v.x, 0.f); v.y = fmaxf(v.y, 0.f);
          v.z = fmaxf(v.z, 0.f); v.w = fmaxf(v.w, 0.f);
        }
        *(float4*)&Crow[c] = v;
      } else {
#pragma unroll
        for (int j = 0; j < 4; ++j) {
          if (c + j >= M) continue;
          float v = acc[i][g * 4 + j];
          if (bias) v += bias[c + j];
          if (do_relu) v = fmaxf(v, 0.f);
          Crow[c + j] = v;
        }
      }
    }
  }
}

// sum Sz split-K partials + bias (+relu), write with ldd
__global__ void bias_sum_kernel(const float* __restrict__ src, int zs, int Sz,
                                float* __restrict__ dst, int ldd,
                                const float* __restrict__ bias,
                                int Nr, int M, int do_relu) {
  int idx = blockIdx.x * blockDim.x + threadIdx.x;
  if (idx >= Nr * M) return;
  int r = idx / M, c = idx - r * M;
  float v = bias[c];
  for (int z = 0; z < Sz; ++z) v += src[idx + (size_t)z * zs];
  if (do_relu) v = fmaxf(v, 0.f);
  dst[(size_t)r * ldd + c] = v;
}

// src(512x128): rows 0..255 branch0, 256..511 branch1 -> dst[256][512] cols 0..255
__global__ void cat_kernel(const float* __restrict__ src, float* __restrict__ dst) {
  int idx = blockIdx.x * blockDim.x + threadIdx.x;
  if (idx >= 512 * 128) return;
  int r = idx >> 7, c = idx & 127;
  dst[(size_t)(r & 255) * 512 + ((r >> 8) << 7) + c] = src[idx];
}

// ------------------------- graph prep -------------------------
__global__ void hist2_kernel(const int* __restrict__ e1, const int* __restrict__ e2,
                             int* __restrict__ cnt, int E, int npass) {
  int e = blockIdx.x * blockDim.x + threadIdx.x;
  if (e < E) atomicAdd(&cnt[e1[E + e]], 1);
  else if (e < npass * E) atomicAdd(&cnt[N_NODES + e2[E + e - E]], 1);
}

// ---- 3-phase parallel exclusive scan over cnt ----
__launch_bounds__(1024)
__global__ void scan1_kernel(const int* __restrict__ cnt, int* __restrict__ row_ptr,
                             int* __restrict__ part, int n) {
  __shared__ int sh[1024];
  const int tid = threadIdx.x;
  const int i = blockIdx.x * 1024 + tid;
  const int v = (i < n) ? cnt[i] : 0;
  sh[tid] = v;
  __syncthreads();
#pragma unroll
  for (int off = 1; off < 1024; off <<= 1) {
    int t = (tid >= off) ? sh[tid - off] : 0;
    __syncthreads();
    sh[tid] += t;
    __syncthreads();
  }
  if (i < n) row_ptr[i] = sh[tid] - v;  // exclusive
  if (tid == 1023) part[blockIdx.x] = sh[tid];
}

__global__ void scan2_kernel(int* __restrict__ part, int nb) {
  if (threadIdx.x == 0 && blockIdx.x == 0) {
    int run = 0;
    for (int b = 0; b < nb; ++b) { int t = part[b]; part[b] = run; run += t; }
  }
}

__global__ void scan3_kernel(const int* __restrict__ cnt, int* __restrict__ row_ptr,
                             const int* __restrict__ part, int* __restrict__ cursor,
                             float* __restrict__ dinv, int n, int total) {
  int i = blockIdx.x * blockDim.x + threadIdx.x;
  if (i >= n) return;
  int rp = row_ptr[i] + part[i >> 10];
  row_ptr[i] = rp;
  cursor[i] = rp;
  dinv[i] = rsqrtf((float)(cnt[i] + 1));
  if (i == 0) row_ptr[n] = total;
}

__global__ void scatter2_kernel(const int* __restrict__ e1, const int* __restrict__ e2,
                                int* __restrict__ cursor, int* __restrict__ col_idx,
                                int E, int npass) {
  int e = blockIdx.x * blockDim.x + threadIdx.x;
  if (e < E) {
    int p = atomicAdd(&cursor[e1[E + e]], 1);
    col_idx[p] = e1[e];
  } else if (e < npass * E) {
    int j = e - E;
    int p = atomicAdd(&cursor[N_NODES + e2[E + j]], 1);
    col_idx[p] = N_NODES + e2[j];
  }
}

// ------------ normalized aggregation, flat (node, vec-slot) threads ------------
// out = D^-1/2 (A+I) D^-1/2 x ; separate in/out leading dims (64B-padded rows).
__global__ void aggf2_flat(const float* __restrict__ h, const float* __restrict__ h2,
                           int nsplit, const int* __restrict__ row_ptr,
                           const int* __restrict__ col_idx, const float* __restrict__ dinv,
                           float* __restrict__ out, int in_ld, int out_ld,
                           int V, int total) {
  int gid = blockIdx.x * blockDim.x + threadIdx.x;
  if (gid >= total) return;
  int n = gid / V, v = gid - n * V;
  const float din = dinv[n];
  auto rowp = [&](int s) -> const float2* {
    const float* base = (s < nsplit) ? h + (size_t)s * in_ld
                                     : h2 + (size_t)(s - nsplit) * in_ld;
    return (const float2*)base;
  };
  float2 a;
  { float2 x = rowp(n)[v]; a.x = din * x.x; a.y = din * x.y; }
  const int beg = row_ptr[n], end = row_ptr[n + 1];
  int e = beg;
  for (; e + 1 < end; e += 2) {
    int s0 = col_idx[e], s1 = col_idx[e + 1];
    float d0 = dinv[s0], d1 = dinv[s1];
    float2 x0 = rowp(s0)[v], x1 = rowp(s1)[v];
    a.x += d0 * x0.x + d1 * x1.x;
    a.y += d0 * x0.y + d1 * x1.y;
  }
  if (e < end) {
    int s0 = col_idx[e];
    float d0 = dinv[s0];
    float2 x0 = rowp(s0)[v];
    a.x += d0 * x0.x; a.y += d0 * x0.y;
  }
  float2 o; o.x = din * a.x; o.y = din * a.y;
  ((float2*)(out + (size_t)n * out_ld))[v] = o;
}

__global__ void aggf4_flat(const float* __restrict__ h, const int* __restrict__ row_ptr,
                           const int* __restrict__ col_idx, const float* __restrict__ dinv,
                           float* __restrict__ out, int in_ld, int out_ld,
                           int V, int total) {
  int gid = blockIdx.x * blockDim.x + threadIdx.x;
  if (gid >= total) return;
  int n = gid / V, v = gid - n * V;
  const float din = dinv[n];
  const int ivs = in_ld >> 2;
  const float4* hv = (const float4*)h;
  float4 a;
  {
    float4 x = hv[(size_t)n * ivs + v];
    a.x = din * x.x; a.y = din * x.y; a.z = din * x.z; a.w = din * x.w;
  }
  const int beg = row_ptr[n], end = row_ptr[n + 1];
  int e = beg;
  for (; e + 1 < end; e += 2) {
    int s0 = col_idx[e], s1 = col_idx[e + 1];
    float d0 = dinv[s0], d1 = dinv[s1];
    float4 x0 = hv[(size_t)s0 * ivs + v], x1 = hv[(size_t)s1 * ivs + v];
    a.x += d0 * x0.x + d1 * x1.x;
    a.y += d0 * x0.y + d1 * x1.y;
    a.z += d0 * x0.z + d1 * x1.z;
    a.w += d0 * x0.w + d1 * x1.w;
  }
  if (e < end) {
    int s0 = col_idx[e];
    float d0 = dinv[s0];
    float4 x0 = hv[(size_t)s0 * ivs + v];
    a.x += d0 * x0.x; a.y += d0 * x0.y; a.z += d0 * x0.z; a.w += d0 * x0.w;
  }
  float4 o;
  o.x = din * a.x; o.y = din * a.y; o.z = din * a.z; o.w = din * a.w;
  ((float4*)(out + (size_t)n * out_ld))[v] = o;
}

__global__ void starts2_kernel(const int* __restrict__ b1, const int* __restrict__ b2,
                               int* __restrict__ s1, int* __restrict__ s2, int n, int npass) {
  int i = blockIdx.x * blockDim.x + threadIdx.x;
  if (i < n) {
    if (i == 0) { s1[0] = 0; s1[N_GRAPH] = n; }
    else if (b1[i] != b1[i - 1]) s1[b1[i]] = i;
  } else if (i < npass * n) {
    int j = i - n;
    if (j == 0) { s2[0] = n; s2[N_GRAPH] = 2 * n; }
    else if (b2[j] != b2[j - 1]) s2[b2[j]] = n + j;
  }
}

__global__ void pool_kernel(const float* __restrict__ x, int xld,
                            const int* __restrict__ s1, const int* __restrict__ s2,
                            float* __restrict__ pooled, int F, int pool_base) {
  int g = blockIdx.x;
  const int* st = (g < N_GRAPH) ? s1 : s2;
  int gi = g & (N_GRAPH - 1);
  int beg = st[gi], end = st[gi + 1];
  for (int f = threadIdx.x; f < F; f += blockDim.x) {
    float m = 0.f;  // post-ReLU inputs >= 0
    for (int nn = beg; nn < end; ++nn) m = fmaxf(m, x[(size_t)nn * xld + f]);
    pooled[(size_t)(pool_base + g) * F + f] = m;
  }
}

__global__ void rownorm_kernel(const float* __restrict__ cell, float* __restrict__ cv, int F) {
  int g = blockIdx.x;
  __shared__ float red[256];
  int tid = threadIdx.x;
  const float* row = cell + (size_t)g * F;
  float s = 0.f;
  for (int f = tid; f < F; f += 256) { float v = row[f]; s += v * v; }
  red[tid] = s;
  __syncthreads();
  for (int off = 128; off > 0; off >>= 1) {
    if (tid < off) red[tid] += red[tid + off];
    __syncthreads();
  }
  float inv = 1.f / fmaxf(sqrtf(red[0]), 1e-12f);
  float* orow = cv + (size_t)g * F;
  for (int f = tid; f < F; f += 256) orow[f] = row[f] * inv;
}

// ------------------------- launcher -------------------------
extern "C" void kernel_launch(void* const* d_in, const int* in_sizes, int n_in,
                              void* d_out, int out_size, void* d_ws, size_t ws_size,
                              hipStream_t stream) {
  (void)in_sizes; (void)n_in; (void)out_size;
  const float* x1  = (const float*)d_in[0];
  const int*   ei1 = (const int*)d_in[1];
  const int*   bt1 = (const int*)d_in[2];
  const float* x2  = (const float*)d_in[3];
  const int*   ei2 = (const int*)d_in[4];
  const int*   bt2 = (const int*)d_in[5];
  const float* cell = (const float*)d_in[6];
  const float* Wc1 = (const float*)d_in[7];  const float* bc1 = (const float*)d_in[8];
  const float* Wc2 = (const float*)d_in[9];  const float* bc2 = (const float*)d_in[10];
  const float* Wc3 = (const float*)d_in[11]; const float* bc3 = (const float*)d_in[12];
  const float* Wg1 = (const float*)d_in[13]; const float* bg1 = (const float*)d_in[14];
  const float* Wg2 = (const float*)d_in[15]; const float* bg2 = (const float*)d_in[16];
  const float* Wr1 = (const float*)d_in[17]; const float* br1 = (const float*)d_in[18];
  const float* Wr2 = (const float*)d_in[19]; const float* br2 = (const float*)d_in[20];
  const float* Wr3 = (const float*)d_in[21]; const float* br3 = (const float*)d_in[22];
  const float* Wf1 = (const float*)d_in[23]; const float* bf1 = (const float*)d_in[24];
  const float* Wf2 = (const float*)d_in[25]; const float* bf2 = (const float*)d_in[26];
  const float* Wf3 = (const float*)d_in[27]; const float* bf3 = (const float*)d_in[28];
  const float* Wo  = (const float*)d_in[29]; const float* bo  = (const float*)d_in[30];
  float* out = (float*)d_out;

  const bool batched = ws_size >= (size_t)95 * 1024 * 1024;
  const int NPASS = batched ? 2 : 1;
  const int NN = NPASS * N_NODES;

  char* ws = (char*)d_ws;
  size_t off = 0;
  auto alloc_f = [&](size_t ne) { float* p = (float*)(ws + off); off += ne * 4; return p; };
  auto alloc_i = [&](size_t ne) { int* p = (int*)(ws + off); off += ne * 4; return p; };
  float* xbuf   = alloc_f((size_t)NN * 320);   // activations (64B-padded rows)
  float* abuf   = alloc_f((size_t)NN * 160);   // aggregated input (64B-padded rows)
  float* dinv   = alloc_f(NN);
  float* pooled = alloc_f((size_t)512 * 312);
  float* cvbuf  = alloc_f((size_t)N_GRAPH * 954);
  float* gtmp1  = alloc_f((size_t)512 * 2048);
  float* gtmp2  = alloc_f((size_t)512 * 512);
  float* gtmp3  = alloc_f((size_t)N_GRAPH * 256);
  float* catbuf = alloc_f((size_t)N_GRAPH * 512);
  int* cnt     = alloc_i(NN);
  int* row_ptr = alloc_i(NN + 1);
  int* cursor  = alloc_i(NN);
  int* col_idx = alloc_i(NPASS * N_EDGES);
  int* part    = alloc_i(64);
  int* start1  = alloc_i(N_GRAPH + 1);
  int* start2  = alloc_i(N_GRAPH + 1);
  float* accb  = xbuf;  // split-K partials (MLP runs after pooling; xbuf free then)

  auto gemm_big = [&](const float* A, int lda, const float* B, int ldb, float* C, int ldc,
                      const float* bias, int Nr, int K, int M, int relu) {
    dim3 grid((M + 127) / 128, (Nr + 127) / 128, 1);
    gemm_t<128, 128, 8, 8><<<grid, 256, 0, stream>>>(A, lda, B, ldb, C, ldc, 0, bias,
                                                     Nr, K, M, relu, K);
  };
  auto gemm_med = [&](const float* A, int lda, const float* B, int ldb, float* C, int ldc,
                      const float* bias, int Nr, int K, int M, int relu) {
    dim3 grid((M + 63) / 64, (Nr + 127) / 128, 1);
    gemm_t<128, 64, 8, 4><<<grid, 256, 0, stream>>>(A, lda, B, ldb, C, ldc, 0, bias,
                                                    Nr, K, M, relu, K);
  };
  auto gemm_small = [&](const float* A, int lda, const float* B, int ldb, float* C, int ldc,
                        const float* bias, int Nr, int K, int M, int relu) {
    dim3 grid((M + 63) / 64, (Nr + 63) / 64, 1);
    gemm_t<64, 64, 4, 4><<<grid, 256, 0, stream>>>(A, lda, B, ldb, C, ldc, 0, bias,
                                                   Nr, K, M, relu, K);
  };
  // split-K MLP layer (Nr = 256): partial stores per z-slice + summing bias/act pass
  auto splitk = [&](const float* A, int lda, const float* B, int M_, int K_, int S,
                    const float* bias, float* dst, int ldd, int relu) {
    int kchunk = (((K_ + S - 1) / S) + 31) / 32 * 32;
    int Sz = (K_ + kchunk - 1) / kchunk;
    dim3 grid((M_ + 63) / 64, (N_GRAPH + 63) / 64, Sz);
    gemm_t<64, 64, 4, 4><<<grid, 256, 0, stream>>>(A, lda, B, M_, accb, M_, N_GRAPH * M_,
                                                   nullptr, N_GRAPH, K_, M_, 0, kchunk);
    int tot = N_GRAPH * M_;
    bias_sum_kernel<<<(tot + 255) / 256, 256, 0, stream>>>(accb, N_GRAPH * M_, Sz, dst, ldd,
                                                           bias, N_GRAPH, M_, relu);
  };

  auto drug_pass = [&](const float* xa, const float* xb, const int* eia, const int* eib,
                       const int* bta, const int* btb, int npass, int pool_base) {
    const int nn = npass * N_NODES;
    const int te = npass * N_EDGES;
    const int nb = (nn + 1023) / 1024;
    hipMemsetAsync(cnt, 0, nn * sizeof(int), stream);
    hist2_kernel<<<(te + 255) / 256, 256, 0, stream>>>(eia, eib, cnt, N_EDGES, npass);
    scan1_kernel<<<nb, 1024, 0, stream>>>(cnt, row_ptr, part, nn);
    scan2_kernel<<<1, 64, 0, stream>>>(part, nb);
    scan3_kernel<<<(nn + 255) / 256, 256, 0, stream>>>(cnt, row_ptr, part, cursor, dinv, nn, te);
    scatter2_kernel<<<(te + 255) / 256, 256, 0, stream>>>(eia, eib, cursor, col_idx, N_EDGES, npass);
    // layer 1: agg(78, dual-source raw x, ld 78) -> abuf ld 80 -> GEMM 78->78 (out ld 80)
    {
      int tot = nn * 39;
      aggf2_flat<<<(tot + 255) / 256, 256, 0, stream>>>(xa, xb, N_NODES, row_ptr, col_idx,
                                                        dinv, abuf, 78, 80, 39, tot);
    }
    gemm_med(abuf, 80, Wc1, 78, xbuf, 80, bc1, nn, 78, 78, 1);
    // layer 2: agg(78, ld 80) -> abuf ld 80 -> GEMM 78->156 (out ld 160)
    {
      int tot = nn * 39;
      aggf2_flat<<<(tot + 255) / 256, 256, 0, stream>>>(xbuf, xbuf, nn, row_ptr, col_idx,
                                                        dinv, abuf, 80, 80, 39, tot);
    }
    gemm_med(abuf, 80, Wc2, 156, xbuf, 160, bc2, nn, 78, 156, 1);
    // layer 3: agg(156, ld 160) -> abuf ld 160 -> GEMM 156->312 (out ld 320)
    {
      int tot = nn * 39;
      aggf4_flat<<<(tot + 255) / 256, 256, 0, stream>>>(xbuf, row_ptr, col_idx,
                                                        dinv, abuf, 160, 160, 39, tot);
    }
    gemm_big(abuf, 160, Wc3, 312, xbuf, 320, bc3, nn, 156, 312, 1);
    // pool
    starts2_kernel<<<(nn + 255) / 256, 256, 0, stream>>>(bta, btb, start1, start2, N_NODES, npass);
    pool_kernel<<<npass * N_GRAPH, 128, 0, stream>>>(xbuf, 320, start1, start2, pooled, 312, pool_base);
  };

  if (batched) {
    drug_pass(x1, x2, ei1, ei2, bt1, bt2, 2, 0);
  } else {
    drug_pass(x1, x1, ei1, ei1, bt1, bt1, 1, 0);
    drug_pass(x2, x2, ei2, ei2, bt2, bt2, 1, N_GRAPH);
  }

  // drug head on both branches at once (512 rows; shared weights)
  gemm_med(pooled, 312, Wg1, 156, gtmp1, 156, bg1, 2 * N_GRAPH, 312, 156, 1);
  gemm_med(gtmp1, 156, Wg2, 128, gtmp2, 128, bg2, 2 * N_GRAPH, 156, 128, 0);
  cat_kernel<<<(512 * 128 + 255) / 256, 256, 0, stream>>>(gtmp2, catbuf);

  // cell branch + head MLP (256-row deep-K layers via split-K)
  rownorm_kernel<<<N_GRAPH, 256, 0, stream>>>(cell, cvbuf, 954);
  splitk(cvbuf, 954, Wr1, 2048, 954, 8,   br1, gtmp1, 2048, 1);
  splitk(gtmp1, 2048, Wr2, 512, 2048, 32, br2, gtmp2, 512, 1);
  splitk(gtmp2, 512, Wr3, 256, 512, 16,   br3, catbuf + 256, 512, 1);
  splitk(catbuf, 512, Wf1, 1024, 512, 16, bf1, gtmp1, 1024, 1);
  splitk(gtmp1, 1024, Wf2, 512, 1024, 32, bf2, gtmp2, 512, 1);
  splitk(gtmp2, 512, Wf3, 128, 512, 32,   bf3, gtmp3, 128, 1);
  gemm_small(gtmp3, 128, Wo, 2, out, 2, bo, N_GRAPH, 128, 2, 0);
}

// Round 9
// 690.893 us; speedup vs baseline: 1.0462x; 1.0462x over previous
//
#include <hip/hip_runtime.h>

#define N_NODES 20000
#define N_EDGES 320000
#define N_GRAPH 256

// ------------------------- templated tiled fp32 GEMM -------------------------
// zstride==0: direct C = op(A@B + bias). zstride>0 (split-K): block z plain-stores
// its partial to C + z*zstride (summed later by bias_sum_kernel).
// A-tile k-major in LDS; B-fragment split in two stride-4 groups (2-way = free).
// STRUCTURE IS MEASUREMENT-PINNED (do not change without re-measuring):
//   BK=16, single LDS buffer, register prefetch of tile k+1 -> VGPR 100, ~81us Wc3.
//   LDS double-buffer: VGPR 188, occ 10%, 135us (R6). BK=32: VGPR 148, 111us (R8).
//   This kernel sits on an occupancy cliff: +30 VGPR or +16KB LDS loses more than
//   any barrier-count saving gains.
template<int BM, int BN, int TM, int TN>
__launch_bounds__(256)
__global__ void gemm_t(const float* __restrict__ A, int lda,
                       const float* __restrict__ B, int ldb,
                       float* __restrict__ C, int ldc, int zstride,
                       const float* __restrict__ bias,
                       int Nr, int K, int M, int do_relu, int kchunk) {
  constexpr int BK = 16;
  constexpr int LDA = BM + 4;
  __shared__ __align__(16) float As[BK][LDA];
  __shared__ __align__(16) float Bs[BK][BN];
  const int tid = threadIdx.x;
  const int row0 = blockIdx.y * BM, col0 = blockIdx.x * BN;
  constexpr int NX = BN / TN;
  const int tx = tid % NX, ty = tid / NX;
  float acc[TM][TN] = {};
  const int klo = blockIdx.z * kchunk;
  const int khi = min(klo + kchunk, K);

  constexpr int AIT = BM * BK / 4 / 256;
  constexpr int BIT = BK * BN / 4 / 256;
  float4 pa[AIT], pb[BIT];

  auto load_tile = [&](int k0) {
#pragma unroll
    for (int it = 0; it < AIT; ++it) {
      const int s = it * 256 + tid;
      const int row = s >> 2, kq = (s & 3) << 2;
      float4 av = make_float4(0.f, 0.f, 0.f, 0.f);
      const int gr = row0 + row, gk = k0 + kq;
      if (gr < Nr) {
        const float* Ap = A + (size_t)gr * lda + gk;
        if (gk + 3 < khi) { av.x = Ap[0]; av.y = Ap[1]; av.z = Ap[2]; av.w = Ap[3]; }
        else {
          if (gk     < khi) av.x = Ap[0];
          if (gk + 1 < khi) av.y = Ap[1];
          if (gk + 2 < khi) av.z = Ap[2];
        }
      }
      pa[it] = av;
    }
#pragma unroll
    for (int it = 0; it < BIT; ++it) {
      const int s = it * 256 + tid;
      const int kr = s / (BN / 4), c = (s % (BN / 4)) << 2;
      float4 bv = make_float4(0.f, 0.f, 0.f, 0.f);
      const int gk = k0 + kr, gc = col0 + c;
      if (gk < khi) {
        const float* Bp = B + (size_t)gk * ldb + gc;
        if (gc + 3 < M) { bv.x = Bp[0]; bv.y = Bp[1]; bv.z = Bp[2]; bv.w = Bp[3]; }
        else {
          if (gc     < M) bv.x = Bp[0];
          if (gc + 1 < M) bv.y = Bp[1];
          if (gc + 2 < M) bv.z = Bp[2];
        }
      }
      pb[it] = bv;
    }
  };

  load_tile(klo);
  for (int k0 = klo; k0 < khi; k0 += BK) {
#pragma unroll
    for (int it = 0; it < AIT; ++it) {
      const int s = it * 256 + tid;
      const int row = s >> 2, kq = (s & 3) << 2;
      As[kq    ][row] = pa[it].x;
      As[kq + 1][row] = pa[it].y;
      As[kq + 2][row] = pa[it].z;
      As[kq + 3][row] = pa[it].w;
    }
#pragma unroll
    for (int it = 0; it < BIT; ++it) {
      const int s = it * 256 + tid;
      const int kr = s / (BN / 4), c = (s % (BN / 4)) << 2;
      *(float4*)&Bs[kr][c] = pb[it];
    }
    __syncthreads();
    if (k0 + BK < khi) load_tile(k0 + BK);  // overlap next-tile fetch with compute
#pragma unroll
    for (int kk = 0; kk < BK; ++kk) {
      float ar[TM], br[TN];
#pragma unroll
      for (int i = 0; i < TM; i += 4)
        *(float4*)&ar[i] = *(const float4*)&As[kk][ty * TM + i];
      if constexpr (TN == 8) {
        *(float4*)&br[0] = *(const float4*)&Bs[kk][tx * 4];
        *(float4*)&br[4] = *(const float4*)&Bs[kk][BN / 2 + tx * 4];
      } else {
        *(float4*)&br[0] = *(const float4*)&Bs[kk][tx * TN];
      }
#pragma unroll
      for (int i = 0; i < TM; ++i)
#pragma unroll
        for (int j = 0; j < TN; ++j)
          acc[i][j] += ar[i] * br[j];
    }
    __syncthreads();
  }

  float* Cz = C + (size_t)blockIdx.z * zstride;
#pragma unroll
  for (int i = 0; i < TM; ++i) {
    const int r = row0 + ty * TM + i;
    if (r >= Nr) continue;
    float* Crow = Cz + (size_t)r * ldc;
#pragma unroll
    for (int g = 0; g < TN / 4; ++g) {
      const int c = col0 + (TN == 8 ? g * (BN / 2) : 0) + tx * 4;
      if (c + 3 < M) {
        float4 v;
        v.x = acc[i][g * 4 + 0]; v.y = acc[i][g * 4 + 1];
        v.z = acc[i][g * 4 + 2]; v.w = acc[i][g * 4 + 3];
        if (bias) { v.x += bias[c]; v.y += bias[c + 1]; v.z += bias[c + 2]; v.w += bias[c + 3]; }
        if (do_relu) {
          v.x = fmaxf(v.x, 0.f); v.y = fmaxf(v.y, 0.f);
          v.z = fmaxf(v.z, 0.f); v.w = fmaxf(v.w, 0.f);
        }
        *(float4*)&Crow[c] = v;
      } else {
#pragma unroll
        for (int j = 0; j < 4; ++j) {
          if (c + j >= M) continue;
          float v = acc[i][g * 4 + j];
          if (bias) v += bias[c + j];
          if (do_relu) v = fmaxf(v, 0.f);
          Crow[c + j] = v;
        }
      }
    }
  }
}

// sum Sz split-K partials + bias (+relu), write with ldd
__global__ void bias_sum_kernel(const float* __restrict__ src, int zs, int Sz,
                                float* __restrict__ dst, int ldd,
                                const float* __restrict__ bias,
                                int Nr, int M, int do_relu) {
  int idx = blockIdx.x * blockDim.x + threadIdx.x;
  if (idx >= Nr * M) return;
  int r = idx / M, c = idx - r * M;
  float v = bias[c];
  for (int z = 0; z < Sz; ++z) v += src[idx + (size_t)z * zs];
  if (do_relu) v = fmaxf(v, 0.f);
  dst[(size_t)r * ldd + c] = v;
}

// src(512x128): rows 0..255 branch0, 256..511 branch1 -> dst[256][512] cols 0..255
__global__ void cat_kernel(const float* __restrict__ src, float* __restrict__ dst) {
  int idx = blockIdx.x * blockDim.x + threadIdx.x;
  if (idx >= 512 * 128) return;
  int r = idx >> 7, c = idx & 127;
  dst[(size_t)(r & 255) * 512 + ((r >> 8) << 7) + c] = src[idx];
}

// ------------------------- graph prep -------------------------
__global__ void hist2_kernel(const int* __restrict__ e1, const int* __restrict__ e2,
                             int* __restrict__ cnt, int E, int npass) {
  int e = blockIdx.x * blockDim.x + threadIdx.x;
  if (e < E) atomicAdd(&cnt[e1[E + e]], 1);
  else if (e < npass * E) atomicAdd(&cnt[N_NODES + e2[E + e - E]], 1);
}

// ---- 3-phase parallel exclusive scan over cnt ----
__launch_bounds__(1024)
__global__ void scan1_kernel(const int* __restrict__ cnt, int* __restrict__ row_ptr,
                             int* __restrict__ part, int n) {
  __shared__ int sh[1024];
  const int tid = threadIdx.x;
  const int i = blockIdx.x * 1024 + tid;
  const int v = (i < n) ? cnt[i] : 0;
  sh[tid] = v;
  __syncthreads();
#pragma unroll
  for (int off = 1; off < 1024; off <<= 1) {
    int t = (tid >= off) ? sh[tid - off] : 0;
    __syncthreads();
    sh[tid] += t;
    __syncthreads();
  }
  if (i < n) row_ptr[i] = sh[tid] - v;  // exclusive
  if (tid == 1023) part[blockIdx.x] = sh[tid];
}

__global__ void scan2_kernel(int* __restrict__ part, int nb) {
  if (threadIdx.x == 0 && blockIdx.x == 0) {
    int run = 0;
    for (int b = 0; b < nb; ++b) { int t = part[b]; part[b] = run; run += t; }
  }
}

__global__ void scan3_kernel(const int* __restrict__ cnt, int* __restrict__ row_ptr,
                             const int* __restrict__ part, int* __restrict__ cursor,
                             float* __restrict__ dinv, int n, int total) {
  int i = blockIdx.x * blockDim.x + threadIdx.x;
  if (i >= n) return;
  int rp = row_ptr[i] + part[i >> 10];
  row_ptr[i] = rp;
  cursor[i] = rp;
  dinv[i] = rsqrtf((float)(cnt[i] + 1));
  if (i == 0) row_ptr[n] = total;
}

__global__ void scatter2_kernel(const int* __restrict__ e1, const int* __restrict__ e2,
                                int* __restrict__ cursor, int* __restrict__ col_idx,
                                int E, int npass) {
  int e = blockIdx.x * blockDim.x + threadIdx.x;
  if (e < E) {
    int p = atomicAdd(&cursor[e1[E + e]], 1);
    col_idx[p] = e1[e];
  } else if (e < npass * E) {
    int j = e - E;
    int p = atomicAdd(&cursor[N_NODES + e2[E + j]], 1);
    col_idx[p] = N_NODES + e2[j];
  }
}

// ------------ normalized aggregation, flat (node, vec-slot) threads ------------
// out = D^-1/2 (A+I) D^-1/2 x ; separate in/out leading dims (64B-padded rows).
__global__ void aggf2_flat(const float* __restrict__ h, const float* __restrict__ h2,
                           int nsplit, const int* __restrict__ row_ptr,
                           const int* __restrict__ col_idx, const float* __restrict__ dinv,
                           float* __restrict__ out, int in_ld, int out_ld,
                           int V, int total) {
  int gid = blockIdx.x * blockDim.x + threadIdx.x;
  if (gid >= total) return;
  int n = gid / V, v = gid - n * V;
  const float din = dinv[n];
  auto rowp = [&](int s) -> const float2* {
    const float* base = (s < nsplit) ? h + (size_t)s * in_ld
                                     : h2 + (size_t)(s - nsplit) * in_ld;
    return (const float2*)base;
  };
  float2 a;
  { float2 x = rowp(n)[v]; a.x = din * x.x; a.y = din * x.y; }
  const int beg = row_ptr[n], end = row_ptr[n + 1];
  int e = beg;
  for (; e + 1 < end; e += 2) {
    int s0 = col_idx[e], s1 = col_idx[e + 1];
    float d0 = dinv[s0], d1 = dinv[s1];
    float2 x0 = rowp(s0)[v], x1 = rowp(s1)[v];
    a.x += d0 * x0.x + d1 * x1.x;
    a.y += d0 * x0.y + d1 * x1.y;
  }
  if (e < end) {
    int s0 = col_idx[e];
    float d0 = dinv[s0];
    float2 x0 = rowp(s0)[v];
    a.x += d0 * x0.x; a.y += d0 * x0.y;
  }
  float2 o; o.x = din * a.x; o.y = din * a.y;
  ((float2*)(out + (size_t)n * out_ld))[v] = o;
}

__global__ void aggf4_flat(const float* __restrict__ h, const int* __restrict__ row_ptr,
                           const int* __restrict__ col_idx, const float* __restrict__ dinv,
                           float* __restrict__ out, int in_ld, int out_ld,
                           int V, int total) {
  int gid = blockIdx.x * blockDim.x + threadIdx.x;
  if (gid >= total) return;
  int n = gid / V, v = gid - n * V;
  const float din = dinv[n];
  const int ivs = in_ld >> 2;
  const float4* hv = (const float4*)h;
  float4 a;
  {
    float4 x = hv[(size_t)n * ivs + v];
    a.x = din * x.x; a.y = din * x.y; a.z = din * x.z; a.w = din * x.w;
  }
  const int beg = row_ptr[n], end = row_ptr[n + 1];
  int e = beg;
  for (; e + 1 < end; e += 2) {
    int s0 = col_idx[e], s1 = col_idx[e + 1];
    float d0 = dinv[s0], d1 = dinv[s1];
    float4 x0 = hv[(size_t)s0 * ivs + v], x1 = hv[(size_t)s1 * ivs + v];
    a.x += d0 * x0.x + d1 * x1.x;
    a.y += d0 * x0.y + d1 * x1.y;
    a.z += d0 * x0.z + d1 * x1.z;
    a.w += d0 * x0.w + d1 * x1.w;
  }
  if (e < end) {
    int s0 = col_idx[e];
    float d0 = dinv[s0];
    float4 x0 = hv[(size_t)s0 * ivs + v];
    a.x += d0 * x0.x; a.y += d0 * x0.y; a.z += d0 * x0.z; a.w += d0 * x0.w;
  }
  float4 o;
  o.x = din * a.x; o.y = din * a.y; o.z = din * a.z; o.w = din * a.w;
  ((float4*)(out + (size_t)n * out_ld))[v] = o;
}

__global__ void starts2_kernel(const int* __restrict__ b1, const int* __restrict__ b2,
                               int* __restrict__ s1, int* __restrict__ s2, int n, int npass) {
  int i = blockIdx.x * blockDim.x + threadIdx.x;
  if (i < n) {
    if (i == 0) { s1[0] = 0; s1[N_GRAPH] = n; }
    else if (b1[i] != b1[i - 1]) s1[b1[i]] = i;
  } else if (i < npass * n) {
    int j = i - n;
    if (j == 0) { s2[0] = n; s2[N_GRAPH] = 2 * n; }
    else if (b2[j] != b2[j - 1]) s2[b2[j]] = n + j;
  }
}

__global__ void pool_kernel(const float* __restrict__ x, int xld,
                            const int* __restrict__ s1, const int* __restrict__ s2,
                            float* __restrict__ pooled, int F, int pool_base) {
  int g = blockIdx.x;
  const int* st = (g < N_GRAPH) ? s1 : s2;
  int gi = g & (N_GRAPH - 1);
  int beg = st[gi], end = st[gi + 1];
  for (int f = threadIdx.x; f < F; f += blockDim.x) {
    float m = 0.f;  // post-ReLU inputs >= 0
    for (int nn = beg; nn < end; ++nn) m = fmaxf(m, x[(size_t)nn * xld + f]);
    pooled[(size_t)(pool_base + g) * F + f] = m;
  }
}

__global__ void rownorm_kernel(const float* __restrict__ cell, float* __restrict__ cv, int F) {
  int g = blockIdx.x;
  __shared__ float red[256];
  int tid = threadIdx.x;
  const float* row = cell + (size_t)g * F;
  float s = 0.f;
  for (int f = tid; f < F; f += 256) { float v = row[f]; s += v * v; }
  red[tid] = s;
  __syncthreads();
  for (int off = 128; off > 0; off >>= 1) {
    if (tid < off) red[tid] += red[tid + off];
    __syncthreads();
  }
  float inv = 1.f / fmaxf(sqrtf(red[0]), 1e-12f);
  float* orow = cv + (size_t)g * F;
  for (int f = tid; f < F; f += 256) orow[f] = row[f] * inv;
}

// ------------------------- launcher -------------------------
extern "C" void kernel_launch(void* const* d_in, const int* in_sizes, int n_in,
                              void* d_out, int out_size, void* d_ws, size_t ws_size,
                              hipStream_t stream) {
  (void)in_sizes; (void)n_in; (void)out_size;
  const float* x1  = (const float*)d_in[0];
  const int*   ei1 = (const int*)d_in[1];
  const int*   bt1 = (const int*)d_in[2];
  const float* x2  = (const float*)d_in[3];
  const int*   ei2 = (const int*)d_in[4];
  const int*   bt2 = (const int*)d_in[5];
  const float* cell = (const float*)d_in[6];
  const float* Wc1 = (const float*)d_in[7];  const float* bc1 = (const float*)d_in[8];
  const float* Wc2 = (const float*)d_in[9];  const float* bc2 = (const float*)d_in[10];
  const float* Wc3 = (const float*)d_in[11]; const float* bc3 = (const float*)d_in[12];
  const float* Wg1 = (const float*)d_in[13]; const float* bg1 = (const float*)d_in[14];
  const float* Wg2 = (const float*)d_in[15]; const float* bg2 = (const float*)d_in[16];
  const float* Wr1 = (const float*)d_in[17]; const float* br1 = (const float*)d_in[18];
  const float* Wr2 = (const float*)d_in[19]; const float* br2 = (const float*)d_in[20];
  const float* Wr3 = (const float*)d_in[21]; const float* br3 = (const float*)d_in[22];
  const float* Wf1 = (const float*)d_in[23]; const float* bf1 = (const float*)d_in[24];
  const float* Wf2 = (const float*)d_in[25]; const float* bf2 = (const float*)d_in[26];
  const float* Wf3 = (const float*)d_in[27]; const float* bf3 = (const float*)d_in[28];
  const float* Wo  = (const float*)d_in[29]; const float* bo  = (const float*)d_in[30];
  float* out = (float*)d_out;

  const bool batched = ws_size >= (size_t)95 * 1024 * 1024;
  const int NPASS = batched ? 2 : 1;
  const int NN = NPASS * N_NODES;

  char* ws = (char*)d_ws;
  size_t off = 0;
  auto alloc_f = [&](size_t ne) { float* p = (float*)(ws + off); off += ne * 4; return p; };
  auto alloc_i = [&](size_t ne) { int* p = (int*)(ws + off); off += ne * 4; return p; };
  float* xbuf   = alloc_f((size_t)NN * 320);   // activations (64B-padded rows)
  float* abuf   = alloc_f((size_t)NN * 160);   // aggregated input (64B-padded rows)
  float* dinv   = alloc_f(NN);
  float* pooled = alloc_f((size_t)512 * 312);
  float* cvbuf  = alloc_f((size_t)N_GRAPH * 954);
  float* gtmp1  = alloc_f((size_t)512 * 2048);
  float* gtmp2  = alloc_f((size_t)512 * 512);
  float* gtmp3  = alloc_f((size_t)N_GRAPH * 256);
  float* catbuf = alloc_f((size_t)N_GRAPH * 512);
  int* cnt     = alloc_i(NN);
  int* row_ptr = alloc_i(NN + 1);
  int* cursor  = alloc_i(NN);
  int* col_idx = alloc_i(NPASS * N_EDGES);
  int* part    = alloc_i(64);
  int* start1  = alloc_i(N_GRAPH + 1);
  int* start2  = alloc_i(N_GRAPH + 1);
  float* accb  = xbuf;  // split-K partials (MLP runs after pooling; xbuf free then)

  auto gemm_big = [&](const float* A, int lda, const float* B, int ldb, float* C, int ldc,
                      const float* bias, int Nr, int K, int M, int relu) {
    dim3 grid((M + 127) / 128, (Nr + 127) / 128, 1);
    gemm_t<128, 128, 8, 8><<<grid, 256, 0, stream>>>(A, lda, B, ldb, C, ldc, 0, bias,
                                                     Nr, K, M, relu, K);
  };
  auto gemm_med = [&](const float* A, int lda, const float* B, int ldb, float* C, int ldc,
                      const float* bias, int Nr, int K, int M, int relu) {
    dim3 grid((M + 63) / 64, (Nr + 127) / 128, 1);
    gemm_t<128, 64, 8, 4><<<grid, 256, 0, stream>>>(A, lda, B, ldb, C, ldc, 0, bias,
                                                    Nr, K, M, relu, K);
  };
  auto gemm_small = [&](const float* A, int lda, const float* B, int ldb, float* C, int ldc,
                        const float* bias, int Nr, int K, int M, int relu) {
    dim3 grid((M + 63) / 64, (Nr + 63) / 64, 1);
    gemm_t<64, 64, 4, 4><<<grid, 256, 0, stream>>>(A, lda, B, ldb, C, ldc, 0, bias,
                                                   Nr, K, M, relu, K);
  };
  // split-K MLP layer (Nr = 256): partial stores per z-slice + summing bias/act pass
  auto splitk = [&](const float* A, int lda, const float* B, int M_, int K_, int S,
                    const float* bias, float* dst, int ldd, int relu) {
    int kchunk = (((K_ + S - 1) / S) + 15) / 16 * 16;
    int Sz = (K_ + kchunk - 1) / kchunk;
    dim3 grid((M_ + 63) / 64, (N_GRAPH + 63) / 64, Sz);
    gemm_t<64, 64, 4, 4><<<grid, 256, 0, stream>>>(A, lda, B, M_, accb, M_, N_GRAPH * M_,
                                                   nullptr, N_GRAPH, K_, M_, 0, kchunk);
    int tot = N_GRAPH * M_;
    bias_sum_kernel<<<(tot + 255) / 256, 256, 0, stream>>>(accb, N_GRAPH * M_, Sz, dst, ldd,
                                                           bias, N_GRAPH, M_, relu);
  };

  auto drug_pass = [&](const float* xa, const float* xb, const int* eia, const int* eib,
                       const int* bta, const int* btb, int npass, int pool_base) {
    const int nn = npass * N_NODES;
    const int te = npass * N_EDGES;
    const int nb = (nn + 1023) / 1024;
    hipMemsetAsync(cnt, 0, nn * sizeof(int), stream);
    hist2_kernel<<<(te + 255) / 256, 256, 0, stream>>>(eia, eib, cnt, N_EDGES, npass);
    scan1_kernel<<<nb, 1024, 0, stream>>>(cnt, row_ptr, part, nn);
    scan2_kernel<<<1, 64, 0, stream>>>(part, nb);
    scan3_kernel<<<(nn + 255) / 256, 256, 0, stream>>>(cnt, row_ptr, part, cursor, dinv, nn, te);
    scatter2_kernel<<<(te + 255) / 256, 256, 0, stream>>>(eia, eib, cursor, col_idx, N_EDGES, npass);
    // layer 1: agg(78, dual-source raw x, ld 78) -> abuf ld 80 -> GEMM 78->78 (out ld 80)
    {
      int tot = nn * 39;
      aggf2_flat<<<(tot + 255) / 256, 256, 0, stream>>>(xa, xb, N_NODES, row_ptr, col_idx,
                                                        dinv, abuf, 78, 80, 39, tot);
    }
    gemm_med(abuf, 80, Wc1, 78, xbuf, 80, bc1, nn, 78, 78, 1);
    // layer 2: agg(78, ld 80) -> abuf ld 80 -> GEMM 78->156 (out ld 160)
    {
      int tot = nn * 39;
      aggf2_flat<<<(tot + 255) / 256, 256, 0, stream>>>(xbuf, xbuf, nn, row_ptr, col_idx,
                                                        dinv, abuf, 80, 80, 39, tot);
    }
    gemm_med(abuf, 80, Wc2, 156, xbuf, 160, bc2, nn, 78, 156, 1);
    // layer 3: agg(156, ld 160) -> abuf ld 160 -> GEMM 156->312 (out ld 320)
    {
      int tot = nn * 39;
      aggf4_flat<<<(tot + 255) / 256, 256, 0, stream>>>(xbuf, row_ptr, col_idx,
                                                        dinv, abuf, 160, 160, 39, tot);
    }
    gemm_big(abuf, 160, Wc3, 312, xbuf, 320, bc3, nn, 156, 312, 1);
    // pool
    starts2_kernel<<<(nn + 255) / 256, 256, 0, stream>>>(bta, btb, start1, start2, N_NODES, npass);
    pool_kernel<<<npass * N_GRAPH, 128, 0, stream>>>(xbuf, 320, start1, start2, pooled, 312, pool_base);
  };

  if (batched) {
    drug_pass(x1, x2, ei1, ei2, bt1, bt2, 2, 0);
  } else {
    drug_pass(x1, x1, ei1, ei1, bt1, bt1, 1, 0);
    drug_pass(x2, x2, ei2, ei2, bt2, bt2, 1, N_GRAPH);
  }

  // drug head on both branches at once (512 rows; shared weights)
  gemm_med(pooled, 312, Wg1, 156, gtmp1, 156, bg1, 2 * N_GRAPH, 312, 156, 1);
  gemm_med(gtmp1, 156, Wg2, 128, gtmp2, 128, bg2, 2 * N_GRAPH, 156, 128, 0);
  cat_kernel<<<(512 * 128 + 255) / 256, 256, 0, stream>>>(gtmp2, catbuf);

  // cell branch + head MLP (256-row deep-K layers via split-K)
  rownorm_kernel<<<N_GRAPH, 256, 0, stream>>>(cell, cvbuf, 954);
  splitk(cvbuf, 954, Wr1, 2048, 954, 8,   br1, gtmp1, 2048, 1);
  splitk(gtmp1, 2048, Wr2, 512, 2048, 32, br2, gtmp2, 512, 1);
  splitk(gtmp2, 512, Wr3, 256, 512, 16,   br3, catbuf + 256, 512, 1);
  splitk(catbuf, 512, Wf1, 1024, 512, 16, bf1, gtmp1, 1024, 1);
  splitk(gtmp1, 1024, Wf2, 512, 1024, 32, bf2, gtmp2, 512, 1);
  splitk(gtmp2, 512, Wf3, 128, 512, 32,   bf3, gtmp3, 128, 1);
  gemm_small(gtmp3, 128, Wo, 2, out, 2, bo, N_GRAPH, 128, 2, 0);
}

// Round 10
// 680.860 us; speedup vs baseline: 1.0616x; 1.0147x over previous
//
#include <hip/hip_runtime.h>

#define N_NODES 20000
#define N_EDGES 320000
#define N_GRAPH 256

// ------------------------- templated tiled fp32 GEMM -------------------------
// zstride==0: direct C = op(A@B + bias). zstride>0 (split-K): block z plain-stores
// its partial to C + z*zstride (summed later by bias_sum_kernel).
// A-tile k-major in LDS; B-fragment split in two stride-4 groups (2-way = free).
// STRUCTURE IS MEASUREMENT-PINNED (do not change without re-measuring):
//   BK=16, single LDS buffer, register prefetch of tile k+1 -> VGPR 100, ~79us Wc3.
//   LDS double-buffer: VGPR 188, occ 10%, 135us (R6). BK=32: VGPR 148, 111us (R8).
//   Occupancy cliff: +30 VGPR or +16KB LDS loses more than any barrier saving gains.
//   R10: Wc3 moved to BN=64 tile for 1565 blocks (was 939) -> better CU balance.
template<int BM, int BN, int TM, int TN>
__launch_bounds__(256)
__global__ void gemm_t(const float* __restrict__ A, int lda,
                       const float* __restrict__ B, int ldb,
                       float* __restrict__ C, int ldc, int zstride,
                       const float* __restrict__ bias,
                       int Nr, int K, int M, int do_relu, int kchunk) {
  constexpr int BK = 16;
  constexpr int LDA = BM + 4;
  __shared__ __align__(16) float As[BK][LDA];
  __shared__ __align__(16) float Bs[BK][BN];
  const int tid = threadIdx.x;
  const int row0 = blockIdx.y * BM, col0 = blockIdx.x * BN;
  constexpr int NX = BN / TN;
  const int tx = tid % NX, ty = tid / NX;
  float acc[TM][TN] = {};
  const int klo = blockIdx.z * kchunk;
  const int khi = min(klo + kchunk, K);

  constexpr int AIT = BM * BK / 4 / 256;
  constexpr int BIT = BK * BN / 4 / 256;
  float4 pa[AIT], pb[BIT];

  auto load_tile = [&](int k0) {
#pragma unroll
    for (int it = 0; it < AIT; ++it) {
      const int s = it * 256 + tid;
      const int row = s >> 2, kq = (s & 3) << 2;
      float4 av = make_float4(0.f, 0.f, 0.f, 0.f);
      const int gr = row0 + row, gk = k0 + kq;
      if (gr < Nr) {
        const float* Ap = A + (size_t)gr * lda + gk;
        if (gk + 3 < khi) { av.x = Ap[0]; av.y = Ap[1]; av.z = Ap[2]; av.w = Ap[3]; }
        else {
          if (gk     < khi) av.x = Ap[0];
          if (gk + 1 < khi) av.y = Ap[1];
          if (gk + 2 < khi) av.z = Ap[2];
        }
      }
      pa[it] = av;
    }
#pragma unroll
    for (int it = 0; it < BIT; ++it) {
      const int s = it * 256 + tid;
      const int kr = s / (BN / 4), c = (s % (BN / 4)) << 2;
      float4 bv = make_float4(0.f, 0.f, 0.f, 0.f);
      const int gk = k0 + kr, gc = col0 + c;
      if (gk < khi) {
        const float* Bp = B + (size_t)gk * ldb + gc;
        if (gc + 3 < M) { bv.x = Bp[0]; bv.y = Bp[1]; bv.z = Bp[2]; bv.w = Bp[3]; }
        else {
          if (gc     < M) bv.x = Bp[0];
          if (gc + 1 < M) bv.y = Bp[1];
          if (gc + 2 < M) bv.z = Bp[2];
        }
      }
      pb[it] = bv;
    }
  };

  load_tile(klo);
  for (int k0 = klo; k0 < khi; k0 += BK) {
#pragma unroll
    for (int it = 0; it < AIT; ++it) {
      const int s = it * 256 + tid;
      const int row = s >> 2, kq = (s & 3) << 2;
      As[kq    ][row] = pa[it].x;
      As[kq + 1][row] = pa[it].y;
      As[kq + 2][row] = pa[it].z;
      As[kq + 3][row] = pa[it].w;
    }
#pragma unroll
    for (int it = 0; it < BIT; ++it) {
      const int s = it * 256 + tid;
      const int kr = s / (BN / 4), c = (s % (BN / 4)) << 2;
      *(float4*)&Bs[kr][c] = pb[it];
    }
    __syncthreads();
    if (k0 + BK < khi) load_tile(k0 + BK);  // overlap next-tile fetch with compute
#pragma unroll
    for (int kk = 0; kk < BK; ++kk) {
      float ar[TM], br[TN];
#pragma unroll
      for (int i = 0; i < TM; i += 4)
        *(float4*)&ar[i] = *(const float4*)&As[kk][ty * TM + i];
      if constexpr (TN == 8) {
        *(float4*)&br[0] = *(const float4*)&Bs[kk][tx * 4];
        *(float4*)&br[4] = *(const float4*)&Bs[kk][BN / 2 + tx * 4];
      } else {
        *(float4*)&br[0] = *(const float4*)&Bs[kk][tx * TN];
      }
#pragma unroll
      for (int i = 0; i < TM; ++i)
#pragma unroll
        for (int j = 0; j < TN; ++j)
          acc[i][j] += ar[i] * br[j];
    }
    __syncthreads();
  }

  float* Cz = C + (size_t)blockIdx.z * zstride;
#pragma unroll
  for (int i = 0; i < TM; ++i) {
    const int r = row0 + ty * TM + i;
    if (r >= Nr) continue;
    float* Crow = Cz + (size_t)r * ldc;
#pragma unroll
    for (int g = 0; g < TN / 4; ++g) {
      const int c = col0 + (TN == 8 ? g * (BN / 2) : 0) + tx * 4;
      if (c + 3 < M) {
        float4 v;
        v.x = acc[i][g * 4 + 0]; v.y = acc[i][g * 4 + 1];
        v.z = acc[i][g * 4 + 2]; v.w = acc[i][g * 4 + 3];
        if (bias) { v.x += bias[c]; v.y += bias[c + 1]; v.z += bias[c + 2]; v.w += bias[c + 3]; }
        if (do_relu) {
          v.x = fmaxf(v.x, 0.f); v.y = fmaxf(v.y, 0.f);
          v.z = fmaxf(v.z, 0.f); v.w = fmaxf(v.w, 0.f);
        }
        *(float4*)&Crow[c] = v;
      } else {
#pragma unroll
        for (int j = 0; j < 4; ++j) {
          if (c + j >= M) continue;
          float v = acc[i][g * 4 + j];
          if (bias) v += bias[c + j];
          if (do_relu) v = fmaxf(v, 0.f);
          Crow[c + j] = v;
        }
      }
    }
  }
}

// sum Sz split-K partials + bias (+relu), write with ldd
__global__ void bias_sum_kernel(const float* __restrict__ src, int zs, int Sz,
                                float* __restrict__ dst, int ldd,
                                const float* __restrict__ bias,
                                int Nr, int M, int do_relu) {
  int idx = blockIdx.x * blockDim.x + threadIdx.x;
  if (idx >= Nr * M) return;
  int r = idx / M, c = idx - r * M;
  float v = bias[c];
  for (int z = 0; z < Sz; ++z) v += src[idx + (size_t)z * zs];
  if (do_relu) v = fmaxf(v, 0.f);
  dst[(size_t)r * ldd + c] = v;
}

// ------------------------- graph prep -------------------------
__global__ void hist2_kernel(const int* __restrict__ e1, const int* __restrict__ e2,
                             int* __restrict__ cnt, int E, int npass) {
  int e = blockIdx.x * blockDim.x + threadIdx.x;
  if (e < E) atomicAdd(&cnt[e1[E + e]], 1);
  else if (e < npass * E) atomicAdd(&cnt[N_NODES + e2[E + e - E]], 1);
}

// ---- parallel exclusive scan over cnt (scan1 = per-1024-block; scan23 = fixup) ----
__launch_bounds__(1024)
__global__ void scan1_kernel(const int* __restrict__ cnt, int* __restrict__ row_ptr,
                             int* __restrict__ part, int n) {
  __shared__ int sh[1024];
  const int tid = threadIdx.x;
  const int i = blockIdx.x * 1024 + tid;
  const int v = (i < n) ? cnt[i] : 0;
  sh[tid] = v;
  __syncthreads();
#pragma unroll
  for (int off = 1; off < 1024; off <<= 1) {
    int t = (tid >= off) ? sh[tid - off] : 0;
    __syncthreads();
    sh[tid] += t;
    __syncthreads();
  }
  if (i < n) row_ptr[i] = sh[tid] - v;  // exclusive
  if (tid == 1023) part[blockIdx.x] = sh[tid];
}

// merged scan2+scan3: each 256-block lies in one 1024-part-block (256|1024), so
// thread 0 sums part[0 .. blockIdx.x>>2) serially (<40 adds), broadcast via LDS.
__global__ void scan23_kernel(const int* __restrict__ cnt, int* __restrict__ row_ptr,
                              const int* __restrict__ part, int* __restrict__ cursor,
                              float* __restrict__ dinv, int n, int total) {
  __shared__ int base_sh;
  const int tid = threadIdx.x;
  if (tid == 0) {
    int blk = blockIdx.x >> 2;
    int s = 0;
    for (int b = 0; b < blk; ++b) s += part[b];
    base_sh = s;
  }
  __syncthreads();
  int i = blockIdx.x * 256 + tid;
  if (i >= n) return;
  int rp = row_ptr[i] + base_sh;
  row_ptr[i] = rp;
  cursor[i] = rp;
  dinv[i] = rsqrtf((float)(cnt[i] + 1));
  if (i == 0) row_ptr[n] = total;
}

__global__ void scatter2_kernel(const int* __restrict__ e1, const int* __restrict__ e2,
                                int* __restrict__ cursor, int* __restrict__ col_idx,
                                int E, int npass) {
  int e = blockIdx.x * blockDim.x + threadIdx.x;
  if (e < E) {
    int p = atomicAdd(&cursor[e1[E + e]], 1);
    col_idx[p] = e1[e];
  } else if (e < npass * E) {
    int j = e - E;
    int p = atomicAdd(&cursor[N_NODES + e2[E + j]], 1);
    col_idx[p] = N_NODES + e2[j];
  }
}

// ------------ normalized aggregation, flat (node, vec-slot) threads ------------
// out = D^-1/2 (A+I) D^-1/2 x ; separate in/out leading dims (64B-padded rows).
__global__ void aggf2_flat(const float* __restrict__ h, const float* __restrict__ h2,
                           int nsplit, const int* __restrict__ row_ptr,
                           const int* __restrict__ col_idx, const float* __restrict__ dinv,
                           float* __restrict__ out, int in_ld, int out_ld,
                           int V, int total) {
  int gid = blockIdx.x * blockDim.x + threadIdx.x;
  if (gid >= total) return;
  int n = gid / V, v = gid - n * V;
  const float din = dinv[n];
  auto rowp = [&](int s) -> const float2* {
    const float* base = (s < nsplit) ? h + (size_t)s * in_ld
                                     : h2 + (size_t)(s - nsplit) * in_ld;
    return (const float2*)base;
  };
  float2 a;
  { float2 x = rowp(n)[v]; a.x = din * x.x; a.y = din * x.y; }
  const int beg = row_ptr[n], end = row_ptr[n + 1];
  int e = beg;
  for (; e + 3 < end; e += 4) {
    int s0 = col_idx[e], s1 = col_idx[e + 1], s2 = col_idx[e + 2], s3 = col_idx[e + 3];
    float d0 = dinv[s0], d1 = dinv[s1], d2 = dinv[s2], d3 = dinv[s3];
    float2 x0 = rowp(s0)[v], x1 = rowp(s1)[v], x2 = rowp(s2)[v], x3 = rowp(s3)[v];
    a.x += d0 * x0.x + d1 * x1.x + d2 * x2.x + d3 * x3.x;
    a.y += d0 * x0.y + d1 * x1.y + d2 * x2.y + d3 * x3.y;
  }
  for (; e < end; ++e) {
    int s0 = col_idx[e];
    float d0 = dinv[s0];
    float2 x0 = rowp(s0)[v];
    a.x += d0 * x0.x; a.y += d0 * x0.y;
  }
  float2 o; o.x = din * a.x; o.y = din * a.y;
  ((float2*)(out + (size_t)n * out_ld))[v] = o;
}

__global__ void aggf4_flat(const float* __restrict__ h, const int* __restrict__ row_ptr,
                           const int* __restrict__ col_idx, const float* __restrict__ dinv,
                           float* __restrict__ out, int in_ld, int out_ld,
                           int V, int total) {
  int gid = blockIdx.x * blockDim.x + threadIdx.x;
  if (gid >= total) return;
  int n = gid / V, v = gid - n * V;
  const float din = dinv[n];
  const int ivs = in_ld >> 2;
  const float4* hv = (const float4*)h;
  float4 a;
  {
    float4 x = hv[(size_t)n * ivs + v];
    a.x = din * x.x; a.y = din * x.y; a.z = din * x.z; a.w = din * x.w;
  }
  const int beg = row_ptr[n], end = row_ptr[n + 1];
  int e = beg;
  for (; e + 3 < end; e += 4) {
    int s0 = col_idx[e], s1 = col_idx[e + 1], s2 = col_idx[e + 2], s3 = col_idx[e + 3];
    float d0 = dinv[s0], d1 = dinv[s1], d2 = dinv[s2], d3 = dinv[s3];
    float4 x0 = hv[(size_t)s0 * ivs + v], x1 = hv[(size_t)s1 * ivs + v];
    float4 x2 = hv[(size_t)s2 * ivs + v], x3 = hv[(size_t)s3 * ivs + v];
    a.x += d0 * x0.x + d1 * x1.x + d2 * x2.x + d3 * x3.x;
    a.y += d0 * x0.y + d1 * x1.y + d2 * x2.y + d3 * x3.y;
    a.z += d0 * x0.z + d1 * x1.z + d2 * x2.z + d3 * x3.z;
    a.w += d0 * x0.w + d1 * x1.w + d2 * x2.w + d3 * x3.w;
  }
  for (; e < end; ++e) {
    int s0 = col_idx[e];
    float d0 = dinv[s0];
    float4 x0 = hv[(size_t)s0 * ivs + v];
    a.x += d0 * x0.x; a.y += d0 * x0.y; a.z += d0 * x0.z; a.w += d0 * x0.w;
  }
  float4 o;
  o.x = din * a.x; o.y = din * a.y; o.z = din * a.z; o.w = din * a.w;
  ((float4*)(out + (size_t)n * out_ld))[v] = o;
}

__global__ void starts2_kernel(const int* __restrict__ b1, const int* __restrict__ b2,
                               int* __restrict__ s1, int* __restrict__ s2, int n, int npass) {
  int i = blockIdx.x * blockDim.x + threadIdx.x;
  if (i < n) {
    if (i == 0) { s1[0] = 0; s1[N_GRAPH] = n; }
    else if (b1[i] != b1[i - 1]) s1[b1[i]] = i;
  } else if (i < npass * n) {
    int j = i - n;
    if (j == 0) { s2[0] = n; s2[N_GRAPH] = 2 * n; }
    else if (b2[j] != b2[j - 1]) s2[b2[j]] = n + j;
  }
}

__global__ void pool_kernel(const float* __restrict__ x, int xld,
                            const int* __restrict__ s1, const int* __restrict__ s2,
                            float* __restrict__ pooled, int F, int pool_base) {
  int g = blockIdx.x;
  const int* st = (g < N_GRAPH) ? s1 : s2;
  int gi = g & (N_GRAPH - 1);
  int beg = st[gi], end = st[gi + 1];
  for (int f = threadIdx.x; f < F; f += blockDim.x) {
    float m = 0.f;  // post-ReLU inputs >= 0
    for (int nn = beg; nn < end; ++nn) m = fmaxf(m, x[(size_t)nn * xld + f]);
    pooled[(size_t)(pool_base + g) * F + f] = m;
  }
}

__global__ void rownorm_kernel(const float* __restrict__ cell, float* __restrict__ cv,
                               int F, int out_ld) {
  int g = blockIdx.x;
  __shared__ float red[256];
  int tid = threadIdx.x;
  const float* row = cell + (size_t)g * F;
  float s = 0.f;
  for (int f = tid; f < F; f += 256) { float v = row[f]; s += v * v; }
  red[tid] = s;
  __syncthreads();
  for (int off = 128; off > 0; off >>= 1) {
    if (tid < off) red[tid] += red[tid + off];
    __syncthreads();
  }
  float inv = 1.f / fmaxf(sqrtf(red[0]), 1e-12f);
  float* orow = cv + (size_t)g * out_ld;
  for (int f = tid; f < F; f += 256) orow[f] = row[f] * inv;
  for (int f = F + tid; f < out_ld; f += 256) orow[f] = 0.f;  // pad zeros (K covers 954 only anyway)
}

// ------------------------- launcher -------------------------
extern "C" void kernel_launch(void* const* d_in, const int* in_sizes, int n_in,
                              void* d_out, int out_size, void* d_ws, size_t ws_size,
                              hipStream_t stream) {
  (void)in_sizes; (void)n_in; (void)out_size;
  const float* x1  = (const float*)d_in[0];
  const int*   ei1 = (const int*)d_in[1];
  const int*   bt1 = (const int*)d_in[2];
  const float* x2  = (const float*)d_in[3];
  const int*   ei2 = (const int*)d_in[4];
  const int*   bt2 = (const int*)d_in[5];
  const float* cell = (const float*)d_in[6];
  const float* Wc1 = (const float*)d_in[7];  const float* bc1 = (const float*)d_in[8];
  const float* Wc2 = (const float*)d_in[9];  const float* bc2 = (const float*)d_in[10];
  const float* Wc3 = (const float*)d_in[11]; const float* bc3 = (const float*)d_in[12];
  const float* Wg1 = (const float*)d_in[13]; const float* bg1 = (const float*)d_in[14];
  const float* Wg2 = (const float*)d_in[15]; const float* bg2 = (const float*)d_in[16];
  const float* Wr1 = (const float*)d_in[17]; const float* br1 = (const float*)d_in[18];
  const float* Wr2 = (const float*)d_in[19]; const float* br2 = (const float*)d_in[20];
  const float* Wr3 = (const float*)d_in[21]; const float* br3 = (const float*)d_in[22];
  const float* Wf1 = (const float*)d_in[23]; const float* bf1 = (const float*)d_in[24];
  const float* Wf2 = (const float*)d_in[25]; const float* bf2 = (const float*)d_in[26];
  const float* Wf3 = (const float*)d_in[27]; const float* bf3 = (const float*)d_in[28];
  const float* Wo  = (const float*)d_in[29]; const float* bo  = (const float*)d_in[30];
  float* out = (float*)d_out;

  const bool batched = ws_size >= (size_t)95 * 1024 * 1024;
  const int NPASS = batched ? 2 : 1;
  const int NN = NPASS * N_NODES;

  char* ws = (char*)d_ws;
  size_t off = 0;
  auto alloc_f = [&](size_t ne) { float* p = (float*)(ws + off); off += ne * 4; return p; };
  auto alloc_i = [&](size_t ne) { int* p = (int*)(ws + off); off += ne * 4; return p; };
  float* xbuf   = alloc_f((size_t)NN * 320);   // activations (64B-padded rows)
  float* abuf   = alloc_f((size_t)NN * 160);   // aggregated input (64B-padded rows)
  float* dinv   = alloc_f(NN);
  float* pooled = alloc_f((size_t)512 * 312);
  float* cvbuf  = alloc_f((size_t)N_GRAPH * 960);
  float* gtmp1  = alloc_f((size_t)512 * 2048);
  float* gtmp2  = alloc_f((size_t)512 * 512);
  float* gtmp3  = alloc_f((size_t)N_GRAPH * 256);
  float* catbuf = alloc_f((size_t)N_GRAPH * 512);
  int* cnt     = alloc_i(NN);
  int* row_ptr = alloc_i(NN + 1);
  int* cursor  = alloc_i(NN);
  int* col_idx = alloc_i(NPASS * N_EDGES);
  int* part    = alloc_i(64);
  int* start1  = alloc_i(N_GRAPH + 1);
  int* start2  = alloc_i(N_GRAPH + 1);
  float* accb  = xbuf;  // split-K partials (MLP runs after pooling; xbuf free then)

  auto gemm_med = [&](const float* A, int lda, const float* B, int ldb, float* C, int ldc,
                      const float* bias, int Nr, int K, int M, int relu) {
    dim3 grid((M + 63) / 64, (Nr + 127) / 128, 1);
    gemm_t<128, 64, 8, 4><<<grid, 256, 0, stream>>>(A, lda, B, ldb, C, ldc, 0, bias,
                                                    Nr, K, M, relu, K);
  };
  auto gemm_small = [&](const float* A, int lda, const float* B, int ldb, float* C, int ldc,
                        const float* bias, int Nr, int K, int M, int relu) {
    dim3 grid((M + 63) / 64, (Nr + 63) / 64, 1);
    gemm_t<64, 64, 4, 4><<<grid, 256, 0, stream>>>(A, lda, B, ldb, C, ldc, 0, bias,
                                                   Nr, K, M, relu, K);
  };
  // split-K MLP layer (Nr = 256): partial stores per z-slice + summing bias/act pass
  auto splitk = [&](const float* A, int lda, const float* B, int M_, int K_, int S,
                    const float* bias, float* dst, int ldd, int relu) {
    int kchunk = (((K_ + S - 1) / S) + 15) / 16 * 16;
    int Sz = (K_ + kchunk - 1) / kchunk;
    dim3 grid((M_ + 63) / 64, (N_GRAPH + 63) / 64, Sz);
    gemm_t<64, 64, 4, 4><<<grid, 256, 0, stream>>>(A, lda, B, M_, accb, M_, N_GRAPH * M_,
                                                   nullptr, N_GRAPH, K_, M_, 0, kchunk);
    int tot = N_GRAPH * M_;
    bias_sum_kernel<<<(tot + 255) / 256, 256, 0, stream>>>(accb, N_GRAPH * M_, Sz, dst, ldd,
                                                           bias, N_GRAPH, M_, relu);
  };

  auto drug_pass = [&](const float* xa, const float* xb, const int* eia, const int* eib,
                       const int* bta, const int* btb, int npass, int pool_base) {
    const int nn = npass * N_NODES;
    const int te = npass * N_EDGES;
    const int nb = (nn + 1023) / 1024;
    hipMemsetAsync(cnt, 0, nn * sizeof(int), stream);
    hist2_kernel<<<(te + 255) / 256, 256, 0, stream>>>(eia, eib, cnt, N_EDGES, npass);
    scan1_kernel<<<nb, 1024, 0, stream>>>(cnt, row_ptr, part, nn);
    scan23_kernel<<<(nn + 255) / 256, 256, 0, stream>>>(cnt, row_ptr, part, cursor, dinv, nn, te);
    scatter2_kernel<<<(te + 255) / 256, 256, 0, stream>>>(eia, eib, cursor, col_idx, N_EDGES, npass);
    // layer 1: agg(78, dual-source raw x, ld 78) -> abuf ld 80 -> GEMM 78->78 (out ld 80)
    {
      int tot = nn * 39;
      aggf2_flat<<<(tot + 255) / 256, 256, 0, stream>>>(xa, xb, N_NODES, row_ptr, col_idx,
                                                        dinv, abuf, 78, 80, 39, tot);
    }
    gemm_med(abuf, 80, Wc1, 78, xbuf, 80, bc1, nn, 78, 78, 1);
    // layer 2: agg(78, ld 80) -> abuf ld 80 -> GEMM 78->156 (out ld 160)
    {
      int tot = nn * 39;
      aggf2_flat<<<(tot + 255) / 256, 256, 0, stream>>>(xbuf, xbuf, nn, row_ptr, col_idx,
                                                        dinv, abuf, 80, 80, 39, tot);
    }
    gemm_med(abuf, 80, Wc2, 156, xbuf, 160, bc2, nn, 78, 156, 1);
    // layer 3: agg(156, ld 160) -> abuf ld 160 -> GEMM 156->312 (out ld 320, BN=64 tile)
    {
      int tot = nn * 39;
      aggf4_flat<<<(tot + 255) / 256, 256, 0, stream>>>(xbuf, row_ptr, col_idx,
                                                        dinv, abuf, 160, 160, 39, tot);
    }
    gemm_med(abuf, 160, Wc3, 312, xbuf, 320, bc3, nn, 156, 312, 1);
    // pool
    starts2_kernel<<<(nn + 255) / 256, 256, 0, stream>>>(bta, btb, start1, start2, N_NODES, npass);
    pool_kernel<<<npass * N_GRAPH, 128, 0, stream>>>(xbuf, 320, start1, start2, pooled, 312, pool_base);
  };

  if (batched) {
    drug_pass(x1, x2, ei1, ei2, bt1, bt2, 2, 0);
  } else {
    drug_pass(x1, x1, ei1, ei1, bt1, bt1, 1, 0);
    drug_pass(x2, x2, ei2, ei2, bt2, bt2, 1, N_GRAPH);
  }

  // drug head on both branches at once (512 rows; shared weights).
  // Wg2 output written straight into catbuf halves (no cat kernel).
  gemm_med(pooled, 312, Wg1, 156, gtmp1, 156, bg1, 2 * N_GRAPH, 312, 156, 1);
  gemm_med(gtmp1, 156, Wg2, 128, catbuf, 512, bg2, N_GRAPH, 156, 128, 0);
  gemm_med(gtmp1 + (size_t)N_GRAPH * 156, 156, Wg2, 128, catbuf + 128, 512, bg2,
           N_GRAPH, 156, 128, 0);

  // cell branch + head MLP (256-row deep-K layers via split-K)
  rownorm_kernel<<<N_GRAPH, 256, 0, stream>>>(cell, cvbuf, 954, 960);
  splitk(cvbuf, 960, Wr1, 2048, 954, 8,   br1, gtmp1, 2048, 1);
  splitk(gtmp1, 2048, Wr2, 512, 2048, 32, br2, gtmp2, 512, 1);
  splitk(gtmp2, 512, Wr3, 256, 512, 16,   br3, catbuf + 256, 512, 1);
  splitk(catbuf, 512, Wf1, 1024, 512, 16, bf1, gtmp1, 1024, 1);
  splitk(gtmp1, 1024, Wf2, 512, 1024, 32, bf2, gtmp2, 512, 1);
  splitk(gtmp2, 512, Wf3, 128, 512, 32,   bf3, gtmp3, 128, 1);
  gemm_small(gtmp3, 128, Wo, 2, out, 2, bo, N_GRAPH, 128, 2, 0);
}

// Round 11
// 591.209 us; speedup vs baseline: 1.2226x; 1.1516x over previous
//
#include <hip/hip_runtime.h>

#define N_NODES 20000
#define N_EDGES 320000
#define N_GRAPH 256
#define POOL_NC 8

// ------------------------- templated tiled fp32 GEMM -------------------------
// zstride==0: direct C = op(A@B + bias). zstride>0 (split-K): block z plain-stores
// its partial to C + z*zstride (summed later by bias_sum_kernel).
// A-tile k-major in LDS; B-fragment split in two stride-4 groups (2-way = free).
// STRUCTURE IS MEASUREMENT-PINNED (do not change without re-measuring):
//   BK=16, single LDS buffer, register prefetch of tile k+1 -> VGPR 100.
//   LDS double-buffer: VGPR 188, occ 10%, 135us (R6). BK=32: VGPR 148, 111us (R8).
//   Occupancy cliff: +30 VGPR or +16KB LDS loses more than any barrier saving gains.
//   Wc3 on BN=64 tile (1565 blocks) beats BN=128 (939 blocks): R10.
template<int BM, int BN, int TM, int TN>
__launch_bounds__(256)
__global__ void gemm_t(const float* __restrict__ A, int lda,
                       const float* __restrict__ B, int ldb,
                       float* __restrict__ C, int ldc, int zstride,
                       const float* __restrict__ bias,
                       int Nr, int K, int M, int do_relu, int kchunk) {
  constexpr int BK = 16;
  constexpr int LDA = BM + 4;
  __shared__ __align__(16) float As[BK][LDA];
  __shared__ __align__(16) float Bs[BK][BN];
  const int tid = threadIdx.x;
  const int row0 = blockIdx.y * BM, col0 = blockIdx.x * BN;
  constexpr int NX = BN / TN;
  const int tx = tid % NX, ty = tid / NX;
  float acc[TM][TN] = {};
  const int klo = blockIdx.z * kchunk;
  const int khi = min(klo + kchunk, K);

  constexpr int AIT = BM * BK / 4 / 256;
  constexpr int BIT = BK * BN / 4 / 256;
  float4 pa[AIT], pb[BIT];

  auto load_tile = [&](int k0) {
#pragma unroll
    for (int it = 0; it < AIT; ++it) {
      const int s = it * 256 + tid;
      const int row = s >> 2, kq = (s & 3) << 2;
      float4 av = make_float4(0.f, 0.f, 0.f, 0.f);
      const int gr = row0 + row, gk = k0 + kq;
      if (gr < Nr) {
        const float* Ap = A + (size_t)gr * lda + gk;
        if (gk + 3 < khi) { av.x = Ap[0]; av.y = Ap[1]; av.z = Ap[2]; av.w = Ap[3]; }
        else {
          if (gk     < khi) av.x = Ap[0];
          if (gk + 1 < khi) av.y = Ap[1];
          if (gk + 2 < khi) av.z = Ap[2];
        }
      }
      pa[it] = av;
    }
#pragma unroll
    for (int it = 0; it < BIT; ++it) {
      const int s = it * 256 + tid;
      const int kr = s / (BN / 4), c = (s % (BN / 4)) << 2;
      float4 bv = make_float4(0.f, 0.f, 0.f, 0.f);
      const int gk = k0 + kr, gc = col0 + c;
      if (gk < khi) {
        const float* Bp = B + (size_t)gk * ldb + gc;
        if (gc + 3 < M) { bv.x = Bp[0]; bv.y = Bp[1]; bv.z = Bp[2]; bv.w = Bp[3]; }
        else {
          if (gc     < M) bv.x = Bp[0];
          if (gc + 1 < M) bv.y = Bp[1];
          if (gc + 2 < M) bv.z = Bp[2];
        }
      }
      pb[it] = bv;
    }
  };

  load_tile(klo);
  for (int k0 = klo; k0 < khi; k0 += BK) {
#pragma unroll
    for (int it = 0; it < AIT; ++it) {
      const int s = it * 256 + tid;
      const int row = s >> 2, kq = (s & 3) << 2;
      As[kq    ][row] = pa[it].x;
      As[kq + 1][row] = pa[it].y;
      As[kq + 2][row] = pa[it].z;
      As[kq + 3][row] = pa[it].w;
    }
#pragma unroll
    for (int it = 0; it < BIT; ++it) {
      const int s = it * 256 + tid;
      const int kr = s / (BN / 4), c = (s % (BN / 4)) << 2;
      *(float4*)&Bs[kr][c] = pb[it];
    }
    __syncthreads();
    if (k0 + BK < khi) load_tile(k0 + BK);  // overlap next-tile fetch with compute
#pragma unroll
    for (int kk = 0; kk < BK; ++kk) {
      float ar[TM], br[TN];
#pragma unroll
      for (int i = 0; i < TM; i += 4)
        *(float4*)&ar[i] = *(const float4*)&As[kk][ty * TM + i];
      if constexpr (TN == 8) {
        *(float4*)&br[0] = *(const float4*)&Bs[kk][tx * 4];
        *(float4*)&br[4] = *(const float4*)&Bs[kk][BN / 2 + tx * 4];
      } else {
        *(float4*)&br[0] = *(const float4*)&Bs[kk][tx * TN];
      }
#pragma unroll
      for (int i = 0; i < TM; ++i)
#pragma unroll
        for (int j = 0; j < TN; ++j)
          acc[i][j] += ar[i] * br[j];
    }
    __syncthreads();
  }

  float* Cz = C + (size_t)blockIdx.z * zstride;
#pragma unroll
  for (int i = 0; i < TM; ++i) {
    const int r = row0 + ty * TM + i;
    if (r >= Nr) continue;
    float* Crow = Cz + (size_t)r * ldc;
#pragma unroll
    for (int g = 0; g < TN / 4; ++g) {
      const int c = col0 + (TN == 8 ? g * (BN / 2) : 0) + tx * 4;
      if (c + 3 < M) {
        float4 v;
        v.x = acc[i][g * 4 + 0]; v.y = acc[i][g * 4 + 1];
        v.z = acc[i][g * 4 + 2]; v.w = acc[i][g * 4 + 3];
        if (bias) { v.x += bias[c]; v.y += bias[c + 1]; v.z += bias[c + 2]; v.w += bias[c + 3]; }
        if (do_relu) {
          v.x = fmaxf(v.x, 0.f); v.y = fmaxf(v.y, 0.f);
          v.z = fmaxf(v.z, 0.f); v.w = fmaxf(v.w, 0.f);
        }
        *(float4*)&Crow[c] = v;
      } else {
#pragma unroll
        for (int j = 0; j < 4; ++j) {
          if (c + j >= M) continue;
          float v = acc[i][g * 4 + j];
          if (bias) v += bias[c + j];
          if (do_relu) v = fmaxf(v, 0.f);
          Crow[c + j] = v;
        }
      }
    }
  }
}

// sum Sz split-K partials + bias (+relu), write with ldd
__global__ void bias_sum_kernel(const float* __restrict__ src, int zs, int Sz,
                                float* __restrict__ dst, int ldd,
                                const float* __restrict__ bias,
                                int Nr, int M, int do_relu) {
  int idx = blockIdx.x * blockDim.x + threadIdx.x;
  if (idx >= Nr * M) return;
  int r = idx / M, c = idx - r * M;
  float v = bias[c];
  for (int z = 0; z < Sz; ++z) v += src[idx + (size_t)z * zs];
  if (do_relu) v = fmaxf(v, 0.f);
  dst[(size_t)r * ldd + c] = v;
}

// ------------------------- graph prep -------------------------
__global__ void hist2_kernel(const int* __restrict__ e1, const int* __restrict__ e2,
                             int* __restrict__ cnt, int E, int npass) {
  int e = blockIdx.x * blockDim.x + threadIdx.x;
  if (e < E) atomicAdd(&cnt[e1[E + e]], 1);
  else if (e < npass * E) atomicAdd(&cnt[N_NODES + e2[E + e - E]], 1);
}

// ---- parallel exclusive scan over cnt (scan1 = per-1024-block; scan23 = fixup) ----
__launch_bounds__(1024)
__global__ void scan1_kernel(const int* __restrict__ cnt, int* __restrict__ row_ptr,
                             int* __restrict__ part, int n) {
  __shared__ int sh[1024];
  const int tid = threadIdx.x;
  const int i = blockIdx.x * 1024 + tid;
  const int v = (i < n) ? cnt[i] : 0;
  sh[tid] = v;
  __syncthreads();
#pragma unroll
  for (int off = 1; off < 1024; off <<= 1) {
    int t = (tid >= off) ? sh[tid - off] : 0;
    __syncthreads();
    sh[tid] += t;
    __syncthreads();
  }
  if (i < n) row_ptr[i] = sh[tid] - v;  // exclusive
  if (tid == 1023) part[blockIdx.x] = sh[tid];
}

// merged scan2+scan3: each 256-block lies in one 1024-part-block (256|1024), so
// thread 0 sums part[0 .. blockIdx.x>>2) serially (<40 adds), broadcast via LDS.
__global__ void scan23_kernel(const int* __restrict__ cnt, int* __restrict__ row_ptr,
                              const int* __restrict__ part, int* __restrict__ cursor,
                              float* __restrict__ dinv, int n, int total) {
  __shared__ int base_sh;
  const int tid = threadIdx.x;
  if (tid == 0) {
    int blk = blockIdx.x >> 2;
    int s = 0;
    for (int b = 0; b < blk; ++b) s += part[b];
    base_sh = s;
  }
  __syncthreads();
  int i = blockIdx.x * 256 + tid;
  if (i >= n) return;
  int rp = row_ptr[i] + base_sh;
  row_ptr[i] = rp;
  cursor[i] = rp;
  dinv[i] = rsqrtf((float)(cnt[i] + 1));
  if (i == 0) row_ptr[n] = total;
}

__global__ void scatter2_kernel(const int* __restrict__ e1, const int* __restrict__ e2,
                                int* __restrict__ cursor, int* __restrict__ col_idx,
                                int E, int npass) {
  int e = blockIdx.x * blockDim.x + threadIdx.x;
  if (e < E) {
    int p = atomicAdd(&cursor[e1[E + e]], 1);
    col_idx[p] = e1[e];
  } else if (e < npass * E) {
    int j = e - E;
    int p = atomicAdd(&cursor[N_NODES + e2[E + j]], 1);
    col_idx[p] = N_NODES + e2[j];
  }
}

// ------------ normalized aggregation, flat (node, vec-slot) threads ------------
// out = D^-1/2 (A+I) D^-1/2 x ; separate in/out leading dims (64B-padded rows).
__global__ void aggf2_flat(const float* __restrict__ h, const float* __restrict__ h2,
                           int nsplit, const int* __restrict__ row_ptr,
                           const int* __restrict__ col_idx, const float* __restrict__ dinv,
                           float* __restrict__ out, int in_ld, int out_ld,
                           int V, int total) {
  int gid = blockIdx.x * blockDim.x + threadIdx.x;
  if (gid >= total) return;
  int n = gid / V, v = gid - n * V;
  const float din = dinv[n];
  auto rowp = [&](int s) -> const float2* {
    const float* base = (s < nsplit) ? h + (size_t)s * in_ld
                                     : h2 + (size_t)(s - nsplit) * in_ld;
    return (const float2*)base;
  };
  float2 a;
  { float2 x = rowp(n)[v]; a.x = din * x.x; a.y = din * x.y; }
  const int beg = row_ptr[n], end = row_ptr[n + 1];
  int e = beg;
  for (; e + 3 < end; e += 4) {
    int s0 = col_idx[e], s1 = col_idx[e + 1], s2 = col_idx[e + 2], s3 = col_idx[e + 3];
    float d0 = dinv[s0], d1 = dinv[s1], d2 = dinv[s2], d3 = dinv[s3];
    float2 x0 = rowp(s0)[v], x1 = rowp(s1)[v], x2 = rowp(s2)[v], x3 = rowp(s3)[v];
    a.x += d0 * x0.x + d1 * x1.x + d2 * x2.x + d3 * x3.x;
    a.y += d0 * x0.y + d1 * x1.y + d2 * x2.y + d3 * x3.y;
  }
  for (; e < end; ++e) {
    int s0 = col_idx[e];
    float d0 = dinv[s0];
    float2 x0 = rowp(s0)[v];
    a.x += d0 * x0.x; a.y += d0 * x0.y;
  }
  float2 o; o.x = din * a.x; o.y = din * a.y;
  ((float2*)(out + (size_t)n * out_ld))[v] = o;
}

__global__ void aggf4_flat(const float* __restrict__ h, const int* __restrict__ row_ptr,
                           const int* __restrict__ col_idx, const float* __restrict__ dinv,
                           float* __restrict__ out, int in_ld, int out_ld,
                           int V, int total) {
  int gid = blockIdx.x * blockDim.x + threadIdx.x;
  if (gid >= total) return;
  int n = gid / V, v = gid - n * V;
  const float din = dinv[n];
  const int ivs = in_ld >> 2;
  const float4* hv = (const float4*)h;
  float4 a;
  {
    float4 x = hv[(size_t)n * ivs + v];
    a.x = din * x.x; a.y = din * x.y; a.z = din * x.z; a.w = din * x.w;
  }
  const int beg = row_ptr[n], end = row_ptr[n + 1];
  int e = beg;
  for (; e + 3 < end; e += 4) {
    int s0 = col_idx[e], s1 = col_idx[e + 1], s2 = col_idx[e + 2], s3 = col_idx[e + 3];
    float d0 = dinv[s0], d1 = dinv[s1], d2 = dinv[s2], d3 = dinv[s3];
    float4 x0 = hv[(size_t)s0 * ivs + v], x1 = hv[(size_t)s1 * ivs + v];
    float4 x2 = hv[(size_t)s2 * ivs + v], x3 = hv[(size_t)s3 * ivs + v];
    a.x += d0 * x0.x + d1 * x1.x + d2 * x2.x + d3 * x3.x;
    a.y += d0 * x0.y + d1 * x1.y + d2 * x2.y + d3 * x3.y;
    a.z += d0 * x0.z + d1 * x1.z + d2 * x2.z + d3 * x3.z;
    a.w += d0 * x0.w + d1 * x1.w + d2 * x2.w + d3 * x3.w;
  }
  for (; e < end; ++e) {
    int s0 = col_idx[e];
    float d0 = dinv[s0];
    float4 x0 = hv[(size_t)s0 * ivs + v];
    a.x += d0 * x0.x; a.y += d0 * x0.y; a.z += d0 * x0.z; a.w += d0 * x0.w;
  }
  float4 o;
  o.x = din * a.x; o.y = din * a.y; o.z = din * a.z; o.w = din * a.w;
  ((float4*)(out + (size_t)n * out_ld))[v] = o;
}

__global__ void starts2_kernel(const int* __restrict__ b1, const int* __restrict__ b2,
                               int* __restrict__ s1, int* __restrict__ s2, int n, int npass) {
  int i = blockIdx.x * blockDim.x + threadIdx.x;
  if (i < n) {
    if (i == 0) { s1[0] = 0; s1[N_GRAPH] = n; }
    else if (b1[i] != b1[i - 1]) s1[b1[i]] = i;
  } else if (i < npass * n) {
    int j = i - n;
    if (j == 0) { s2[0] = n; s2[N_GRAPH] = 2 * n; }
    else if (b2[j] != b2[j - 1]) s2[b2[j]] = n + j;
  }
}

// ---- two-stage max pool: part (NC interleaved node-chunks/graph) + combine ----
// thread = (graph, chunk, float4-slot); post-ReLU inputs >= 0 so identity is 0.
__global__ void pool_part_kernel(const float* __restrict__ x, int xld,
                                 const int* __restrict__ s1, const int* __restrict__ s2,
                                 float* __restrict__ part, int V, int total) {
  int gid = blockIdx.x * blockDim.x + threadIdx.x;
  if (gid >= total) return;
  int v = gid % V;
  int gc = gid / V;                 // g * POOL_NC + c
  int g = gc / POOL_NC, c = gc - g * POOL_NC;
  const int* st = (g < N_GRAPH) ? s1 : s2;
  int gi = g & (N_GRAPH - 1);
  int beg = st[gi], end = st[gi + 1];
  float4 m0 = make_float4(0.f, 0.f, 0.f, 0.f);
  float4 m1 = make_float4(0.f, 0.f, 0.f, 0.f);
  int nn = beg + c;
  for (; nn + POOL_NC < end; nn += 2 * POOL_NC) {
    float4 a = ((const float4*)(x + (size_t)nn * xld))[v];
    float4 b = ((const float4*)(x + (size_t)(nn + POOL_NC) * xld))[v];
    m0.x = fmaxf(m0.x, a.x); m0.y = fmaxf(m0.y, a.y);
    m0.z = fmaxf(m0.z, a.z); m0.w = fmaxf(m0.w, a.w);
    m1.x = fmaxf(m1.x, b.x); m1.y = fmaxf(m1.y, b.y);
    m1.z = fmaxf(m1.z, b.z); m1.w = fmaxf(m1.w, b.w);
  }
  if (nn < end) {
    float4 a = ((const float4*)(x + (size_t)nn * xld))[v];
    m0.x = fmaxf(m0.x, a.x); m0.y = fmaxf(m0.y, a.y);
    m0.z = fmaxf(m0.z, a.z); m0.w = fmaxf(m0.w, a.w);
  }
  float4 m;
  m.x = fmaxf(m0.x, m1.x); m.y = fmaxf(m0.y, m1.y);
  m.z = fmaxf(m0.z, m1.z); m.w = fmaxf(m0.w, m1.w);
  ((float4*)(part + (size_t)gc * (V * 4)))[v] = m;
}

__global__ void pool_combine_kernel(const float* __restrict__ part,
                                    float* __restrict__ pooled, int V, int total,
                                    int pool_base) {
  int gid = blockIdx.x * blockDim.x + threadIdx.x;
  if (gid >= total) return;
  int v = gid % V, g = gid / V;
  float4 m = make_float4(0.f, 0.f, 0.f, 0.f);
#pragma unroll
  for (int c = 0; c < POOL_NC; ++c) {
    float4 a = ((const float4*)(part + (size_t)(g * POOL_NC + c) * (V * 4)))[v];
    m.x = fmaxf(m.x, a.x); m.y = fmaxf(m.y, a.y);
    m.z = fmaxf(m.z, a.z); m.w = fmaxf(m.w, a.w);
  }
  ((float4*)(pooled + (size_t)(pool_base + g) * (V * 4)))[v] = m;
}

__global__ void rownorm_kernel(const float* __restrict__ cell, float* __restrict__ cv,
                               int F, int out_ld) {
  int g = blockIdx.x;
  __shared__ float red[256];
  int tid = threadIdx.x;
  const float* row = cell + (size_t)g * F;
  float s = 0.f;
  for (int f = tid; f < F; f += 256) { float v = row[f]; s += v * v; }
  red[tid] = s;
  __syncthreads();
  for (int off = 128; off > 0; off >>= 1) {
    if (tid < off) red[tid] += red[tid + off];
    __syncthreads();
  }
  float inv = 1.f / fmaxf(sqrtf(red[0]), 1e-12f);
  float* orow = cv + (size_t)g * out_ld;
  for (int f = tid; f < F; f += 256) orow[f] = row[f] * inv;
  for (int f = F + tid; f < out_ld; f += 256) orow[f] = 0.f;
}

// ------------------------- launcher -------------------------
extern "C" void kernel_launch(void* const* d_in, const int* in_sizes, int n_in,
                              void* d_out, int out_size, void* d_ws, size_t ws_size,
                              hipStream_t stream) {
  (void)in_sizes; (void)n_in; (void)out_size;
  const float* x1  = (const float*)d_in[0];
  const int*   ei1 = (const int*)d_in[1];
  const int*   bt1 = (const int*)d_in[2];
  const float* x2  = (const float*)d_in[3];
  const int*   ei2 = (const int*)d_in[4];
  const int*   bt2 = (const int*)d_in[5];
  const float* cell = (const float*)d_in[6];
  const float* Wc1 = (const float*)d_in[7];  const float* bc1 = (const float*)d_in[8];
  const float* Wc2 = (const float*)d_in[9];  const float* bc2 = (const float*)d_in[10];
  const float* Wc3 = (const float*)d_in[11]; const float* bc3 = (const float*)d_in[12];
  const float* Wg1 = (const float*)d_in[13]; const float* bg1 = (const float*)d_in[14];
  const float* Wg2 = (const float*)d_in[15]; const float* bg2 = (const float*)d_in[16];
  const float* Wr1 = (const float*)d_in[17]; const float* br1 = (const float*)d_in[18];
  const float* Wr2 = (const float*)d_in[19]; const float* br2 = (const float*)d_in[20];
  const float* Wr3 = (const float*)d_in[21]; const float* br3 = (const float*)d_in[22];
  const float* Wf1 = (const float*)d_in[23]; const float* bf1 = (const float*)d_in[24];
  const float* Wf2 = (const float*)d_in[25]; const float* bf2 = (const float*)d_in[26];
  const float* Wf3 = (const float*)d_in[27]; const float* bf3 = (const float*)d_in[28];
  const float* Wo  = (const float*)d_in[29]; const float* bo  = (const float*)d_in[30];
  float* out = (float*)d_out;

  const bool batched = ws_size >= (size_t)95 * 1024 * 1024;
  const int NPASS = batched ? 2 : 1;
  const int NN = NPASS * N_NODES;

  char* ws = (char*)d_ws;
  size_t off = 0;
  auto alloc_f = [&](size_t ne) { float* p = (float*)(ws + off); off += ne * 4; return p; };
  auto alloc_i = [&](size_t ne) { int* p = (int*)(ws + off); off += ne * 4; return p; };
  float* xbuf   = alloc_f((size_t)NN * 320);   // activations (64B-padded rows)
  float* abuf   = alloc_f((size_t)NN * 160);   // aggregated input (64B-padded rows)
  float* dinv   = alloc_f(NN);
  float* pooled = alloc_f((size_t)512 * 312);
  float* ppart  = alloc_f((size_t)512 * POOL_NC * 312);
  float* cvbuf  = alloc_f((size_t)N_GRAPH * 960);
  float* gtmp1  = alloc_f((size_t)512 * 2048);
  float* gtmp2  = alloc_f((size_t)512 * 512);
  float* gtmp3  = alloc_f((size_t)N_GRAPH * 256);
  float* catbuf = alloc_f((size_t)N_GRAPH * 512);
  int* cnt     = alloc_i(NN);
  int* row_ptr = alloc_i(NN + 1);
  int* cursor  = alloc_i(NN);
  int* col_idx = alloc_i(NPASS * N_EDGES);
  int* part    = alloc_i(64);
  int* start1  = alloc_i(N_GRAPH + 1);
  int* start2  = alloc_i(N_GRAPH + 1);
  float* accb  = xbuf;  // split-K partials (MLP runs after pooling; xbuf free then)

  auto gemm_med = [&](const float* A, int lda, const float* B, int ldb, float* C, int ldc,
                      const float* bias, int Nr, int K, int M, int relu) {
    dim3 grid((M + 63) / 64, (Nr + 127) / 128, 1);
    gemm_t<128, 64, 8, 4><<<grid, 256, 0, stream>>>(A, lda, B, ldb, C, ldc, 0, bias,
                                                    Nr, K, M, relu, K);
  };
  auto gemm_small = [&](const float* A, int lda, const float* B, int ldb, float* C, int ldc,
                        const float* bias, int Nr, int K, int M, int relu) {
    dim3 grid((M + 63) / 64, (Nr + 63) / 64, 1);
    gemm_t<64, 64, 4, 4><<<grid, 256, 0, stream>>>(A, lda, B, ldb, C, ldc, 0, bias,
                                                   Nr, K, M, relu, K);
  };
  // split-K layer: partial stores per z-slice + summing bias/act pass
  auto splitk = [&](const float* A, int lda, const float* B, int M_, int K_, int S,
                    const float* bias, float* dst, int ldd, int relu, int Nr) {
    int kchunk = (((K_ + S - 1) / S) + 15) / 16 * 16;
    int Sz = (K_ + kchunk - 1) / kchunk;
    dim3 grid((M_ + 63) / 64, (Nr + 63) / 64, Sz);
    gemm_t<64, 64, 4, 4><<<grid, 256, 0, stream>>>(A, lda, B, M_, accb, M_, Nr * M_,
                                                   nullptr, Nr, K_, M_, 0, kchunk);
    int tot = Nr * M_;
    bias_sum_kernel<<<(tot + 255) / 256, 256, 0, stream>>>(accb, Nr * M_, Sz, dst, ldd,
                                                           bias, Nr, M_, relu);
  };

  auto drug_pass = [&](const float* xa, const float* xb, const int* eia, const int* eib,
                       const int* bta, const int* btb, int npass, int pool_base) {
    const int nn = npass * N_NODES;
    const int te = npass * N_EDGES;
    const int nb = (nn + 1023) / 1024;
    hipMemsetAsync(cnt, 0, nn * sizeof(int), stream);
    hist2_kernel<<<(te + 255) / 256, 256, 0, stream>>>(eia, eib, cnt, N_EDGES, npass);
    scan1_kernel<<<nb, 1024, 0, stream>>>(cnt, row_ptr, part, nn);
    scan23_kernel<<<(nn + 255) / 256, 256, 0, stream>>>(cnt, row_ptr, part, cursor, dinv, nn, te);
    scatter2_kernel<<<(te + 255) / 256, 256, 0, stream>>>(eia, eib, cursor, col_idx, N_EDGES, npass);
    // layer 1: agg(78, dual-source raw x, ld 78) -> abuf ld 80 -> GEMM 78->78 (out ld 80)
    {
      int tot = nn * 39;
      aggf2_flat<<<(tot + 255) / 256, 256, 0, stream>>>(xa, xb, N_NODES, row_ptr, col_idx,
                                                        dinv, abuf, 78, 80, 39, tot);
    }
    gemm_med(abuf, 80, Wc1, 78, xbuf, 80, bc1, nn, 78, 78, 1);
    // layer 2: agg(78, ld 80) -> abuf ld 80 -> GEMM 78->156 (out ld 160)
    {
      int tot = nn * 39;
      aggf2_flat<<<(tot + 255) / 256, 256, 0, stream>>>(xbuf, xbuf, nn, row_ptr, col_idx,
                                                        dinv, abuf, 80, 80, 39, tot);
    }
    gemm_med(abuf, 80, Wc2, 156, xbuf, 160, bc2, nn, 78, 156, 1);
    // layer 3: agg(156, ld 160) -> abuf ld 160 -> GEMM 156->312 (out ld 320, BN=64 tile)
    {
      int tot = nn * 39;
      aggf4_flat<<<(tot + 255) / 256, 256, 0, stream>>>(xbuf, row_ptr, col_idx,
                                                        dinv, abuf, 160, 160, 39, tot);
    }
    gemm_med(abuf, 160, Wc3, 312, xbuf, 320, bc3, nn, 156, 312, 1);
    // two-stage pool (V = 312/4 = 78 float4 slots)
    starts2_kernel<<<(nn + 255) / 256, 256, 0, stream>>>(bta, btb, start1, start2, N_NODES, npass);
    {
      int totp = npass * N_GRAPH * POOL_NC * 78;
      pool_part_kernel<<<(totp + 255) / 256, 256, 0, stream>>>(xbuf, 320, start1, start2,
                                                               ppart, 78, totp);
      int totc = npass * N_GRAPH * 78;
      pool_combine_kernel<<<(totc + 255) / 256, 256, 0, stream>>>(ppart, pooled, 78, totc,
                                                                  pool_base);
    }
  };

  if (batched) {
    drug_pass(x1, x2, ei1, ei2, bt1, bt2, 2, 0);
  } else {
    drug_pass(x1, x1, ei1, ei1, bt1, bt1, 1, 0);
    drug_pass(x2, x2, ei2, ei2, bt2, bt2, 1, N_GRAPH);
  }

  // drug head on both branches at once (512 rows; shared weights), split-K for
  // block-count; Wg2 outputs written straight into catbuf halves.
  splitk(pooled, 312, Wg1, 156, 312, 4, bg1, gtmp1, 156, 1, 2 * N_GRAPH);
  splitk(gtmp1, 156, Wg2, 128, 156, 2, bg2, catbuf, 512, 0, N_GRAPH);
  splitk(gtmp1 + (size_t)N_GRAPH * 156, 156, Wg2, 128, 156, 2, bg2, catbuf + 128, 512, 0,
         N_GRAPH);

  // cell branch + head MLP (256-row deep-K layers via split-K)
  rownorm_kernel<<<N_GRAPH, 256, 0, stream>>>(cell, cvbuf, 954, 960);
  splitk(cvbuf, 960, Wr1, 2048, 954, 8,   br1, gtmp1, 2048, 1, N_GRAPH);
  splitk(gtmp1, 2048, Wr2, 512, 2048, 32, br2, gtmp2, 512, 1, N_GRAPH);
  splitk(gtmp2, 512, Wr3, 256, 512, 16,   br3, catbuf + 256, 512, 1, N_GRAPH);
  splitk(catbuf, 512, Wf1, 1024, 512, 16, bf1, gtmp1, 1024, 1, N_GRAPH);
  splitk(gtmp1, 1024, Wf2, 512, 1024, 32, bf2, gtmp2, 512, 1, N_GRAPH);
  splitk(gtmp2, 512, Wf3, 128, 512, 32,   bf3, gtmp3, 128, 1, N_GRAPH);
  gemm_small(gtmp3, 128, Wo, 2, out, 2, bo, N_GRAPH, 128, 2, 0);
}

// Round 12
// 576.746 us; speedup vs baseline: 1.2533x; 1.0251x over previous
//
#include <hip/hip_runtime.h>

#define N_NODES 20000
#define N_EDGES 320000
#define N_GRAPH 256
#define POOL_NC 8

// ------------------------- templated tiled fp32 GEMM -------------------------
// zstride==0: direct C = op(A@B + bias). zstride>0 (split-K): block z plain-stores
// its partial to C + z*zstride (summed later by bias_sum_kernel).
// A-tile k-major in LDS; B-fragment split in two stride-4 groups (2-way = free).
// STRUCTURE IS MEASUREMENT-PINNED (do not change without re-measuring):
//   BK=16, single LDS buffer, register prefetch of tile k+1 -> VGPR 60-100.
//   LDS double-buffer: VGPR 188, occ 10%, 135us (R6). BK=32: VGPR 148, 111us (R8).
//   Wc3 on BN=64 tile (1565 blocks) beats BN=128 (939 blocks): R10/R11.
// swz!=0: 1D-grid XCD-aware swizzle — all column-tiles of a row-slab map to the
//   same XCD (lin&7) so the A row-panel is fetched into ONE per-XCD L2, not 5.
template<int BM, int BN, int TM, int TN>
__launch_bounds__(256)
__global__ void gemm_t(const float* __restrict__ A, int lda,
                       const float* __restrict__ B, int ldb,
                       float* __restrict__ C, int ldc, int zstride,
                       const float* __restrict__ bias,
                       int Nr, int K, int M, int do_relu, int kchunk, int swz) {
  constexpr int BK = 16;
  constexpr int LDA = BM + 4;
  __shared__ __align__(16) float As[BK][LDA];
  __shared__ __align__(16) float Bs[BK][BN];
  const int tid = threadIdx.x;
  int bx, by;
  if (swz) {
    const int C = (M + BN - 1) / BN;
    const int R = (Nr + BM - 1) / BM;
    const int RR = (R + 7) >> 3;
    const int x = blockIdx.x & 7, g = blockIdx.x >> 3;
    const int q = g / C;
    by = x * RR + q;
    bx = g - q * C;
    if (by >= R) return;
  } else {
    bx = blockIdx.x; by = blockIdx.y;
  }
  const int row0 = by * BM, col0 = bx * BN;
  constexpr int NX = BN / TN;
  const int tx = tid % NX, ty = tid / NX;
  float acc[TM][TN] = {};
  const int klo = blockIdx.z * kchunk;
  const int khi = min(klo + kchunk, K);

  constexpr int AIT = BM * BK / 4 / 256;
  constexpr int BIT = BK * BN / 4 / 256;
  float4 pa[AIT], pb[BIT];

  auto load_tile = [&](int k0) {
#pragma unroll
    for (int it = 0; it < AIT; ++it) {
      const int s = it * 256 + tid;
      const int row = s >> 2, kq = (s & 3) << 2;
      float4 av = make_float4(0.f, 0.f, 0.f, 0.f);
      const int gr = row0 + row, gk = k0 + kq;
      if (gr < Nr) {
        const float* Ap = A + (size_t)gr * lda + gk;
        if (gk + 3 < khi) { av.x = Ap[0]; av.y = Ap[1]; av.z = Ap[2]; av.w = Ap[3]; }
        else {
          if (gk     < khi) av.x = Ap[0];
          if (gk + 1 < khi) av.y = Ap[1];
          if (gk + 2 < khi) av.z = Ap[2];
        }
      }
      pa[it] = av;
    }
#pragma unroll
    for (int it = 0; it < BIT; ++it) {
      const int s = it * 256 + tid;
      const int kr = s / (BN / 4), c = (s % (BN / 4)) << 2;
      float4 bv = make_float4(0.f, 0.f, 0.f, 0.f);
      const int gk = k0 + kr, gc = col0 + c;
      if (gk < khi) {
        const float* Bp = B + (size_t)gk * ldb + gc;
        if (gc + 3 < M) { bv.x = Bp[0]; bv.y = Bp[1]; bv.z = Bp[2]; bv.w = Bp[3]; }
        else {
          if (gc     < M) bv.x = Bp[0];
          if (gc + 1 < M) bv.y = Bp[1];
          if (gc + 2 < M) bv.z = Bp[2];
        }
      }
      pb[it] = bv;
    }
  };

  load_tile(klo);
  for (int k0 = klo; k0 < khi; k0 += BK) {
#pragma unroll
    for (int it = 0; it < AIT; ++it) {
      const int s = it * 256 + tid;
      const int row = s >> 2, kq = (s & 3) << 2;
      As[kq    ][row] = pa[it].x;
      As[kq + 1][row] = pa[it].y;
      As[kq + 2][row] = pa[it].z;
      As[kq + 3][row] = pa[it].w;
    }
#pragma unroll
    for (int it = 0; it < BIT; ++it) {
      const int s = it * 256 + tid;
      const int kr = s / (BN / 4), c = (s % (BN / 4)) << 2;
      *(float4*)&Bs[kr][c] = pb[it];
    }
    __syncthreads();
    if (k0 + BK < khi) load_tile(k0 + BK);  // overlap next-tile fetch with compute
#pragma unroll
    for (int kk = 0; kk < BK; ++kk) {
      float ar[TM], br[TN];
#pragma unroll
      for (int i = 0; i < TM; i += 4)
        *(float4*)&ar[i] = *(const float4*)&As[kk][ty * TM + i];
      if constexpr (TN == 8) {
        *(float4*)&br[0] = *(const float4*)&Bs[kk][tx * 4];
        *(float4*)&br[4] = *(const float4*)&Bs[kk][BN / 2 + tx * 4];
      } else {
        *(float4*)&br[0] = *(const float4*)&Bs[kk][tx * TN];
      }
#pragma unroll
      for (int i = 0; i < TM; ++i)
#pragma unroll
        for (int j = 0; j < TN; ++j)
          acc[i][j] += ar[i] * br[j];
    }
    __syncthreads();
  }

  float* Cz = C + (size_t)blockIdx.z * zstride;
#pragma unroll
  for (int i = 0; i < TM; ++i) {
    const int r = row0 + ty * TM + i;
    if (r >= Nr) continue;
    float* Crow = Cz + (size_t)r * ldc;
#pragma unroll
    for (int g = 0; g < TN / 4; ++g) {
      const int c = col0 + (TN == 8 ? g * (BN / 2) : 0) + tx * 4;
      if (c + 3 < M) {
        float4 v;
        v.x = acc[i][g * 4 + 0]; v.y = acc[i][g * 4 + 1];
        v.z = acc[i][g * 4 + 2]; v.w = acc[i][g * 4 + 3];
        if (bias) { v.x += bias[c]; v.y += bias[c + 1]; v.z += bias[c + 2]; v.w += bias[c + 3]; }
        if (do_relu) {
          v.x = fmaxf(v.x, 0.f); v.y = fmaxf(v.y, 0.f);
          v.z = fmaxf(v.z, 0.f); v.w = fmaxf(v.w, 0.f);
        }
        *(float4*)&Crow[c] = v;
      } else {
#pragma unroll
        for (int j = 0; j < 4; ++j) {
          if (c + j >= M) continue;
          float v = acc[i][g * 4 + j];
          if (bias) v += bias[c + j];
          if (do_relu) v = fmaxf(v, 0.f);
          Crow[c + j] = v;
        }
      }
    }
  }
}

// sum Sz split-K partials + bias (+relu), write with ldd
__global__ void bias_sum_kernel(const float* __restrict__ src, int zs, int Sz,
                                float* __restrict__ dst, int ldd,
                                const float* __restrict__ bias,
                                int Nr, int M, int do_relu) {
  int idx = blockIdx.x * blockDim.x + threadIdx.x;
  if (idx >= Nr * M) return;
  int r = idx / M, c = idx - r * M;
  float v = bias[c];
  for (int z = 0; z < Sz; ++z) v += src[idx + (size_t)z * zs];
  if (do_relu) v = fmaxf(v, 0.f);
  dst[(size_t)r * ldd + c] = v;
}

// ------------------------- graph prep -------------------------
__global__ void hist2_kernel(const int* __restrict__ e1, const int* __restrict__ e2,
                             int* __restrict__ cnt, int E, int npass) {
  int e = blockIdx.x * blockDim.x + threadIdx.x;
  if (e < E) atomicAdd(&cnt[e1[E + e]], 1);
  else if (e < npass * E) atomicAdd(&cnt[N_NODES + e2[E + e - E]], 1);
}

// ---- parallel exclusive scan over cnt (scan1 = per-1024-block; scan23 = fixup) ----
__launch_bounds__(1024)
__global__ void scan1_kernel(const int* __restrict__ cnt, int* __restrict__ row_ptr,
                             int* __restrict__ part, int n) {
  __shared__ int sh[1024];
  const int tid = threadIdx.x;
  const int i = blockIdx.x * 1024 + tid;
  const int v = (i < n) ? cnt[i] : 0;
  sh[tid] = v;
  __syncthreads();
#pragma unroll
  for (int off = 1; off < 1024; off <<= 1) {
    int t = (tid >= off) ? sh[tid - off] : 0;
    __syncthreads();
    sh[tid] += t;
    __syncthreads();
  }
  if (i < n) row_ptr[i] = sh[tid] - v;  // exclusive
  if (tid == 1023) part[blockIdx.x] = sh[tid];
}

// merged scan2+scan3+starts: fixup scan, init cursor/dinv, find graph starts.
__global__ void scan23_kernel(const int* __restrict__ cnt, int* __restrict__ row_ptr,
                              const int* __restrict__ part, int* __restrict__ cursor,
                              float* __restrict__ dinv, int n, int total,
                              const int* __restrict__ b1, const int* __restrict__ b2,
                              int* __restrict__ s1, int* __restrict__ s2) {
  __shared__ int base_sh;
  const int tid = threadIdx.x;
  if (tid == 0) {
    int blk = blockIdx.x >> 2;
    int s = 0;
    for (int b = 0; b < blk; ++b) s += part[b];
    base_sh = s;
  }
  __syncthreads();
  int i = blockIdx.x * 256 + tid;
  if (i >= n) return;
  int rp = row_ptr[i] + base_sh;
  row_ptr[i] = rp;
  cursor[i] = rp;
  dinv[i] = rsqrtf((float)(cnt[i] + 1));
  if (i == 0) row_ptr[n] = total;
  // graph starts (batch arrays are sorted)
  if (i < N_NODES) {
    if (i == 0) { s1[0] = 0; s1[N_GRAPH] = N_NODES; }
    else if (b1[i] != b1[i - 1]) s1[b1[i]] = i;
  } else {
    int j = i - N_NODES;
    if (j == 0) { s2[0] = N_NODES; s2[N_GRAPH] = 2 * N_NODES; }
    else if (b2[j] != b2[j - 1]) s2[b2[j]] = N_NODES + j;
  }
}

__global__ void scatter2_kernel(const int* __restrict__ e1, const int* __restrict__ e2,
                                int* __restrict__ cursor, int* __restrict__ col_idx,
                                int E, int npass) {
  int e = blockIdx.x * blockDim.x + threadIdx.x;
  if (e < E) {
    int p = atomicAdd(&cursor[e1[E + e]], 1);
    col_idx[p] = e1[e];
  } else if (e < npass * E) {
    int j = e - E;
    int p = atomicAdd(&cursor[N_NODES + e2[E + j]], 1);
    col_idx[p] = N_NODES + e2[j];
  }
}

// ------------ normalized aggregation, flat (node, vec-slot) threads ------------
// out = D^-1/2 (A+I) D^-1/2 x ; separate in/out leading dims (64B-padded rows).
__global__ void aggf2_flat(const float* __restrict__ h, const float* __restrict__ h2,
                           int nsplit, const int* __restrict__ row_ptr,
                           const int* __restrict__ col_idx, const float* __restrict__ dinv,
                           float* __restrict__ out, int in_ld, int out_ld,
                           int V, int total) {
  int gid = blockIdx.x * blockDim.x + threadIdx.x;
  if (gid >= total) return;
  int n = gid / V, v = gid - n * V;
  const float din = dinv[n];
  auto rowp = [&](int s) -> const float2* {
    const float* base = (s < nsplit) ? h + (size_t)s * in_ld
                                     : h2 + (size_t)(s - nsplit) * in_ld;
    return (const float2*)base;
  };
  float2 a;
  { float2 x = rowp(n)[v]; a.x = din * x.x; a.y = din * x.y; }
  const int beg = row_ptr[n], end = row_ptr[n + 1];
  int e = beg;
  for (; e + 3 < end; e += 4) {
    int s0 = col_idx[e], s1 = col_idx[e + 1], s2 = col_idx[e + 2], s3 = col_idx[e + 3];
    float d0 = dinv[s0], d1 = dinv[s1], d2 = dinv[s2], d3 = dinv[s3];
    float2 x0 = rowp(s0)[v], x1 = rowp(s1)[v], x2 = rowp(s2)[v], x3 = rowp(s3)[v];
    a.x += d0 * x0.x + d1 * x1.x + d2 * x2.x + d3 * x3.x;
    a.y += d0 * x0.y + d1 * x1.y + d2 * x2.y + d3 * x3.y;
  }
  for (; e < end; ++e) {
    int s0 = col_idx[e];
    float d0 = dinv[s0];
    float2 x0 = rowp(s0)[v];
    a.x += d0 * x0.x; a.y += d0 * x0.y;
  }
  float2 o; o.x = din * a.x; o.y = din * a.y;
  ((float2*)(out + (size_t)n * out_ld))[v] = o;
}

__global__ void aggf4_flat(const float* __restrict__ h, const int* __restrict__ row_ptr,
                           const int* __restrict__ col_idx, const float* __restrict__ dinv,
                           float* __restrict__ out, int in_ld, int out_ld,
                           int V, int total) {
  int gid = blockIdx.x * blockDim.x + threadIdx.x;
  if (gid >= total) return;
  int n = gid / V, v = gid - n * V;
  const float din = dinv[n];
  const int ivs = in_ld >> 2;
  const float4* hv = (const float4*)h;
  float4 a;
  {
    float4 x = hv[(size_t)n * ivs + v];
    a.x = din * x.x; a.y = din * x.y; a.z = din * x.z; a.w = din * x.w;
  }
  const int beg = row_ptr[n], end = row_ptr[n + 1];
  int e = beg;
  for (; e + 3 < end; e += 4) {
    int s0 = col_idx[e], s1 = col_idx[e + 1], s2 = col_idx[e + 2], s3 = col_idx[e + 3];
    float d0 = dinv[s0], d1 = dinv[s1], d2 = dinv[s2], d3 = dinv[s3];
    float4 x0 = hv[(size_t)s0 * ivs + v], x1 = hv[(size_t)s1 * ivs + v];
    float4 x2 = hv[(size_t)s2 * ivs + v], x3 = hv[(size_t)s3 * ivs + v];
    a.x += d0 * x0.x + d1 * x1.x + d2 * x2.x + d3 * x3.x;
    a.y += d0 * x0.y + d1 * x1.y + d2 * x2.y + d3 * x3.y;
    a.z += d0 * x0.z + d1 * x1.z + d2 * x2.z + d3 * x3.z;
    a.w += d0 * x0.w + d1 * x1.w + d2 * x2.w + d3 * x3.w;
  }
  for (; e < end; ++e) {
    int s0 = col_idx[e];
    float d0 = dinv[s0];
    float4 x0 = hv[(size_t)s0 * ivs + v];
    a.x += d0 * x0.x; a.y += d0 * x0.y; a.z += d0 * x0.z; a.w += d0 * x0.w;
  }
  float4 o;
  o.x = din * a.x; o.y = din * a.y; o.z = din * a.z; o.w = din * a.w;
  ((float4*)(out + (size_t)n * out_ld))[v] = o;
}

__global__ void starts2_kernel(const int* __restrict__ b1, const int* __restrict__ b2,
                               int* __restrict__ s1, int* __restrict__ s2, int n, int npass) {
  int i = blockIdx.x * blockDim.x + threadIdx.x;
  if (i < n) {
    if (i == 0) { s1[0] = 0; s1[N_GRAPH] = n; }
    else if (b1[i] != b1[i - 1]) s1[b1[i]] = i;
  } else if (i < npass * n) {
    int j = i - n;
    if (j == 0) { s2[0] = n; s2[N_GRAPH] = 2 * n; }
    else if (b2[j] != b2[j - 1]) s2[b2[j]] = n + j;
  }
}

// ---- two-stage max pool: part (NC interleaved node-chunks/graph) + combine ----
__global__ void pool_part_kernel(const float* __restrict__ x, int xld,
                                 const int* __restrict__ s1, const int* __restrict__ s2,
                                 float* __restrict__ part, int V, int total) {
  int gid = blockIdx.x * blockDim.x + threadIdx.x;
  if (gid >= total) return;
  int v = gid % V;
  int gc = gid / V;                 // g * POOL_NC + c
  int g = gc / POOL_NC, c = gc - g * POOL_NC;
  const int* st = (g < N_GRAPH) ? s1 : s2;
  int gi = g & (N_GRAPH - 1);
  int beg = st[gi], end = st[gi + 1];
  float4 m0 = make_float4(0.f, 0.f, 0.f, 0.f);
  float4 m1 = make_float4(0.f, 0.f, 0.f, 0.f);
  int nn = beg + c;
  for (; nn + POOL_NC < end; nn += 2 * POOL_NC) {
    float4 a = ((const float4*)(x + (size_t)nn * xld))[v];
    float4 b = ((const float4*)(x + (size_t)(nn + POOL_NC) * xld))[v];
    m0.x = fmaxf(m0.x, a.x); m0.y = fmaxf(m0.y, a.y);
    m0.z = fmaxf(m0.z, a.z); m0.w = fmaxf(m0.w, a.w);
    m1.x = fmaxf(m1.x, b.x); m1.y = fmaxf(m1.y, b.y);
    m1.z = fmaxf(m1.z, b.z); m1.w = fmaxf(m1.w, b.w);
  }
  if (nn < end) {
    float4 a = ((const float4*)(x + (size_t)nn * xld))[v];
    m0.x = fmaxf(m0.x, a.x); m0.y = fmaxf(m0.y, a.y);
    m0.z = fmaxf(m0.z, a.z); m0.w = fmaxf(m0.w, a.w);
  }
  float4 m;
  m.x = fmaxf(m0.x, m1.x); m.y = fmaxf(m0.y, m1.y);
  m.z = fmaxf(m0.z, m1.z); m.w = fmaxf(m0.w, m1.w);
  ((float4*)(part + (size_t)gc * (V * 4)))[v] = m;
}

__global__ void pool_combine_kernel(const float* __restrict__ part,
                                    float* __restrict__ pooled, int V, int total,
                                    int pool_base) {
  int gid = blockIdx.x * blockDim.x + threadIdx.x;
  if (gid >= total) return;
  int v = gid % V, g = gid / V;
  float4 m = make_float4(0.f, 0.f, 0.f, 0.f);
#pragma unroll
  for (int c = 0; c < POOL_NC; ++c) {
    float4 a = ((const float4*)(part + (size_t)(g * POOL_NC + c) * (V * 4)))[v];
    m.x = fmaxf(m.x, a.x); m.y = fmaxf(m.y, a.y);
    m.z = fmaxf(m.z, a.z); m.w = fmaxf(m.w, a.w);
  }
  ((float4*)(pooled + (size_t)(pool_base + g) * (V * 4)))[v] = m;
}

__global__ void rownorm_kernel(const float* __restrict__ cell, float* __restrict__ cv,
                               int F, int out_ld) {
  int g = blockIdx.x;
  __shared__ float red[256];
  int tid = threadIdx.x;
  const float* row = cell + (size_t)g * F;
  float s = 0.f;
  for (int f = tid; f < F; f += 256) { float v = row[f]; s += v * v; }
  red[tid] = s;
  __syncthreads();
  for (int off = 128; off > 0; off >>= 1) {
    if (tid < off) red[tid] += red[tid + off];
    __syncthreads();
  }
  float inv = 1.f / fmaxf(sqrtf(red[0]), 1e-12f);
  float* orow = cv + (size_t)g * out_ld;
  for (int f = tid; f < F; f += 256) orow[f] = row[f] * inv;
  for (int f = F + tid; f < out_ld; f += 256) orow[f] = 0.f;
}

// ------------------------- launcher -------------------------
extern "C" void kernel_launch(void* const* d_in, const int* in_sizes, int n_in,
                              void* d_out, int out_size, void* d_ws, size_t ws_size,
                              hipStream_t stream) {
  (void)in_sizes; (void)n_in; (void)out_size;
  const float* x1  = (const float*)d_in[0];
  const int*   ei1 = (const int*)d_in[1];
  const int*   bt1 = (const int*)d_in[2];
  const float* x2  = (const float*)d_in[3];
  const int*   ei2 = (const int*)d_in[4];
  const int*   bt2 = (const int*)d_in[5];
  const float* cell = (const float*)d_in[6];
  const float* Wc1 = (const float*)d_in[7];  const float* bc1 = (const float*)d_in[8];
  const float* Wc2 = (const float*)d_in[9];  const float* bc2 = (const float*)d_in[10];
  const float* Wc3 = (const float*)d_in[11]; const float* bc3 = (const float*)d_in[12];
  const float* Wg1 = (const float*)d_in[13]; const float* bg1 = (const float*)d_in[14];
  const float* Wg2 = (const float*)d_in[15]; const float* bg2 = (const float*)d_in[16];
  const float* Wr1 = (const float*)d_in[17]; const float* br1 = (const float*)d_in[18];
  const float* Wr2 = (const float*)d_in[19]; const float* br2 = (const float*)d_in[20];
  const float* Wr3 = (const float*)d_in[21]; const float* br3 = (const float*)d_in[22];
  const float* Wf1 = (const float*)d_in[23]; const float* bf1 = (const float*)d_in[24];
  const float* Wf2 = (const float*)d_in[25]; const float* bf2 = (const float*)d_in[26];
  const float* Wf3 = (const float*)d_in[27]; const float* bf3 = (const float*)d_in[28];
  const float* Wo  = (const float*)d_in[29]; const float* bo  = (const float*)d_in[30];
  float* out = (float*)d_out;

  const bool batched = ws_size >= (size_t)95 * 1024 * 1024;
  const int NPASS = batched ? 2 : 1;
  const int NN = NPASS * N_NODES;

  char* ws = (char*)d_ws;
  size_t off = 0;
  auto alloc_f = [&](size_t ne) { float* p = (float*)(ws + off); off += ne * 4; return p; };
  auto alloc_i = [&](size_t ne) { int* p = (int*)(ws + off); off += ne * 4; return p; };
  float* xbuf   = alloc_f((size_t)NN * 320);   // activations (64B-padded rows)
  float* abuf   = alloc_f((size_t)NN * 160);   // aggregated input (64B-padded rows)
  float* dinv   = alloc_f(NN);
  float* pooled = alloc_f((size_t)512 * 312);
  float* ppart  = alloc_f((size_t)512 * POOL_NC * 312);
  float* cvbuf  = alloc_f((size_t)N_GRAPH * 960);
  float* gtmp1  = alloc_f((size_t)512 * 2048);
  float* gtmp2  = alloc_f((size_t)512 * 512);
  float* gtmp3  = alloc_f((size_t)N_GRAPH * 256);
  float* catbuf = alloc_f((size_t)N_GRAPH * 512);
  int* cnt     = alloc_i(NN);
  int* row_ptr = alloc_i(NN + 1);
  int* cursor  = alloc_i(NN);
  int* col_idx = alloc_i(NPASS * N_EDGES);
  int* part    = alloc_i(64);
  int* start1  = alloc_i(N_GRAPH + 1);
  int* start2  = alloc_i(N_GRAPH + 1);
  float* accb  = xbuf;  // split-K partials (MLP runs after pooling; xbuf free then)

  // XCD-swizzled med GEMM for the 40000-row node-feature layers
  auto gemm_med_swz = [&](const float* A, int lda, const float* B, int ldb, float* C, int ldc,
                          const float* bias, int Nr, int K, int M, int relu) {
    int Cc = (M + 63) / 64, R = (Nr + 127) / 128, RR = (R + 7) >> 3;
    dim3 grid(8 * RR * Cc, 1, 1);
    gemm_t<128, 64, 8, 4><<<grid, 256, 0, stream>>>(A, lda, B, ldb, C, ldc, 0, bias,
                                                    Nr, K, M, relu, K, 1);
  };
  auto gemm_small = [&](const float* A, int lda, const float* B, int ldb, float* C, int ldc,
                        const float* bias, int Nr, int K, int M, int relu) {
    dim3 grid((M + 63) / 64, (Nr + 63) / 64, 1);
    gemm_t<64, 64, 4, 4><<<grid, 256, 0, stream>>>(A, lda, B, ldb, C, ldc, 0, bias,
                                                   Nr, K, M, relu, K, 0);
  };
  // split-K layer: partial stores per z-slice + summing bias/act pass
  auto splitk = [&](const float* A, int lda, const float* B, int M_, int K_, int S,
                    const float* bias, float* dst, int ldd, int relu, int Nr) {
    int kchunk = (((K_ + S - 1) / S) + 15) / 16 * 16;
    int Sz = (K_ + kchunk - 1) / kchunk;
    dim3 grid((M_ + 63) / 64, (Nr + 63) / 64, Sz);
    gemm_t<64, 64, 4, 4><<<grid, 256, 0, stream>>>(A, lda, B, M_, accb, M_, Nr * M_,
                                                   nullptr, Nr, K_, M_, 0, kchunk, 0);
    int tot = Nr * M_;
    bias_sum_kernel<<<(tot + 255) / 256, 256, 0, stream>>>(accb, Nr * M_, Sz, dst, ldd,
                                                           bias, Nr, M_, relu);
  };

  auto drug_pass = [&](const float* xa, const float* xb, const int* eia, const int* eib,
                       const int* bta, const int* btb, int npass, int pool_base) {
    const int nn = npass * N_NODES;
    const int te = npass * N_EDGES;
    const int nb = (nn + 1023) / 1024;
    hipMemsetAsync(cnt, 0, nn * sizeof(int), stream);
    hist2_kernel<<<(te + 255) / 256, 256, 0, stream>>>(eia, eib, cnt, N_EDGES, npass);
    scan1_kernel<<<nb, 1024, 0, stream>>>(cnt, row_ptr, part, nn);
    scan23_kernel<<<(nn + 255) / 256, 256, 0, stream>>>(cnt, row_ptr, part, cursor, dinv,
                                                        nn, te, bta, btb, start1, start2);
    scatter2_kernel<<<(te + 255) / 256, 256, 0, stream>>>(eia, eib, cursor, col_idx, N_EDGES, npass);
    // layer 1: agg(78, dual-source raw x, ld 78) -> abuf ld 80 -> GEMM 78->78 (out ld 80)
    {
      int tot = nn * 39;
      aggf2_flat<<<(tot + 255) / 256, 256, 0, stream>>>(xa, xb, N_NODES, row_ptr, col_idx,
                                                        dinv, abuf, 78, 80, 39, tot);
    }
    gemm_med_swz(abuf, 80, Wc1, 78, xbuf, 80, bc1, nn, 78, 78, 1);
    // layer 2: agg(78, ld 80) -> abuf ld 80 -> GEMM 78->156 (out ld 160)
    {
      int tot = nn * 39;
      aggf2_flat<<<(tot + 255) / 256, 256, 0, stream>>>(xbuf, xbuf, nn, row_ptr, col_idx,
                                                        dinv, abuf, 80, 80, 39, tot);
    }
    gemm_med_swz(abuf, 80, Wc2, 156, xbuf, 160, bc2, nn, 78, 156, 1);
    // layer 3: agg(156, ld 160) -> abuf ld 160 -> GEMM 156->312 (out ld 320)
    {
      int tot = nn * 39;
      aggf4_flat<<<(tot + 255) / 256, 256, 0, stream>>>(xbuf, row_ptr, col_idx,
                                                        dinv, abuf, 160, 160, 39, tot);
    }
    gemm_med_swz(abuf, 160, Wc3, 312, xbuf, 320, bc3, nn, 156, 312, 1);
    // two-stage pool (V = 312/4 = 78 float4 slots)
    {
      int totp = npass * N_GRAPH * POOL_NC * 78;
      pool_part_kernel<<<(totp + 255) / 256, 256, 0, stream>>>(xbuf, 320, start1, start2,
                                                               ppart, 78, totp);
      int totc = npass * N_GRAPH * 78;
      pool_combine_kernel<<<(totc + 255) / 256, 256, 0, stream>>>(ppart, pooled, 78, totc,
                                                                  pool_base);
    }
  };

  if (batched) {
    drug_pass(x1, x2, ei1, ei2, bt1, bt2, 2, 0);
  } else {
    drug_pass(x1, x1, ei1, ei1, bt1, bt1, 1, 0);
    drug_pass(x2, x2, ei2, ei2, bt2, bt2, 1, N_GRAPH);
  }

  // drug head on both branches at once (512 rows; shared weights), split-K for
  // block-count; Wg2 outputs written straight into catbuf halves.
  splitk(pooled, 312, Wg1, 156, 312, 4, bg1, gtmp1, 156, 1, 2 * N_GRAPH);
  splitk(gtmp1, 156, Wg2, 128, 156, 2, bg2, catbuf, 512, 0, N_GRAPH);
  splitk(gtmp1 + (size_t)N_GRAPH * 156, 156, Wg2, 128, 156, 2, bg2, catbuf + 128, 512, 0,
         N_GRAPH);

  // cell branch + head MLP (256-row deep-K layers via split-K)
  rownorm_kernel<<<N_GRAPH, 256, 0, stream>>>(cell, cvbuf, 954, 960);
  splitk(cvbuf, 960, Wr1, 2048, 954, 8,   br1, gtmp1, 2048, 1, N_GRAPH);
  splitk(gtmp1, 2048, Wr2, 512, 2048, 32, br2, gtmp2, 512, 1, N_GRAPH);
  splitk(gtmp2, 512, Wr3, 256, 512, 16,   br3, catbuf + 256, 512, 1, N_GRAPH);
  splitk(catbuf, 512, Wf1, 1024, 512, 16, bf1, gtmp1, 1024, 1, N_GRAPH);
  splitk(gtmp1, 1024, Wf2, 512, 1024, 32, bf2, gtmp2, 512, 1, N_GRAPH);
  splitk(gtmp2, 512, Wf3, 128, 512, 32,   bf3, gtmp3, 128, 1, N_GRAPH);
  gemm_small(gtmp3, 128, Wo, 2, out, 2, bo, N_GRAPH, 128, 2, 0);
}

// Round 13
// 550.906 us; speedup vs baseline: 1.3120x; 1.0469x over previous
//
#include <hip/hip_runtime.h>

#define N_NODES 20000
#define N_EDGES 320000
#define N_GRAPH 256
#define POOL_NC 8

__device__ __forceinline__ ushort f2b(float f) {  // fp32 -> bf16 RNE
  unsigned u = __float_as_uint(f);
  u += 0x7FFFu + ((u >> 16) & 1u);
  return (ushort)(u >> 16);
}
__device__ __forceinline__ float b2f(ushort u) {
  return __uint_as_float(((unsigned)u) << 16);
}

// ------------------------- templated tiled fp32 GEMM -------------------------
// zstride==0: direct C = op(A@B + bias). zstride>0 (split-K): block z plain-stores
// its partial to C + z*zstride (summed later by bias_sum_kernel).
// obf!=0: epilogue stores bf16 (C reinterpreted as ushort rows, ldc in ushorts).
// STRUCTURE IS MEASUREMENT-PINNED (do not change without re-measuring):
//   BK=16, single LDS buffer, register prefetch of tile k+1.
//   LDS double-buffer: VGPR 188, occ 10%, 135us (R6). BK=32: VGPR 148, 111us (R8).
//   Wc3 on BN=64 tile beats BN=128 (R10/R11). XCD swizzle cut FETCH 65->13MB (R12).
template<int BM, int BN, int TM, int TN>
__launch_bounds__(256)
__global__ void gemm_t(const float* __restrict__ A, int lda,
                       const float* __restrict__ B, int ldb,
                       float* __restrict__ C, int ldc, int zstride,
                       const float* __restrict__ bias,
                       int Nr, int K, int M, int do_relu, int kchunk, int swz, int obf) {
  constexpr int BK = 16;
  constexpr int LDA = BM + 4;
  __shared__ __align__(16) float As[BK][LDA];
  __shared__ __align__(16) float Bs[BK][BN];
  const int tid = threadIdx.x;
  int bx, by;
  if (swz) {
    const int Cc = (M + BN - 1) / BN;
    const int R = (Nr + BM - 1) / BM;
    const int RR = (R + 7) >> 3;
    const int x = blockIdx.x & 7, g = blockIdx.x >> 3;
    const int q = g / Cc;
    by = x * RR + q;
    bx = g - q * Cc;
    if (by >= R) return;
  } else {
    bx = blockIdx.x; by = blockIdx.y;
  }
  const int row0 = by * BM, col0 = bx * BN;
  constexpr int NX = BN / TN;
  const int tx = tid % NX, ty = tid / NX;
  float acc[TM][TN] = {};
  const int klo = blockIdx.z * kchunk;
  const int khi = min(klo + kchunk, K);

  constexpr int AIT = BM * BK / 4 / 256;
  constexpr int BIT = BK * BN / 4 / 256;
  float4 pa[AIT], pb[BIT];

  auto load_tile = [&](int k0) {
#pragma unroll
    for (int it = 0; it < AIT; ++it) {
      const int s = it * 256 + tid;
      const int row = s >> 2, kq = (s & 3) << 2;
      float4 av = make_float4(0.f, 0.f, 0.f, 0.f);
      const int gr = row0 + row, gk = k0 + kq;
      if (gr < Nr) {
        const float* Ap = A + (size_t)gr * lda + gk;
        if (gk + 3 < khi) { av.x = Ap[0]; av.y = Ap[1]; av.z = Ap[2]; av.w = Ap[3]; }
        else {
          if (gk     < khi) av.x = Ap[0];
          if (gk + 1 < khi) av.y = Ap[1];
          if (gk + 2 < khi) av.z = Ap[2];
        }
      }
      pa[it] = av;
    }
#pragma unroll
    for (int it = 0; it < BIT; ++it) {
      const int s = it * 256 + tid;
      const int kr = s / (BN / 4), c = (s % (BN / 4)) << 2;
      float4 bv = make_float4(0.f, 0.f, 0.f, 0.f);
      const int gk = k0 + kr, gc = col0 + c;
      if (gk < khi) {
        const float* Bp = B + (size_t)gk * ldb + gc;
        if (gc + 3 < M) { bv.x = Bp[0]; bv.y = Bp[1]; bv.z = Bp[2]; bv.w = Bp[3]; }
        else {
          if (gc     < M) bv.x = Bp[0];
          if (gc + 1 < M) bv.y = Bp[1];
          if (gc + 2 < M) bv.z = Bp[2];
        }
      }
      pb[it] = bv;
    }
  };

  load_tile(klo);
  for (int k0 = klo; k0 < khi; k0 += BK) {
#pragma unroll
    for (int it = 0; it < AIT; ++it) {
      const int s = it * 256 + tid;
      const int row = s >> 2, kq = (s & 3) << 2;
      As[kq    ][row] = pa[it].x;
      As[kq + 1][row] = pa[it].y;
      As[kq + 2][row] = pa[it].z;
      As[kq + 3][row] = pa[it].w;
    }
#pragma unroll
    for (int it = 0; it < BIT; ++it) {
      const int s = it * 256 + tid;
      const int kr = s / (BN / 4), c = (s % (BN / 4)) << 2;
      *(float4*)&Bs[kr][c] = pb[it];
    }
    __syncthreads();
    if (k0 + BK < khi) load_tile(k0 + BK);  // overlap next-tile fetch with compute
#pragma unroll
    for (int kk = 0; kk < BK; ++kk) {
      float ar[TM], br[TN];
#pragma unroll
      for (int i = 0; i < TM; i += 4)
        *(float4*)&ar[i] = *(const float4*)&As[kk][ty * TM + i];
      if constexpr (TN == 8) {
        *(float4*)&br[0] = *(const float4*)&Bs[kk][tx * 4];
        *(float4*)&br[4] = *(const float4*)&Bs[kk][BN / 2 + tx * 4];
      } else {
        *(float4*)&br[0] = *(const float4*)&Bs[kk][tx * TN];
      }
#pragma unroll
      for (int i = 0; i < TM; ++i)
#pragma unroll
        for (int j = 0; j < TN; ++j)
          acc[i][j] += ar[i] * br[j];
    }
    __syncthreads();
  }

  if (obf) {  // bf16 store path (direct only)
    ushort* Cu = (ushort*)C;
#pragma unroll
    for (int i = 0; i < TM; ++i) {
      const int r = row0 + ty * TM + i;
      if (r >= Nr) continue;
      ushort* Crow = Cu + (size_t)r * ldc;
#pragma unroll
      for (int g = 0; g < TN / 4; ++g) {
        const int c = col0 + (TN == 8 ? g * (BN / 2) : 0) + tx * 4;
        float v0 = acc[i][g * 4 + 0], v1 = acc[i][g * 4 + 1];
        float v2 = acc[i][g * 4 + 2], v3 = acc[i][g * 4 + 3];
        if (bias && c + 3 < M) { v0 += bias[c]; v1 += bias[c + 1]; v2 += bias[c + 2]; v3 += bias[c + 3]; }
        if (c + 3 < M) {
          if (do_relu) {
            v0 = fmaxf(v0, 0.f); v1 = fmaxf(v1, 0.f);
            v2 = fmaxf(v2, 0.f); v3 = fmaxf(v3, 0.f);
          }
          ushort4 o; o.x = f2b(v0); o.y = f2b(v1); o.z = f2b(v2); o.w = f2b(v3);
          *(ushort4*)&Crow[c] = o;
        } else {
          float vv[4] = {acc[i][g * 4 + 0], acc[i][g * 4 + 1], acc[i][g * 4 + 2], acc[i][g * 4 + 3]};
#pragma unroll
          for (int j = 0; j < 4; ++j) {
            if (c + j >= M) continue;
            float v = vv[j];
            if (bias) v += bias[c + j];
            if (do_relu) v = fmaxf(v, 0.f);
            Crow[c + j] = f2b(v);
          }
        }
      }
    }
    return;
  }

  float* Cz = C + (size_t)blockIdx.z * zstride;
#pragma unroll
  for (int i = 0; i < TM; ++i) {
    const int r = row0 + ty * TM + i;
    if (r >= Nr) continue;
    float* Crow = Cz + (size_t)r * ldc;
#pragma unroll
    for (int g = 0; g < TN / 4; ++g) {
      const int c = col0 + (TN == 8 ? g * (BN / 2) : 0) + tx * 4;
      if (c + 3 < M) {
        float4 v;
        v.x = acc[i][g * 4 + 0]; v.y = acc[i][g * 4 + 1];
        v.z = acc[i][g * 4 + 2]; v.w = acc[i][g * 4 + 3];
        if (bias) { v.x += bias[c]; v.y += bias[c + 1]; v.z += bias[c + 2]; v.w += bias[c + 3]; }
        if (do_relu) {
          v.x = fmaxf(v.x, 0.f); v.y = fmaxf(v.y, 0.f);
          v.z = fmaxf(v.z, 0.f); v.w = fmaxf(v.w, 0.f);
        }
        *(float4*)&Crow[c] = v;
      } else {
#pragma unroll
        for (int j = 0; j < 4; ++j) {
          if (c + j >= M) continue;
          float v = acc[i][g * 4 + j];
          if (bias) v += bias[c + j];
          if (do_relu) v = fmaxf(v, 0.f);
          Crow[c + j] = v;
        }
      }
    }
  }
}

// sum Sz split-K partials + bias (+relu), write with ldd
__global__ void bias_sum_kernel(const float* __restrict__ src, int zs, int Sz,
                                float* __restrict__ dst, int ldd,
                                const float* __restrict__ bias,
                                int Nr, int M, int do_relu) {
  int idx = blockIdx.x * blockDim.x + threadIdx.x;
  if (idx >= Nr * M) return;
  int r = idx / M, c = idx - r * M;
  float v = bias[c];
  for (int z = 0; z < Sz; ++z) v += src[idx + (size_t)z * zs];
  if (do_relu) v = fmaxf(v, 0.f);
  dst[(size_t)r * ldd + c] = v;
}

// ------------------------- graph prep -------------------------
__global__ void hist2_kernel(const int* __restrict__ e1, const int* __restrict__ e2,
                             int* __restrict__ cnt, int E, int npass) {
  int e = blockIdx.x * blockDim.x + threadIdx.x;
  if (e < E) atomicAdd(&cnt[e1[E + e]], 1);
  else if (e < npass * E) atomicAdd(&cnt[N_NODES + e2[E + e - E]], 1);
}

__launch_bounds__(1024)
__global__ void scan1_kernel(const int* __restrict__ cnt, int* __restrict__ row_ptr,
                             int* __restrict__ part, int n) {
  __shared__ int sh[1024];
  const int tid = threadIdx.x;
  const int i = blockIdx.x * 1024 + tid;
  const int v = (i < n) ? cnt[i] : 0;
  sh[tid] = v;
  __syncthreads();
#pragma unroll
  for (int off = 1; off < 1024; off <<= 1) {
    int t = (tid >= off) ? sh[tid - off] : 0;
    __syncthreads();
    sh[tid] += t;
    __syncthreads();
  }
  if (i < n) row_ptr[i] = sh[tid] - v;  // exclusive
  if (tid == 1023) part[blockIdx.x] = sh[tid];
}

// merged scan fixup + cursor/dinv init + graph starts
__global__ void scan23_kernel(const int* __restrict__ cnt, int* __restrict__ row_ptr,
                              const int* __restrict__ part, int* __restrict__ cursor,
                              float* __restrict__ dinv, int n, int total,
                              const int* __restrict__ b1, const int* __restrict__ b2,
                              int* __restrict__ s1, int* __restrict__ s2) {
  __shared__ int base_sh;
  const int tid = threadIdx.x;
  if (tid == 0) {
    int blk = blockIdx.x >> 2;
    int s = 0;
    for (int b = 0; b < blk; ++b) s += part[b];
    base_sh = s;
  }
  __syncthreads();
  int i = blockIdx.x * 256 + tid;
  if (i >= n) return;
  int rp = row_ptr[i] + base_sh;
  row_ptr[i] = rp;
  cursor[i] = rp;
  dinv[i] = rsqrtf((float)(cnt[i] + 1));
  if (i == 0) row_ptr[n] = total;
  if (i < N_NODES) {
    if (i == 0) { s1[0] = 0; s1[N_GRAPH] = N_NODES; }
    else if (b1[i] != b1[i - 1]) s1[b1[i]] = i;
  } else {
    int j = i - N_NODES;
    if (j == 0) { s2[0] = N_NODES; s2[N_GRAPH] = 2 * N_NODES; }
    else if (b2[j] != b2[j - 1]) s2[b2[j]] = N_NODES + j;
  }
}

__global__ void scatter2_kernel(const int* __restrict__ e1, const int* __restrict__ e2,
                                int* __restrict__ cursor, int* __restrict__ col_idx,
                                int E, int npass) {
  int e = blockIdx.x * blockDim.x + threadIdx.x;
  if (e < E) {
    int p = atomicAdd(&cursor[e1[E + e]], 1);
    col_idx[p] = e1[e];
  } else if (e < npass * E) {
    int j = e - E;
    int p = atomicAdd(&cursor[N_NODES + e2[E + j]], 1);
    col_idx[p] = N_NODES + e2[j];
  }
}

// ---- x1/x2 fp32 (ld 78) -> concat bf16 buffer (ld 80, pads zeroed) ----
__global__ void tobf16_kernel(const float* __restrict__ xa, const float* __restrict__ xb,
                              int nsplit, ushort* __restrict__ dst, int total) {
  int gid = blockIdx.x * blockDim.x + threadIdx.x;
  if (gid >= total) return;
  int n = gid / 20, v = gid - n * 20;
  const float* src = (n < nsplit) ? xa + (size_t)n * 78 : xb + (size_t)(n - nsplit) * 78;
  int f0 = v * 4;
  ushort4 o;
  o.x = (f0     < 78) ? f2b(src[f0])     : 0;
  o.y = (f0 + 1 < 78) ? f2b(src[f0 + 1]) : 0;
  o.z = (f0 + 2 < 78) ? f2b(src[f0 + 2]) : 0;
  o.w = (f0 + 3 < 78) ? f2b(src[f0 + 3]) : 0;
  ((ushort4*)(dst + (size_t)n * 80))[v] = o;
}

// ------------ normalized aggregation, bf16 gather, fp32 math/output ------------
// out = D^-1/2 (A+I) D^-1/2 h ; thread = (node, 4-wide slot); edge-unroll 4.
__global__ void aggb_flat(const ushort* __restrict__ h, const int* __restrict__ row_ptr,
                          const int* __restrict__ col_idx, const float* __restrict__ dinv,
                          float* __restrict__ out, int in_ld, int out_ld,
                          int V, int total) {
  int gid = blockIdx.x * blockDim.x + threadIdx.x;
  if (gid >= total) return;
  int n = gid / V, v = gid - n * V;
  const float din = dinv[n];
  const ushort4* hv = (const ushort4*)h;
  const int ivs = in_ld >> 2;
  float4 a;
  {
    ushort4 u = hv[(size_t)n * ivs + v];
    a.x = din * b2f(u.x); a.y = din * b2f(u.y);
    a.z = din * b2f(u.z); a.w = din * b2f(u.w);
  }
  const int beg = row_ptr[n], end = row_ptr[n + 1];
  int e = beg;
  for (; e + 3 < end; e += 4) {
    int s0 = col_idx[e], s1 = col_idx[e + 1], s2 = col_idx[e + 2], s3 = col_idx[e + 3];
    float d0 = dinv[s0], d1 = dinv[s1], d2 = dinv[s2], d3 = dinv[s3];
    ushort4 u0 = hv[(size_t)s0 * ivs + v], u1 = hv[(size_t)s1 * ivs + v];
    ushort4 u2 = hv[(size_t)s2 * ivs + v], u3 = hv[(size_t)s3 * ivs + v];
    a.x += d0 * b2f(u0.x) + d1 * b2f(u1.x) + d2 * b2f(u2.x) + d3 * b2f(u3.x);
    a.y += d0 * b2f(u0.y) + d1 * b2f(u1.y) + d2 * b2f(u2.y) + d3 * b2f(u3.y);
    a.z += d0 * b2f(u0.z) + d1 * b2f(u1.z) + d2 * b2f(u2.z) + d3 * b2f(u3.z);
    a.w += d0 * b2f(u0.w) + d1 * b2f(u1.w) + d2 * b2f(u2.w) + d3 * b2f(u3.w);
  }
  for (; e < end; ++e) {
    int s0 = col_idx[e];
    float d0 = dinv[s0];
    ushort4 u0 = hv[(size_t)s0 * ivs + v];
    a.x += d0 * b2f(u0.x); a.y += d0 * b2f(u0.y);
    a.z += d0 * b2f(u0.z); a.w += d0 * b2f(u0.w);
  }
  float4 o;
  o.x = din * a.x; o.y = din * a.y; o.z = din * a.z; o.w = din * a.w;
  ((float4*)(out + (size_t)n * out_ld))[v] = o;
}

// ---- two-stage max pool ----
__global__ void pool_part_kernel(const float* __restrict__ x, int xld,
                                 const int* __restrict__ s1, const int* __restrict__ s2,
                                 float* __restrict__ part, int V, int total) {
  int gid = blockIdx.x * blockDim.x + threadIdx.x;
  if (gid >= total) return;
  int v = gid % V;
  int gc = gid / V;
  int g = gc / POOL_NC, c = gc - g * POOL_NC;
  const int* st = (g < N_GRAPH) ? s1 : s2;
  int gi = g & (N_GRAPH - 1);
  int beg = st[gi], end = st[gi + 1];
  float4 m0 = make_float4(0.f, 0.f, 0.f, 0.f);
  float4 m1 = make_float4(0.f, 0.f, 0.f, 0.f);
  int nn = beg + c;
  for (; nn + POOL_NC < end; nn += 2 * POOL_NC) {
    float4 a = ((const float4*)(x + (size_t)nn * xld))[v];
    float4 b = ((const float4*)(x + (size_t)(nn + POOL_NC) * xld))[v];
    m0.x = fmaxf(m0.x, a.x); m0.y = fmaxf(m0.y, a.y);
    m0.z = fmaxf(m0.z, a.z); m0.w = fmaxf(m0.w, a.w);
    m1.x = fmaxf(m1.x, b.x); m1.y = fmaxf(m1.y, b.y);
    m1.z = fmaxf(m1.z, b.z); m1.w = fmaxf(m1.w, b.w);
  }
  if (nn < end) {
    float4 a = ((const float4*)(x + (size_t)nn * xld))[v];
    m0.x = fmaxf(m0.x, a.x); m0.y = fmaxf(m0.y, a.y);
    m0.z = fmaxf(m0.z, a.z); m0.w = fmaxf(m0.w, a.w);
  }
  float4 m;
  m.x = fmaxf(m0.x, m1.x); m.y = fmaxf(m0.y, m1.y);
  m.z = fmaxf(m0.z, m1.z); m.w = fmaxf(m0.w, m1.w);
  ((float4*)(part + (size_t)gc * (V * 4)))[v] = m;
}

__global__ void pool_combine_kernel(const float* __restrict__ part,
                                    float* __restrict__ pooled, int V, int total,
                                    int pool_base) {
  int gid = blockIdx.x * blockDim.x + threadIdx.x;
  if (gid >= total) return;
  int v = gid % V, g = gid / V;
  float4 m = make_float4(0.f, 0.f, 0.f, 0.f);
#pragma unroll
  for (int c = 0; c < POOL_NC; ++c) {
    float4 a = ((const float4*)(part + (size_t)(g * POOL_NC + c) * (V * 4)))[v];
    m.x = fmaxf(m.x, a.x); m.y = fmaxf(m.y, a.y);
    m.z = fmaxf(m.z, a.z); m.w = fmaxf(m.w, a.w);
  }
  ((float4*)(pooled + (size_t)(pool_base + g) * (V * 4)))[v] = m;
}

__global__ void rownorm_kernel(const float* __restrict__ cell, float* __restrict__ cv,
                               int F, int out_ld) {
  int g = blockIdx.x;
  __shared__ float red[256];
  int tid = threadIdx.x;
  const float* row = cell + (size_t)g * F;
  float s = 0.f;
  for (int f = tid; f < F; f += 256) { float v = row[f]; s += v * v; }
  red[tid] = s;
  __syncthreads();
  for (int off = 128; off > 0; off >>= 1) {
    if (tid < off) red[tid] += red[tid + off];
    __syncthreads();
  }
  float inv = 1.f / fmaxf(sqrtf(red[0]), 1e-12f);
  float* orow = cv + (size_t)g * out_ld;
  for (int f = tid; f < F; f += 256) orow[f] = row[f] * inv;
  for (int f = F + tid; f < out_ld; f += 256) orow[f] = 0.f;
}

// ------------------------- launcher -------------------------
extern "C" void kernel_launch(void* const* d_in, const int* in_sizes, int n_in,
                              void* d_out, int out_size, void* d_ws, size_t ws_size,
                              hipStream_t stream) {
  (void)in_sizes; (void)n_in; (void)out_size;
  const float* x1  = (const float*)d_in[0];
  const int*   ei1 = (const int*)d_in[1];
  const int*   bt1 = (const int*)d_in[2];
  const float* x2  = (const float*)d_in[3];
  const int*   ei2 = (const int*)d_in[4];
  const int*   bt2 = (const int*)d_in[5];
  const float* cell = (const float*)d_in[6];
  const float* Wc1 = (const float*)d_in[7];  const float* bc1 = (const float*)d_in[8];
  const float* Wc2 = (const float*)d_in[9];  const float* bc2 = (const float*)d_in[10];
  const float* Wc3 = (const float*)d_in[11]; const float* bc3 = (const float*)d_in[12];
  const float* Wg1 = (const float*)d_in[13]; const float* bg1 = (const float*)d_in[14];
  const float* Wg2 = (const float*)d_in[15]; const float* bg2 = (const float*)d_in[16];
  const float* Wr1 = (const float*)d_in[17]; const float* br1 = (const float*)d_in[18];
  const float* Wr2 = (const float*)d_in[19]; const float* br2 = (const float*)d_in[20];
  const float* Wr3 = (const float*)d_in[21]; const float* br3 = (const float*)d_in[22];
  const float* Wf1 = (const float*)d_in[23]; const float* bf1 = (const float*)d_in[24];
  const float* Wf2 = (const float*)d_in[25]; const float* bf2 = (const float*)d_in[26];
  const float* Wf3 = (const float*)d_in[27]; const float* bf3 = (const float*)d_in[28];
  const float* Wo  = (const float*)d_in[29]; const float* bo  = (const float*)d_in[30];
  float* out = (float*)d_out;

  const bool batched = ws_size >= (size_t)95 * 1024 * 1024;
  const int NPASS = batched ? 2 : 1;
  const int NN = NPASS * N_NODES;

  char* ws = (char*)d_ws;
  size_t off = 0;
  auto alloc_f = [&](size_t ne) { float* p = (float*)(ws + off); off += ne * 4; return p; };
  auto alloc_i = [&](size_t ne) { int* p = (int*)(ws + off); off += ne * 4; return p; };
  float* xbuf   = alloc_f((size_t)NN * 320);   // layer-3 fp32 out; also hosts xb16a + accb
  float* abuf   = alloc_f((size_t)NN * 160);   // fp32 agg out (lower); upper hosts bf16 h
  float* dinv   = alloc_f(NN);
  float* pooled = alloc_f((size_t)512 * 312);
  float* ppart  = alloc_f((size_t)512 * POOL_NC * 312);
  float* cvbuf  = alloc_f((size_t)N_GRAPH * 960);
  float* gtmp1  = alloc_f((size_t)512 * 2048);
  float* gtmp2  = alloc_f((size_t)512 * 512);
  float* gtmp3  = alloc_f((size_t)N_GRAPH * 256);
  float* catbuf = alloc_f((size_t)N_GRAPH * 512);
  int* cnt     = alloc_i(NN);
  int* row_ptr = alloc_i(NN + 1);
  int* cursor  = alloc_i(NN);
  int* col_idx = alloc_i(NPASS * N_EDGES);
  int* part    = alloc_i(64);
  int* start1  = alloc_i(N_GRAPH + 1);
  int* start2  = alloc_i(N_GRAPH + 1);
  float* accb  = xbuf;                                    // split-K partials (after pool)
  ushort* xb16s = (ushort*)(abuf + (size_t)NN * 80);      // bf16 h, ld 80 (layers 1-2 src)
  ushort* xb16w = (ushort*)xbuf;                          // bf16 h, ld 160 (layer-3 src)

  auto gemm_med_swz = [&](const float* A, int lda, const float* B, int ldb, float* C, int ldc,
                          const float* bias, int Nr, int K, int M, int relu, int obf) {
    int Cc = (M + 63) / 64, R = (Nr + 127) / 128, RR = (R + 7) >> 3;
    dim3 grid(8 * RR * Cc, 1, 1);
    gemm_t<128, 64, 8, 4><<<grid, 256, 0, stream>>>(A, lda, B, ldb, C, ldc, 0, bias,
                                                    Nr, K, M, relu, K, 1, obf);
  };
  auto gemm_small = [&](const float* A, int lda, const float* B, int ldb, float* C, int ldc,
                        const float* bias, int Nr, int K, int M, int relu) {
    dim3 grid((M + 63) / 64, (Nr + 63) / 64, 1);
    gemm_t<64, 64, 4, 4><<<grid, 256, 0, stream>>>(A, lda, B, ldb, C, ldc, 0, bias,
                                                   Nr, K, M, relu, K, 0, 0);
  };
  auto splitk = [&](const float* A, int lda, const float* B, int M_, int K_, int S,
                    const float* bias, float* dst, int ldd, int relu, int Nr) {
    int kchunk = (((K_ + S - 1) / S) + 15) / 16 * 16;
    int Sz = (K_ + kchunk - 1) / kchunk;
    dim3 grid((M_ + 63) / 64, (Nr + 63) / 64, Sz);
    gemm_t<64, 64, 4, 4><<<grid, 256, 0, stream>>>(A, lda, B, M_, accb, M_, Nr * M_,
                                                   nullptr, Nr, K_, M_, 0, kchunk, 0, 0);
    int tot = Nr * M_;
    bias_sum_kernel<<<(tot + 255) / 256, 256, 0, stream>>>(accb, Nr * M_, Sz, dst, ldd,
                                                           bias, Nr, M_, relu);
  };

  auto drug_pass = [&](const float* xa, const float* xb, const int* eia, const int* eib,
                       const int* bta, const int* btb, int npass, int pool_base) {
    const int nn = npass * N_NODES;
    const int te = npass * N_EDGES;
    const int nb = (nn + 1023) / 1024;
    hipMemsetAsync(cnt, 0, nn * sizeof(int), stream);
    hist2_kernel<<<(te + 255) / 256, 256, 0, stream>>>(eia, eib, cnt, N_EDGES, npass);
    scan1_kernel<<<nb, 1024, 0, stream>>>(cnt, row_ptr, part, nn);
    scan23_kernel<<<(nn + 255) / 256, 256, 0, stream>>>(cnt, row_ptr, part, cursor, dinv,
                                                        nn, te, bta, btb, start1, start2);
    scatter2_kernel<<<(te + 255) / 256, 256, 0, stream>>>(eia, eib, cursor, col_idx, N_EDGES, npass);
    // x -> bf16 (ld 80), virtual concat
    {
      int tot = nn * 20;
      tobf16_kernel<<<(tot + 255) / 256, 256, 0, stream>>>(
          xa, xb, (npass == 2) ? N_NODES : nn, xb16s, tot);
    }
    // layer 1: agg(bf16 ld80) -> abuf fp32 ld80 -> GEMM 78->78 -> bf16 (xb16s, ld80)
    {
      int tot = nn * 20;
      aggb_flat<<<(tot + 255) / 256, 256, 0, stream>>>(xb16s, row_ptr, col_idx, dinv,
                                                       abuf, 80, 80, 20, tot);
    }
    gemm_med_swz(abuf, 80, Wc1, 78, (float*)xb16s, 80, bc1, nn, 78, 78, 1, 1);
    // layer 2: agg(bf16 ld80) -> abuf ld80 -> GEMM 78->156 -> bf16 (xb16w, ld160)
    {
      int tot = nn * 20;
      aggb_flat<<<(tot + 255) / 256, 256, 0, stream>>>(xb16s, row_ptr, col_idx, dinv,
                                                       abuf, 80, 80, 20, tot);
    }
    gemm_med_swz(abuf, 80, Wc2, 156, (float*)xb16w, 160, bc2, nn, 78, 156, 1, 1);
    // layer 3: agg(bf16 ld160) -> abuf ld160 -> GEMM 156->312 -> fp32 xbuf ld320
    {
      int tot = nn * 40;
      aggb_flat<<<(tot + 255) / 256, 256, 0, stream>>>(xb16w, row_ptr, col_idx, dinv,
                                                       abuf, 160, 160, 40, tot);
    }
    gemm_med_swz(abuf, 160, Wc3, 312, xbuf, 320, bc3, nn, 156, 312, 1, 0);
    // two-stage pool (V = 78 float4 slots)
    {
      int totp = npass * N_GRAPH * POOL_NC * 78;
      pool_part_kernel<<<(totp + 255) / 256, 256, 0, stream>>>(xbuf, 320, start1, start2,
                                                               ppart, 78, totp);
      int totc = npass * N_GRAPH * 78;
      pool_combine_kernel<<<(totc + 255) / 256, 256, 0, stream>>>(ppart, pooled, 78, totc,
                                                                  pool_base);
    }
  };

  if (batched) {
    drug_pass(x1, x2, ei1, ei2, bt1, bt2, 2, 0);
  } else {
    drug_pass(x1, x1, ei1, ei1, bt1, bt1, 1, 0);
    drug_pass(x2, x2, ei2, ei2, bt2, bt2, 1, N_GRAPH);
  }

  // drug head (512 rows, shared weights); Wg2 straight into catbuf halves
  splitk(pooled, 312, Wg1, 156, 312, 4, bg1, gtmp1, 156, 1, 2 * N_GRAPH);
  splitk(gtmp1, 156, Wg2, 128, 156, 2, bg2, catbuf, 512, 0, N_GRAPH);
  splitk(gtmp1 + (size_t)N_GRAPH * 156, 156, Wg2, 128, 156, 2, bg2, catbuf + 128, 512, 0,
         N_GRAPH);

  // cell branch + head MLP
  rownorm_kernel<<<N_GRAPH, 256, 0, stream>>>(cell, cvbuf, 954, 960);
  splitk(cvbuf, 960, Wr1, 2048, 954, 8,   br1, gtmp1, 2048, 1, N_GRAPH);
  splitk(gtmp1, 2048, Wr2, 512, 2048, 32, br2, gtmp2, 512, 1, N_GRAPH);
  splitk(gtmp2, 512, Wr3, 256, 512, 16,   br3, catbuf + 256, 512, 1, N_GRAPH);
  splitk(catbuf, 512, Wf1, 1024, 512, 16, bf1, gtmp1, 1024, 1, N_GRAPH);
  splitk(gtmp1, 1024, Wf2, 512, 1024, 32, bf2, gtmp2, 512, 1, N_GRAPH);
  splitk(gtmp2, 512, Wf3, 128, 512, 32,   bf3, gtmp3, 128, 1, N_GRAPH);
  gemm_small(gtmp3, 128, Wo, 2, out, 2, bo, N_GRAPH, 128, 2, 0);
}

// Round 14
// 491.788 us; speedup vs baseline: 1.4698x; 1.1202x over previous
//
#include <hip/hip_runtime.h>

#define N_NODES 20000
#define N_EDGES 320000
#define N_GRAPH 256
#define POOL_NC 8

__device__ __forceinline__ ushort f2b(float f) {  // fp32 -> bf16 RNE
  unsigned u = __float_as_uint(f);
  u += 0x7FFFu + ((u >> 16) & 1u);
  return (ushort)(u >> 16);
}
__device__ __forceinline__ float b2f(ushort u) {
  return __uint_as_float(((unsigned)u) << 16);
}

typedef __attribute__((ext_vector_type(8))) short bf16x8;
typedef __attribute__((ext_vector_type(4))) float f32x4;

// ---------------- bf16 MFMA GEMM: C = op(A_bf16 @ B_bf16 + bias) ----------------
// A[Nr][lda] bf16 row-major; Bt[M][ldbt] bf16 = B TRANSPOSED (k contiguous).
// Kpad = multiple of 32 (<= lda, <= ldbt); Bt rows padded to grid cols*64, k-pads zero.
// Block 128x64, 4 waves, each wave 32x64 = 2x4 mfma_f32_16x16x32_bf16 tiles.
// Frag layouts (m89/m91-verified): A[m=lane&15][k=quad*8+j]; B[n=lane&15][k=quad*8+j];
// D[row=quad*4+r][col=lane&15]. Pinned loop structure from gemm_t (R7/R9).
__launch_bounds__(256)
__global__ void gemm_mfma(const ushort* __restrict__ A, int lda,
                          const ushort* __restrict__ Bt, int ldbt,
                          void* __restrict__ Cv, int ldc,
                          const float* __restrict__ bias,
                          int Nr, int Kpad, int M, int do_relu, int obf) {
  constexpr int BM = 128, BN = 64, BK = 32, LK = 40;
  __shared__ __align__(16) ushort Asl[BM][LK];
  __shared__ __align__(16) ushort Bsl[BN][LK];
  const int tid = threadIdx.x;
  // XCD-aware swizzle (1D grid): all column-tiles of a row-slab on one XCD (R12)
  const int Cc = (M + BN - 1) / BN;
  const int R = (Nr + BM - 1) / BM;
  const int RR = (R + 7) >> 3;
  const int xz = blockIdx.x & 7, g = blockIdx.x >> 3;
  const int q = g / Cc;
  const int by = xz * RR + q;
  const int bx = g - q * Cc;
  if (by >= R) return;
  const int row0 = by * BM, col0 = bx * BN;

  const int lane = tid & 63, w = tid >> 6;
  const int a_r = tid >> 1, a_h = tid & 1;        // A: row, 32B half
  const int b_r = tid >> 2, b_o = (tid & 3) * 8;  // B: row, 16B quarter

  uint4 pa0, pa1, pb0;
  auto load_tile = [&](int k0) {
    if (row0 + a_r < Nr) {
      const uint4* p = (const uint4*)(A + (size_t)(row0 + a_r) * lda + k0 + a_h * 16);
      pa0 = p[0]; pa1 = p[1];
    } else {
      pa0 = make_uint4(0u, 0u, 0u, 0u); pa1 = pa0;
    }
    pb0 = *(const uint4*)(Bt + (size_t)(col0 + b_r) * ldbt + k0 + b_o);
  };
  auto commit = [&]() {
    *(uint4*)&Asl[a_r][a_h * 16] = pa0;
    *(uint4*)&Asl[a_r][a_h * 16 + 8] = pa1;
    *(uint4*)&Bsl[b_r][b_o] = pb0;
  };

  f32x4 acc[2][4] = {};
  const int nst = Kpad / BK;
  const int mrow = w * 32;
  const int lm = lane & 15, lq = (lane >> 4) * 8;

  load_tile(0);
  for (int t = 0; t < nst; ++t) {
    commit();
    __syncthreads();
    if (t + 1 < nst) load_tile((t + 1) * BK);
    bf16x8 af0 = *(const bf16x8*)&Asl[mrow + lm][lq];
    bf16x8 af1 = *(const bf16x8*)&Asl[mrow + 16 + lm][lq];
    bf16x8 bf0 = *(const bf16x8*)&Bsl[lm][lq];
    bf16x8 bf1 = *(const bf16x8*)&Bsl[16 + lm][lq];
    bf16x8 bf2 = *(const bf16x8*)&Bsl[32 + lm][lq];
    bf16x8 bf3 = *(const bf16x8*)&Bsl[48 + lm][lq];
    acc[0][0] = __builtin_amdgcn_mfma_f32_16x16x32_bf16(af0, bf0, acc[0][0], 0, 0, 0);
    acc[0][1] = __builtin_amdgcn_mfma_f32_16x16x32_bf16(af0, bf1, acc[0][1], 0, 0, 0);
    acc[0][2] = __builtin_amdgcn_mfma_f32_16x16x32_bf16(af0, bf2, acc[0][2], 0, 0, 0);
    acc[0][3] = __builtin_amdgcn_mfma_f32_16x16x32_bf16(af0, bf3, acc[0][3], 0, 0, 0);
    acc[1][0] = __builtin_amdgcn_mfma_f32_16x16x32_bf16(af1, bf0, acc[1][0], 0, 0, 0);
    acc[1][1] = __builtin_amdgcn_mfma_f32_16x16x32_bf16(af1, bf1, acc[1][1], 0, 0, 0);
    acc[1][2] = __builtin_amdgcn_mfma_f32_16x16x32_bf16(af1, bf2, acc[1][2], 0, 0, 0);
    acc[1][3] = __builtin_amdgcn_mfma_f32_16x16x32_bf16(af1, bf3, acc[1][3], 0, 0, 0);
    __syncthreads();
  }

  const int rquad = (lane >> 4) * 4;
#pragma unroll
  for (int mt = 0; mt < 2; ++mt) {
#pragma unroll
    for (int nt = 0; nt < 4; ++nt) {
      const int cc = col0 + nt * 16 + lm;
      if (cc >= M) continue;
      const float bv = bias ? bias[cc] : 0.f;
#pragma unroll
      for (int r = 0; r < 4; ++r) {
        const int rr = row0 + mrow + mt * 16 + rquad + r;
        if (rr >= Nr) continue;
        float v = acc[mt][nt][r] + bv;
        if (do_relu) v = fmaxf(v, 0.f);
        if (obf) ((ushort*)Cv)[(size_t)rr * ldc + cc] = f2b(v);
        else     ((float*)Cv)[(size_t)rr * ldc + cc] = v;
      }
    }
  }
}

// weights -> bf16 transposed (Bt[n][k]), zero-padded. T1:128x96(78,78)
// T2:192x96(156,78) T3:320x160(312,156)
__global__ void wcvt_kernel(const float* __restrict__ W1, const float* __restrict__ W2,
                            const float* __restrict__ W3, ushort* __restrict__ T1,
                            ushort* __restrict__ T2, ushort* __restrict__ T3) {
  int gid = blockIdx.x * blockDim.x + threadIdx.x;
  if (gid < 128 * 96) {
    int n = gid / 96, k = gid - n * 96;
    T1[gid] = (n < 78 && k < 78) ? f2b(W1[k * 78 + n]) : 0;
  } else if (gid < 128 * 96 + 192 * 96) {
    int g = gid - 128 * 96;
    int n = g / 96, k = g - n * 96;
    T2[g] = (n < 156 && k < 78) ? f2b(W2[k * 156 + n]) : 0;
  } else if (gid < 128 * 96 + 192 * 96 + 320 * 160) {
    int g = gid - 128 * 96 - 192 * 96;
    int n = g / 160, k = g - n * 160;
    T3[g] = (n < 312 && k < 156) ? f2b(W3[k * 312 + n]) : 0;
  }
}

// ------------------------- fp32 tiled GEMM (MLP/head; pinned structure) -------------------------
template<int BM, int BN, int TM, int TN>
__launch_bounds__(256)
__global__ void gemm_t(const float* __restrict__ A, int lda,
                       const float* __restrict__ B, int ldb,
                       float* __restrict__ C, int ldc, int zstride,
                       const float* __restrict__ bias,
                       int Nr, int K, int M, int do_relu, int kchunk) {
  constexpr int BK = 16;
  constexpr int LDA = BM + 4;
  __shared__ __align__(16) float As[BK][LDA];
  __shared__ __align__(16) float Bs[BK][BN];
  const int tid = threadIdx.x;
  const int row0 = blockIdx.y * BM, col0 = blockIdx.x * BN;
  constexpr int NX = BN / TN;
  const int tx = tid % NX, ty = tid / NX;
  float acc[TM][TN] = {};
  const int klo = blockIdx.z * kchunk;
  const int khi = min(klo + kchunk, K);

  constexpr int AIT = BM * BK / 4 / 256;
  constexpr int BIT = BK * BN / 4 / 256;
  float4 pa[AIT], pb[BIT];

  auto load_tile = [&](int k0) {
#pragma unroll
    for (int it = 0; it < AIT; ++it) {
      const int s = it * 256 + tid;
      const int row = s >> 2, kq = (s & 3) << 2;
      float4 av = make_float4(0.f, 0.f, 0.f, 0.f);
      const int gr = row0 + row, gk = k0 + kq;
      if (gr < Nr) {
        const float* Ap = A + (size_t)gr * lda + gk;
        if (gk + 3 < khi) { av.x = Ap[0]; av.y = Ap[1]; av.z = Ap[2]; av.w = Ap[3]; }
        else {
          if (gk     < khi) av.x = Ap[0];
          if (gk + 1 < khi) av.y = Ap[1];
          if (gk + 2 < khi) av.z = Ap[2];
        }
      }
      pa[it] = av;
    }
#pragma unroll
    for (int it = 0; it < BIT; ++it) {
      const int s = it * 256 + tid;
      const int kr = s / (BN / 4), c = (s % (BN / 4)) << 2;
      float4 bv = make_float4(0.f, 0.f, 0.f, 0.f);
      const int gk = k0 + kr, gc = col0 + c;
      if (gk < khi) {
        const float* Bp = B + (size_t)gk * ldb + gc;
        if (gc + 3 < M) { bv.x = Bp[0]; bv.y = Bp[1]; bv.z = Bp[2]; bv.w = Bp[3]; }
        else {
          if (gc     < M) bv.x = Bp[0];
          if (gc + 1 < M) bv.y = Bp[1];
          if (gc + 2 < M) bv.z = Bp[2];
        }
      }
      pb[it] = bv;
    }
  };

  load_tile(klo);
  for (int k0 = klo; k0 < khi; k0 += BK) {
#pragma unroll
    for (int it = 0; it < AIT; ++it) {
      const int s = it * 256 + tid;
      const int row = s >> 2, kq = (s & 3) << 2;
      As[kq    ][row] = pa[it].x;
      As[kq + 1][row] = pa[it].y;
      As[kq + 2][row] = pa[it].z;
      As[kq + 3][row] = pa[it].w;
    }
#pragma unroll
    for (int it = 0; it < BIT; ++it) {
      const int s = it * 256 + tid;
      const int kr = s / (BN / 4), c = (s % (BN / 4)) << 2;
      *(float4*)&Bs[kr][c] = pb[it];
    }
    __syncthreads();
    if (k0 + BK < khi) load_tile(k0 + BK);
#pragma unroll
    for (int kk = 0; kk < BK; ++kk) {
      float ar[TM], br[TN];
#pragma unroll
      for (int i = 0; i < TM; i += 4)
        *(float4*)&ar[i] = *(const float4*)&As[kk][ty * TM + i];
      if constexpr (TN == 8) {
        *(float4*)&br[0] = *(const float4*)&Bs[kk][tx * 4];
        *(float4*)&br[4] = *(const float4*)&Bs[kk][BN / 2 + tx * 4];
      } else {
        *(float4*)&br[0] = *(const float4*)&Bs[kk][tx * TN];
      }
#pragma unroll
      for (int i = 0; i < TM; ++i)
#pragma unroll
        for (int j = 0; j < TN; ++j)
          acc[i][j] += ar[i] * br[j];
    }
    __syncthreads();
  }

  float* Cz = C + (size_t)blockIdx.z * zstride;
#pragma unroll
  for (int i = 0; i < TM; ++i) {
    const int r = row0 + ty * TM + i;
    if (r >= Nr) continue;
    float* Crow = Cz + (size_t)r * ldc;
#pragma unroll
    for (int g = 0; g < TN / 4; ++g) {
      const int c = col0 + (TN == 8 ? g * (BN / 2) : 0) + tx * 4;
      if (c + 3 < M) {
        float4 v;
        v.x = acc[i][g * 4 + 0]; v.y = acc[i][g * 4 + 1];
        v.z = acc[i][g * 4 + 2]; v.w = acc[i][g * 4 + 3];
        if (bias) { v.x += bias[c]; v.y += bias[c + 1]; v.z += bias[c + 2]; v.w += bias[c + 3]; }
        if (do_relu) {
          v.x = fmaxf(v.x, 0.f); v.y = fmaxf(v.y, 0.f);
          v.z = fmaxf(v.z, 0.f); v.w = fmaxf(v.w, 0.f);
        }
        *(float4*)&Crow[c] = v;
      } else {
#pragma unroll
        for (int j = 0; j < 4; ++j) {
          if (c + j >= M) continue;
          float v = acc[i][g * 4 + j];
          if (bias) v += bias[c + j];
          if (do_relu) v = fmaxf(v, 0.f);
          Crow[c + j] = v;
        }
      }
    }
  }
}

__global__ void bias_sum_kernel(const float* __restrict__ src, int zs, int Sz,
                                float* __restrict__ dst, int ldd,
                                const float* __restrict__ bias,
                                int Nr, int M, int do_relu) {
  int idx = blockIdx.x * blockDim.x + threadIdx.x;
  if (idx >= Nr * M) return;
  int r = idx / M, c = idx - r * M;
  float v = bias[c];
  for (int z = 0; z < Sz; ++z) v += src[idx + (size_t)z * zs];
  if (do_relu) v = fmaxf(v, 0.f);
  dst[(size_t)r * ldd + c] = v;
}

// ------------------------- graph prep -------------------------
__global__ void hist2_kernel(const int* __restrict__ e1, const int* __restrict__ e2,
                             int* __restrict__ cnt, int E, int npass) {
  int e = blockIdx.x * blockDim.x + threadIdx.x;
  if (e < E) atomicAdd(&cnt[e1[E + e]], 1);
  else if (e < npass * E) atomicAdd(&cnt[N_NODES + e2[E + e - E]], 1);
}

__launch_bounds__(1024)
__global__ void scan1_kernel(const int* __restrict__ cnt, int* __restrict__ row_ptr,
                             int* __restrict__ part, int n) {
  __shared__ int sh[1024];
  const int tid = threadIdx.x;
  const int i = blockIdx.x * 1024 + tid;
  const int v = (i < n) ? cnt[i] : 0;
  sh[tid] = v;
  __syncthreads();
#pragma unroll
  for (int off = 1; off < 1024; off <<= 1) {
    int t = (tid >= off) ? sh[tid - off] : 0;
    __syncthreads();
    sh[tid] += t;
    __syncthreads();
  }
  if (i < n) row_ptr[i] = sh[tid] - v;
  if (tid == 1023) part[blockIdx.x] = sh[tid];
}

__global__ void scan23_kernel(const int* __restrict__ cnt, int* __restrict__ row_ptr,
                              const int* __restrict__ part, int* __restrict__ cursor,
                              float* __restrict__ dinv, int n, int total,
                              const int* __restrict__ b1, const int* __restrict__ b2,
                              int* __restrict__ s1, int* __restrict__ s2) {
  __shared__ int base_sh;
  const int tid = threadIdx.x;
  if (tid == 0) {
    int blk = blockIdx.x >> 2;
    int s = 0;
    for (int b = 0; b < blk; ++b) s += part[b];
    base_sh = s;
  }
  __syncthreads();
  int i = blockIdx.x * 256 + tid;
  if (i >= n) return;
  int rp = row_ptr[i] + base_sh;
  row_ptr[i] = rp;
  cursor[i] = rp;
  dinv[i] = rsqrtf((float)(cnt[i] + 1));
  if (i == 0) row_ptr[n] = total;
  if (i < N_NODES) {
    if (i == 0) { s1[0] = 0; s1[N_GRAPH] = N_NODES; }
    else if (b1[i] != b1[i - 1]) s1[b1[i]] = i;
  } else {
    int j = i - N_NODES;
    if (j == 0) { s2[0] = N_NODES; s2[N_GRAPH] = 2 * N_NODES; }
    else if (b2[j] != b2[j - 1]) s2[b2[j]] = N_NODES + j;
  }
}

__global__ void scatter2_kernel(const int* __restrict__ e1, const int* __restrict__ e2,
                                int* __restrict__ cursor, int* __restrict__ col_idx,
                                int E, int npass) {
  int e = blockIdx.x * blockDim.x + threadIdx.x;
  if (e < E) {
    int p = atomicAdd(&cursor[e1[E + e]], 1);
    col_idx[p] = e1[e];
  } else if (e < npass * E) {
    int j = e - E;
    int p = atomicAdd(&cursor[N_NODES + e2[E + j]], 1);
    col_idx[p] = N_NODES + e2[j];
  }
}

// ---- x1/x2 fp32 (ld 78) -> concat bf16 buffer (ld 80, pads zeroed) ----
__global__ void tobf16_kernel(const float* __restrict__ xa, const float* __restrict__ xb,
                              int nsplit, ushort* __restrict__ dst, int total) {
  int gid = blockIdx.x * blockDim.x + threadIdx.x;
  if (gid >= total) return;
  int n = gid / 20, v = gid - n * 20;
  const float* src = (n < nsplit) ? xa + (size_t)n * 78 : xb + (size_t)(n - nsplit) * 78;
  int f0 = v * 4;
  ushort4 o;
  o.x = (f0     < 78) ? f2b(src[f0])     : 0;
  o.y = (f0 + 1 < 78) ? f2b(src[f0 + 1]) : 0;
  o.z = (f0 + 2 < 78) ? f2b(src[f0 + 2]) : 0;
  o.w = (f0 + 3 < 78) ? f2b(src[f0 + 3]) : 0;
  ((ushort4*)(dst + (size_t)n * 80))[v] = o;
}

// ---- normalized aggregation: bf16 gather, fp32 math, bf16 output ----
__global__ void aggb_flat(const ushort* __restrict__ h, const int* __restrict__ row_ptr,
                          const int* __restrict__ col_idx, const float* __restrict__ dinv,
                          ushort* __restrict__ out, int in_ld, int out_ld,
                          int V, int total) {
  int gid = blockIdx.x * blockDim.x + threadIdx.x;
  if (gid >= total) return;
  int n = gid / V, v = gid - n * V;
  const float din = dinv[n];
  const ushort4* hv = (const ushort4*)h;
  const int ivs = in_ld >> 2;
  float4 a;
  {
    ushort4 u = hv[(size_t)n * ivs + v];
    a.x = din * b2f(u.x); a.y = din * b2f(u.y);
    a.z = din * b2f(u.z); a.w = din * b2f(u.w);
  }
  const int beg = row_ptr[n], end = row_ptr[n + 1];
  int e = beg;
  for (; e + 3 < end; e += 4) {
    int s0 = col_idx[e], s1 = col_idx[e + 1], s2 = col_idx[e + 2], s3 = col_idx[e + 3];
    float d0 = dinv[s0], d1 = dinv[s1], d2 = dinv[s2], d3 = dinv[s3];
    ushort4 u0 = hv[(size_t)s0 * ivs + v], u1 = hv[(size_t)s1 * ivs + v];
    ushort4 u2 = hv[(size_t)s2 * ivs + v], u3 = hv[(size_t)s3 * ivs + v];
    a.x += d0 * b2f(u0.x) + d1 * b2f(u1.x) + d2 * b2f(u2.x) + d3 * b2f(u3.x);
    a.y += d0 * b2f(u0.y) + d1 * b2f(u1.y) + d2 * b2f(u2.y) + d3 * b2f(u3.y);
    a.z += d0 * b2f(u0.z) + d1 * b2f(u1.z) + d2 * b2f(u2.z) + d3 * b2f(u3.z);
    a.w += d0 * b2f(u0.w) + d1 * b2f(u1.w) + d2 * b2f(u2.w) + d3 * b2f(u3.w);
  }
  for (; e < end; ++e) {
    int s0 = col_idx[e];
    float d0 = dinv[s0];
    ushort4 u0 = hv[(size_t)s0 * ivs + v];
    a.x += d0 * b2f(u0.x); a.y += d0 * b2f(u0.y);
    a.z += d0 * b2f(u0.z); a.w += d0 * b2f(u0.w);
  }
  ushort4 o;
  o.x = f2b(din * a.x); o.y = f2b(din * a.y);
  o.z = f2b(din * a.z); o.w = f2b(din * a.w);
  ((ushort4*)(out + (size_t)n * out_ld))[v] = o;
}

// ---- two-stage max pool ----
__global__ void pool_part_kernel(const float* __restrict__ x, int xld,
                                 const int* __restrict__ s1, const int* __restrict__ s2,
                                 float* __restrict__ part, int V, int total) {
  int gid = blockIdx.x * blockDim.x + threadIdx.x;
  if (gid >= total) return;
  int v = gid % V;
  int gc = gid / V;
  int g = gc / POOL_NC, c = gc - g * POOL_NC;
  const int* st = (g < N_GRAPH) ? s1 : s2;
  int gi = g & (N_GRAPH - 1);
  int beg = st[gi], end = st[gi + 1];
  float4 m0 = make_float4(0.f, 0.f, 0.f, 0.f);
  float4 m1 = make_float4(0.f, 0.f, 0.f, 0.f);
  int nn = beg + c;
  for (; nn + POOL_NC < end; nn += 2 * POOL_NC) {
    float4 a = ((const float4*)(x + (size_t)nn * xld))[v];
    float4 b = ((const float4*)(x + (size_t)(nn + POOL_NC) * xld))[v];
    m0.x = fmaxf(m0.x, a.x); m0.y = fmaxf(m0.y, a.y);
    m0.z = fmaxf(m0.z, a.z); m0.w = fmaxf(m0.w, a.w);
    m1.x = fmaxf(m1.x, b.x); m1.y = fmaxf(m1.y, b.y);
    m1.z = fmaxf(m1.z, b.z); m1.w = fmaxf(m1.w, b.w);
  }
  if (nn < end) {
    float4 a = ((const float4*)(x + (size_t)nn * xld))[v];
    m0.x = fmaxf(m0.x, a.x); m0.y = fmaxf(m0.y, a.y);
    m0.z = fmaxf(m0.z, a.z); m0.w = fmaxf(m0.w, a.w);
  }
  float4 m;
  m.x = fmaxf(m0.x, m1.x); m.y = fmaxf(m0.y, m1.y);
  m.z = fmaxf(m0.z, m1.z); m.w = fmaxf(m0.w, m1.w);
  ((float4*)(part + (size_t)gc * (V * 4)))[v] = m;
}

__global__ void pool_combine_kernel(const float* __restrict__ part,
                                    float* __restrict__ pooled, int V, int total,
                                    int pool_base) {
  int gid = blockIdx.x * blockDim.x + threadIdx.x;
  if (gid >= total) return;
  int v = gid % V, g = gid / V;
  float4 m = make_float4(0.f, 0.f, 0.f, 0.f);
#pragma unroll
  for (int c = 0; c < POOL_NC; ++c) {
    float4 a = ((const float4*)(part + (size_t)(g * POOL_NC + c) * (V * 4)))[v];
    m.x = fmaxf(m.x, a.x); m.y = fmaxf(m.y, a.y);
    m.z = fmaxf(m.z, a.z); m.w = fmaxf(m.w, a.w);
  }
  ((float4*)(pooled + (size_t)(pool_base + g) * (V * 4)))[v] = m;
}

__global__ void rownorm_kernel(const float* __restrict__ cell, float* __restrict__ cv,
                               int F, int out_ld) {
  int g = blockIdx.x;
  __shared__ float red[256];
  int tid = threadIdx.x;
  const float* row = cell + (size_t)g * F;
  float s = 0.f;
  for (int f = tid; f < F; f += 256) { float v = row[f]; s += v * v; }
  red[tid] = s;
  __syncthreads();
  for (int off = 128; off > 0; off >>= 1) {
    if (tid < off) red[tid] += red[tid + off];
    __syncthreads();
  }
  float inv = 1.f / fmaxf(sqrtf(red[0]), 1e-12f);
  float* orow = cv + (size_t)g * out_ld;
  for (int f = tid; f < F; f += 256) orow[f] = row[f] * inv;
  for (int f = F + tid; f < out_ld; f += 256) orow[f] = 0.f;
}

// ------------------------- launcher -------------------------
extern "C" void kernel_launch(void* const* d_in, const int* in_sizes, int n_in,
                              void* d_out, int out_size, void* d_ws, size_t ws_size,
                              hipStream_t stream) {
  (void)in_sizes; (void)n_in; (void)out_size;
  const float* x1  = (const float*)d_in[0];
  const int*   ei1 = (const int*)d_in[1];
  const int*   bt1 = (const int*)d_in[2];
  const float* x2  = (const float*)d_in[3];
  const int*   ei2 = (const int*)d_in[4];
  const int*   bt2 = (const int*)d_in[5];
  const float* cell = (const float*)d_in[6];
  const float* Wc1 = (const float*)d_in[7];  const float* bc1 = (const float*)d_in[8];
  const float* Wc2 = (const float*)d_in[9];  const float* bc2 = (const float*)d_in[10];
  const float* Wc3 = (const float*)d_in[11]; const float* bc3 = (const float*)d_in[12];
  const float* Wg1 = (const float*)d_in[13]; const float* bg1 = (const float*)d_in[14];
  const float* Wg2 = (const float*)d_in[15]; const float* bg2 = (const float*)d_in[16];
  const float* Wr1 = (const float*)d_in[17]; const float* br1 = (const float*)d_in[18];
  const float* Wr2 = (const float*)d_in[19]; const float* br2 = (const float*)d_in[20];
  const float* Wr3 = (const float*)d_in[21]; const float* br3 = (const float*)d_in[22];
  const float* Wf1 = (const float*)d_in[23]; const float* bf1 = (const float*)d_in[24];
  const float* Wf2 = (const float*)d_in[25]; const float* bf2 = (const float*)d_in[26];
  const float* Wf3 = (const float*)d_in[27]; const float* bf3 = (const float*)d_in[28];
  const float* Wo  = (const float*)d_in[29]; const float* bo  = (const float*)d_in[30];
  float* out = (float*)d_out;

  const bool batched = ws_size >= (size_t)95 * 1024 * 1024;
  const int NPASS = batched ? 2 : 1;
  const int NN = NPASS * N_NODES;

  char* ws = (char*)d_ws;
  size_t off = 0;
  auto alloc_f = [&](size_t ne) { float* p = (float*)(ws + off); off += ne * 4; return p; };
  auto alloc_i = [&](size_t ne) { int* p = (int*)(ws + off); off += ne * 4; return p; };
  float* xbuf   = alloc_f((size_t)NN * 320);            // L3 fp32 out; aliases accb, xb16w
  ushort* ab16  = (ushort*)alloc_f((size_t)NN * 80);    // bf16 agg out, ld 96 / 160
  ushort* xb16s = (ushort*)alloc_f((size_t)NN * 40);    // bf16 h, ld 80 (L1-2 src)
  float* dinv   = alloc_f(NN);
  float* pooled = alloc_f((size_t)512 * 312);
  float* ppart  = alloc_f((size_t)512 * POOL_NC * 312);
  float* cvbuf  = alloc_f((size_t)N_GRAPH * 960);
  float* gtmp1  = alloc_f((size_t)512 * 2048);
  float* gtmp2  = alloc_f((size_t)512 * 512);
  float* gtmp3  = alloc_f((size_t)N_GRAPH * 256);
  float* catbuf = alloc_f((size_t)N_GRAPH * 512);
  ushort* wc1t  = (ushort*)alloc_f(128 * 96 / 2);
  ushort* wc2t  = (ushort*)alloc_f(192 * 96 / 2);
  ushort* wc3t  = (ushort*)alloc_f(320 * 160 / 2);
  int* cnt     = alloc_i(NN);
  int* row_ptr = alloc_i(NN + 1);
  int* cursor  = alloc_i(NN);
  int* col_idx = alloc_i(NPASS * N_EDGES);
  int* part    = alloc_i(64);
  int* start1  = alloc_i(N_GRAPH + 1);
  int* start2  = alloc_i(N_GRAPH + 1);
  float* accb  = xbuf;                    // split-K partials (MLP runs after pooling)
  ushort* xb16w = (ushort*)xbuf;          // bf16 h, ld 160 (L3 src)

  auto gemm_small = [&](const float* A, int lda, const float* B, int ldb, float* C, int ldc,
                        const float* bias, int Nr, int K, int M, int relu) {
    dim3 grid((M + 63) / 64, (Nr + 63) / 64, 1);
    gemm_t<64, 64, 4, 4><<<grid, 256, 0, stream>>>(A, lda, B, ldb, C, ldc, 0, bias,
                                                   Nr, K, M, relu, K);
  };
  auto splitk = [&](const float* A, int lda, const float* B, int M_, int K_, int S,
                    const float* bias, float* dst, int ldd, int relu, int Nr) {
    int kchunk = (((K_ + S - 1) / S) + 15) / 16 * 16;
    int Sz = (K_ + kchunk - 1) / kchunk;
    dim3 grid((M_ + 63) / 64, (Nr + 63) / 64, Sz);
    gemm_t<64, 64, 4, 4><<<grid, 256, 0, stream>>>(A, lda, B, M_, accb, M_, Nr * M_,
                                                   nullptr, Nr, K_, M_, 0, kchunk);
    int tot = Nr * M_;
    bias_sum_kernel<<<(tot + 255) / 256, 256, 0, stream>>>(accb, Nr * M_, Sz, dst, ldd,
                                                           bias, Nr, M_, relu);
  };
  auto mfma = [&](const ushort* A, int lda, const ushort* Bt, int ldbt, void* C, int ldc,
                  const float* bias, int Nr, int Kpad, int M, int relu, int obf) {
    int Cc = (M + 63) / 64, R = (Nr + 127) / 128, RR = (R + 7) >> 3;
    dim3 grid(8 * RR * Cc, 1, 1);
    gemm_mfma<<<grid, 256, 0, stream>>>(A, lda, Bt, ldbt, C, ldc, bias, Nr, Kpad, M, relu, obf);
  };

  // one-time weight convert+transpose (shared across branches)
  {
    int tot = 128 * 96 + 192 * 96 + 320 * 160;
    wcvt_kernel<<<(tot + 255) / 256, 256, 0, stream>>>(Wc1, Wc2, Wc3, wc1t, wc2t, wc3t);
  }

  auto drug_pass = [&](const float* xa, const float* xb, const int* eia, const int* eib,
                       const int* bta, const int* btb, int npass, int pool_base) {
    const int nn = npass * N_NODES;
    const int te = npass * N_EDGES;
    const int nb = (nn + 1023) / 1024;
    hipMemsetAsync(cnt, 0, nn * sizeof(int), stream);
    hist2_kernel<<<(te + 255) / 256, 256, 0, stream>>>(eia, eib, cnt, N_EDGES, npass);
    scan1_kernel<<<nb, 1024, 0, stream>>>(cnt, row_ptr, part, nn);
    scan23_kernel<<<(nn + 255) / 256, 256, 0, stream>>>(cnt, row_ptr, part, cursor, dinv,
                                                        nn, te, bta, btb, start1, start2);
    scatter2_kernel<<<(te + 255) / 256, 256, 0, stream>>>(eia, eib, cursor, col_idx, N_EDGES, npass);
    // x -> bf16 (ld 80), virtual concat
    {
      int tot = nn * 20;
      tobf16_kernel<<<(tot + 255) / 256, 256, 0, stream>>>(
          xa, xb, (npass == 2) ? N_NODES : nn, xb16s, tot);
    }
    // layer 1: agg(bf16 ld80) -> ab16 ld96 -> MFMA 78->78 (Kpad 96) -> bf16 xb16s ld80
    {
      int tot = nn * 20;
      aggb_flat<<<(tot + 255) / 256, 256, 0, stream>>>(xb16s, row_ptr, col_idx, dinv,
                                                       ab16, 80, 96, 20, tot);
    }
    mfma(ab16, 96, wc1t, 96, xb16s, 80, bc1, nn, 96, 78, 1, 1);
    // layer 2: agg(bf16 ld80) -> ab16 ld96 -> MFMA 78->156 -> bf16 xb16w ld160
    {
      int tot = nn * 20;
      aggb_flat<<<(tot + 255) / 256, 256, 0, stream>>>(xb16s, row_ptr, col_idx, dinv,
                                                       ab16, 80, 96, 20, tot);
    }
    mfma(ab16, 96, wc2t, 96, xb16w, 160, bc2, nn, 96, 156, 1, 1);
    // layer 3: agg(bf16 ld160) -> ab16 ld160 -> MFMA 156->312 (Kpad 160) -> fp32 xbuf ld320
    {
      int tot = nn * 40;
      aggb_flat<<<(tot + 255) / 256, 256, 0, stream>>>(xb16w, row_ptr, col_idx, dinv,
                                                       ab16, 160, 160, 40, tot);
    }
    mfma(ab16, 160, wc3t, 160, xbuf, 320, bc3, nn, 160, 312, 1, 0);
    // two-stage pool (V = 78 float4 slots)
    {
      int totp = npass * N_GRAPH * POOL_NC * 78;
      pool_part_kernel<<<(totp + 255) / 256, 256, 0, stream>>>(xbuf, 320, start1, start2,
                                                               ppart, 78, totp);
      int totc = npass * N_GRAPH * 78;
      pool_combine_kernel<<<(totc + 255) / 256, 256, 0, stream>>>(ppart, pooled, 78, totc,
                                                                  pool_base);
    }
  };

  if (batched) {
    drug_pass(x1, x2, ei1, ei2, bt1, bt2, 2, 0);
  } else {
    drug_pass(x1, x1, ei1, ei1, bt1, bt1, 1, 0);
    drug_pass(x2, x2, ei2, ei2, bt2, bt2, 1, N_GRAPH);
  }

  // drug head (512 rows, shared weights); Wg2 straight into catbuf halves
  splitk(pooled, 312, Wg1, 156, 312, 4, bg1, gtmp1, 156, 1, 2 * N_GRAPH);
  splitk(gtmp1, 156, Wg2, 128, 156, 2, bg2, catbuf, 512, 0, N_GRAPH);
  splitk(gtmp1 + (size_t)N_GRAPH * 156, 156, Wg2, 128, 156, 2, bg2, catbuf + 128, 512, 0,
         N_GRAPH);

  // cell branch + head MLP
  rownorm_kernel<<<N_GRAPH, 256, 0, stream>>>(cell, cvbuf, 954, 960);
  splitk(cvbuf, 960, Wr1, 2048, 954, 8,   br1, gtmp1, 2048, 1, N_GRAPH);
  splitk(gtmp1, 2048, Wr2, 512, 2048, 32, br2, gtmp2, 512, 1, N_GRAPH);
  splitk(gtmp2, 512, Wr3, 256, 512, 16,   br3, catbuf + 256, 512, 1, N_GRAPH);
  splitk(catbuf, 512, Wf1, 1024, 512, 16, bf1, gtmp1, 1024, 1, N_GRAPH);
  splitk(gtmp1, 1024, Wf2, 512, 1024, 32, bf2, gtmp2, 512, 1, N_GRAPH);
  splitk(gtmp2, 512, Wf3, 128, 512, 32,   bf3, gtmp3, 128, 1, N_GRAPH);
  gemm_small(gtmp3, 128, Wo, 2, out, 2, bo, N_GRAPH, 128, 2, 0);
}

// Round 15
// 471.073 us; speedup vs baseline: 1.5344x; 1.0440x over previous
//
#include <hip/hip_runtime.h>

#define N_NODES 20000
#define N_EDGES 320000
#define N_GRAPH 256
#define POOL_NC 8

__device__ __forceinline__ ushort f2b(float f) {  // fp32 -> bf16 RNE
  unsigned u = __float_as_uint(f);
  u += 0x7FFFu + ((u >> 16) & 1u);
  return (ushort)(u >> 16);
}
__device__ __forceinline__ float b2f(ushort u) {
  return __uint_as_float(((unsigned)u) << 16);
}

typedef __attribute__((ext_vector_type(8))) short bf16x8;
typedef __attribute__((ext_vector_type(4))) float f32x4;

// ---------------- bf16 MFMA GEMM ----------------
// A[Nr][lda] bf16 row-major; Bt[M][ldbt] bf16 = B transposed (k contiguous).
// kchunk==Kpad, zstride==0: direct C = op(A@B + bias) (fp32 or bf16 via obf).
// zstride>0: split-K — block z plain-stores fp32 partial to C + z*zstride.
// swz: XCD-aware 1D-grid swizzle (R12) — use only when row-blocks >= 8.
// Block 128x64, 4 waves, 2x4 mfma_f32_16x16x32_bf16 tiles per wave.
__launch_bounds__(256)
__global__ void gemm_mfma(const ushort* __restrict__ A, int lda,
                          const ushort* __restrict__ Bt, int ldbt,
                          void* __restrict__ Cv, int ldc, int zstride,
                          const float* __restrict__ bias,
                          int Nr, int Kpad, int M, int do_relu, int obf,
                          int kchunk, int swz) {
  constexpr int BM = 128, BN = 64, BK = 32, LK = 40;
  __shared__ __align__(16) ushort Asl[BM][LK];
  __shared__ __align__(16) ushort Bsl[BN][LK];
  const int tid = threadIdx.x;
  int bx, by;
  if (swz) {
    const int Cc = (M + BN - 1) / BN;
    const int R = (Nr + BM - 1) / BM;
    const int RR = (R + 7) >> 3;
    const int xz = blockIdx.x & 7, g = blockIdx.x >> 3;
    const int q = g / Cc;
    by = xz * RR + q;
    bx = g - q * Cc;
    if (by >= R) return;
  } else {
    bx = blockIdx.x; by = blockIdx.y;
  }
  const int row0 = by * BM, col0 = bx * BN;

  const int lane = tid & 63, w = tid >> 6;
  const int a_r = tid >> 1, a_h = tid & 1;        // A: row, 32B half
  const int b_r = tid >> 2, b_o = (tid & 3) * 8;  // B: row, 16B quarter

  const int klo = blockIdx.z * kchunk;
  const int khi = min(klo + kchunk, Kpad);
  const int nst = (khi - klo) / BK;

  uint4 pa0, pa1, pb0;
  auto load_tile = [&](int k0) {
    if (row0 + a_r < Nr) {
      const uint4* p = (const uint4*)(A + (size_t)(row0 + a_r) * lda + k0 + a_h * 16);
      pa0 = p[0]; pa1 = p[1];
    } else {
      pa0 = make_uint4(0u, 0u, 0u, 0u); pa1 = pa0;
    }
    pb0 = *(const uint4*)(Bt + (size_t)(col0 + b_r) * ldbt + k0 + b_o);
  };
  auto commit = [&]() {
    *(uint4*)&Asl[a_r][a_h * 16] = pa0;
    *(uint4*)&Asl[a_r][a_h * 16 + 8] = pa1;
    *(uint4*)&Bsl[b_r][b_o] = pb0;
  };

  f32x4 acc[2][4] = {};
  const int mrow = w * 32;
  const int lm = lane & 15, lq = (lane >> 4) * 8;

  load_tile(klo);
  for (int t = 0; t < nst; ++t) {
    commit();
    __syncthreads();
    if (t + 1 < nst) load_tile(klo + (t + 1) * BK);
    bf16x8 af0 = *(const bf16x8*)&Asl[mrow + lm][lq];
    bf16x8 af1 = *(const bf16x8*)&Asl[mrow + 16 + lm][lq];
    bf16x8 bf0 = *(const bf16x8*)&Bsl[lm][lq];
    bf16x8 bf1 = *(const bf16x8*)&Bsl[16 + lm][lq];
    bf16x8 bf2 = *(const bf16x8*)&Bsl[32 + lm][lq];
    bf16x8 bf3 = *(const bf16x8*)&Bsl[48 + lm][lq];
    acc[0][0] = __builtin_amdgcn_mfma_f32_16x16x32_bf16(af0, bf0, acc[0][0], 0, 0, 0);
    acc[0][1] = __builtin_amdgcn_mfma_f32_16x16x32_bf16(af0, bf1, acc[0][1], 0, 0, 0);
    acc[0][2] = __builtin_amdgcn_mfma_f32_16x16x32_bf16(af0, bf2, acc[0][2], 0, 0, 0);
    acc[0][3] = __builtin_amdgcn_mfma_f32_16x16x32_bf16(af0, bf3, acc[0][3], 0, 0, 0);
    acc[1][0] = __builtin_amdgcn_mfma_f32_16x16x32_bf16(af1, bf0, acc[1][0], 0, 0, 0);
    acc[1][1] = __builtin_amdgcn_mfma_f32_16x16x32_bf16(af1, bf1, acc[1][1], 0, 0, 0);
    acc[1][2] = __builtin_amdgcn_mfma_f32_16x16x32_bf16(af1, bf2, acc[1][2], 0, 0, 0);
    acc[1][3] = __builtin_amdgcn_mfma_f32_16x16x32_bf16(af1, bf3, acc[1][3], 0, 0, 0);
    __syncthreads();
  }

  const int rquad = (lane >> 4) * 4;
  if (zstride) {  // split-K fp32 partial store
    float* Cz = (float*)Cv + (size_t)blockIdx.z * zstride;
#pragma unroll
    for (int mt = 0; mt < 2; ++mt)
#pragma unroll
      for (int nt = 0; nt < 4; ++nt) {
        const int cc = col0 + nt * 16 + lm;
        if (cc >= M) continue;
#pragma unroll
        for (int r = 0; r < 4; ++r) {
          const int rr = row0 + mrow + mt * 16 + rquad + r;
          if (rr < Nr) Cz[(size_t)rr * ldc + cc] = acc[mt][nt][r];
        }
      }
    return;
  }
#pragma unroll
  for (int mt = 0; mt < 2; ++mt) {
#pragma unroll
    for (int nt = 0; nt < 4; ++nt) {
      const int cc = col0 + nt * 16 + lm;
      if (cc >= M) continue;
      const float bv = bias ? bias[cc] : 0.f;
#pragma unroll
      for (int r = 0; r < 4; ++r) {
        const int rr = row0 + mrow + mt * 16 + rquad + r;
        if (rr >= Nr) continue;
        float v = acc[mt][nt][r] + bv;
        if (do_relu) v = fmaxf(v, 0.f);
        if (obf) ((ushort*)Cv)[(size_t)rr * ldc + cc] = f2b(v);
        else     ((float*)Cv)[(size_t)rr * ldc + cc] = v;
      }
    }
  }
}

// node-layer weights -> bf16 transposed, zero-padded
__global__ void wcvt_kernel(const float* __restrict__ W1, const float* __restrict__ W2,
                            const float* __restrict__ W3, ushort* __restrict__ T1,
                            ushort* __restrict__ T2, ushort* __restrict__ T3) {
  int gid = blockIdx.x * blockDim.x + threadIdx.x;
  if (gid < 128 * 96) {
    int n = gid / 96, k = gid - n * 96;
    T1[gid] = (n < 78 && k < 78) ? f2b(W1[k * 78 + n]) : 0;
  } else if (gid < 128 * 96 + 192 * 96) {
    int g = gid - 128 * 96;
    int n = g / 96, k = g - n * 96;
    T2[g] = (n < 156 && k < 78) ? f2b(W2[k * 156 + n]) : 0;
  } else if (gid < 128 * 96 + 192 * 96 + 320 * 160) {
    int g = gid - 128 * 96 - 192 * 96;
    int n = g / 160, k = g - n * 160;
    T3[g] = (n < 312 && k < 156) ? f2b(W3[k * 312 + n]) : 0;
  }
}

// MLP weights -> bf16 transposed: T1[2048][960]<-Wr1[954][2048],
// T2[512][2048]<-Wr2[2048][512], T3[1024][512]<-Wf1[512][1024]
__global__ void wcvt2_kernel(const float* __restrict__ Wr1, const float* __restrict__ Wr2,
                             const float* __restrict__ Wf1, ushort* __restrict__ T1,
                             ushort* __restrict__ T2, ushort* __restrict__ T3) {
  const int S1 = 2048 * 960, S2 = 512 * 2048, S3 = 1024 * 512;
  int gid = blockIdx.x * blockDim.x + threadIdx.x;
  if (gid < S1) {
    int n = gid / 960, k = gid - n * 960;
    T1[gid] = (k < 954) ? f2b(Wr1[(size_t)k * 2048 + n]) : 0;
  } else if (gid < S1 + S2) {
    int g = gid - S1;
    int n = g / 2048, k = g - n * 2048;
    T2[g] = f2b(Wr2[(size_t)k * 512 + n]);
  } else if (gid < S1 + S2 + S3) {
    int g = gid - S1 - S2;
    int n = g / 512, k = g - n * 512;
    T3[g] = f2b(Wf1[(size_t)k * 1024 + n]);
  }
}

// ------------------- fp32 tiled GEMM (small/remaining layers; pinned) -------------------
template<int BM, int BN, int TM, int TN>
__launch_bounds__(256)
__global__ void gemm_t(const float* __restrict__ A, int lda,
                       const float* __restrict__ B, int ldb,
                       float* __restrict__ C, int ldc, int zstride,
                       const float* __restrict__ bias,
                       int Nr, int K, int M, int do_relu, int kchunk) {
  constexpr int BK = 16;
  constexpr int LDA = BM + 4;
  __shared__ __align__(16) float As[BK][LDA];
  __shared__ __align__(16) float Bs[BK][BN];
  const int tid = threadIdx.x;
  const int row0 = blockIdx.y * BM, col0 = blockIdx.x * BN;
  constexpr int NX = BN / TN;
  const int tx = tid % NX, ty = tid / NX;
  float acc[TM][TN] = {};
  const int klo = blockIdx.z * kchunk;
  const int khi = min(klo + kchunk, K);

  constexpr int AIT = BM * BK / 4 / 256;
  constexpr int BIT = BK * BN / 4 / 256;
  float4 pa[AIT], pb[BIT];

  auto load_tile = [&](int k0) {
#pragma unroll
    for (int it = 0; it < AIT; ++it) {
      const int s = it * 256 + tid;
      const int row = s >> 2, kq = (s & 3) << 2;
      float4 av = make_float4(0.f, 0.f, 0.f, 0.f);
      const int gr = row0 + row, gk = k0 + kq;
      if (gr < Nr) {
        const float* Ap = A + (size_t)gr * lda + gk;
        if (gk + 3 < khi) { av.x = Ap[0]; av.y = Ap[1]; av.z = Ap[2]; av.w = Ap[3]; }
        else {
          if (gk     < khi) av.x = Ap[0];
          if (gk + 1 < khi) av.y = Ap[1];
          if (gk + 2 < khi) av.z = Ap[2];
        }
      }
      pa[it] = av;
    }
#pragma unroll
    for (int it = 0; it < BIT; ++it) {
      const int s = it * 256 + tid;
      const int kr = s / (BN / 4), c = (s % (BN / 4)) << 2;
      float4 bv = make_float4(0.f, 0.f, 0.f, 0.f);
      const int gk = k0 + kr, gc = col0 + c;
      if (gk < khi) {
        const float* Bp = B + (size_t)gk * ldb + gc;
        if (gc + 3 < M) { bv.x = Bp[0]; bv.y = Bp[1]; bv.z = Bp[2]; bv.w = Bp[3]; }
        else {
          if (gc     < M) bv.x = Bp[0];
          if (gc + 1 < M) bv.y = Bp[1];
          if (gc + 2 < M) bv.z = Bp[2];
        }
      }
      pb[it] = bv;
    }
  };

  load_tile(klo);
  for (int k0 = klo; k0 < khi; k0 += BK) {
#pragma unroll
    for (int it = 0; it < AIT; ++it) {
      const int s = it * 256 + tid;
      const int row = s >> 2, kq = (s & 3) << 2;
      As[kq    ][row] = pa[it].x;
      As[kq + 1][row] = pa[it].y;
      As[kq + 2][row] = pa[it].z;
      As[kq + 3][row] = pa[it].w;
    }
#pragma unroll
    for (int it = 0; it < BIT; ++it) {
      const int s = it * 256 + tid;
      const int kr = s / (BN / 4), c = (s % (BN / 4)) << 2;
      *(float4*)&Bs[kr][c] = pb[it];
    }
    __syncthreads();
    if (k0 + BK < khi) load_tile(k0 + BK);
#pragma unroll
    for (int kk = 0; kk < BK; ++kk) {
      float ar[TM], br[TN];
#pragma unroll
      for (int i = 0; i < TM; i += 4)
        *(float4*)&ar[i] = *(const float4*)&As[kk][ty * TM + i];
      if constexpr (TN == 8) {
        *(float4*)&br[0] = *(const float4*)&Bs[kk][tx * 4];
        *(float4*)&br[4] = *(const float4*)&Bs[kk][BN / 2 + tx * 4];
      } else {
        *(float4*)&br[0] = *(const float4*)&Bs[kk][tx * TN];
      }
#pragma unroll
      for (int i = 0; i < TM; ++i)
#pragma unroll
        for (int j = 0; j < TN; ++j)
          acc[i][j] += ar[i] * br[j];
    }
    __syncthreads();
  }

  float* Cz = C + (size_t)blockIdx.z * zstride;
#pragma unroll
  for (int i = 0; i < TM; ++i) {
    const int r = row0 + ty * TM + i;
    if (r >= Nr) continue;
    float* Crow = Cz + (size_t)r * ldc;
#pragma unroll
    for (int g = 0; g < TN / 4; ++g) {
      const int c = col0 + (TN == 8 ? g * (BN / 2) : 0) + tx * 4;
      if (c + 3 < M) {
        float4 v;
        v.x = acc[i][g * 4 + 0]; v.y = acc[i][g * 4 + 1];
        v.z = acc[i][g * 4 + 2]; v.w = acc[i][g * 4 + 3];
        if (bias) { v.x += bias[c]; v.y += bias[c + 1]; v.z += bias[c + 2]; v.w += bias[c + 3]; }
        if (do_relu) {
          v.x = fmaxf(v.x, 0.f); v.y = fmaxf(v.y, 0.f);
          v.z = fmaxf(v.z, 0.f); v.w = fmaxf(v.w, 0.f);
        }
        *(float4*)&Crow[c] = v;
      } else {
#pragma unroll
        for (int j = 0; j < 4; ++j) {
          if (c + j >= M) continue;
          float v = acc[i][g * 4 + j];
          if (bias) v += bias[c + j];
          if (do_relu) v = fmaxf(v, 0.f);
          Crow[c + j] = v;
        }
      }
    }
  }
}

// sum Sz split-K fp32 partials + bias (+relu); write fp32 or bf16 (obf)
__global__ void bias_sum_kernel(const float* __restrict__ src, int zs, int Sz,
                                void* __restrict__ dstv, int ldd,
                                const float* __restrict__ bias,
                                int Nr, int M, int do_relu, int obf) {
  int idx = blockIdx.x * blockDim.x + threadIdx.x;
  if (idx >= Nr * M) return;
  int r = idx / M, c = idx - r * M;
  float v = bias[c];
  for (int z = 0; z < Sz; ++z) v += src[idx + (size_t)z * zs];
  if (do_relu) v = fmaxf(v, 0.f);
  if (obf) ((ushort*)dstv)[(size_t)r * ldd + c] = f2b(v);
  else     ((float*)dstv)[(size_t)r * ldd + c] = v;
}

// ------------------------- graph prep -------------------------
__global__ void hist2_kernel(const int* __restrict__ e1, const int* __restrict__ e2,
                             int* __restrict__ cnt, int E, int npass) {
  int e = blockIdx.x * blockDim.x + threadIdx.x;
  if (e < E) atomicAdd(&cnt[e1[E + e]], 1);
  else if (e < npass * E) atomicAdd(&cnt[N_NODES + e2[E + e - E]], 1);
}

__launch_bounds__(1024)
__global__ void scan1_kernel(const int* __restrict__ cnt, int* __restrict__ row_ptr,
                             int* __restrict__ part, int n) {
  __shared__ int sh[1024];
  const int tid = threadIdx.x;
  const int i = blockIdx.x * 1024 + tid;
  const int v = (i < n) ? cnt[i] : 0;
  sh[tid] = v;
  __syncthreads();
#pragma unroll
  for (int off = 1; off < 1024; off <<= 1) {
    int t = (tid >= off) ? sh[tid - off] : 0;
    __syncthreads();
    sh[tid] += t;
    __syncthreads();
  }
  if (i < n) row_ptr[i] = sh[tid] - v;
  if (tid == 1023) part[blockIdx.x] = sh[tid];
}

__global__ void scan23_kernel(const int* __restrict__ cnt, int* __restrict__ row_ptr,
                              const int* __restrict__ part, int* __restrict__ cursor,
                              float* __restrict__ dinv, int n, int total,
                              const int* __restrict__ b1, const int* __restrict__ b2,
                              int* __restrict__ s1, int* __restrict__ s2) {
  __shared__ int base_sh;
  const int tid = threadIdx.x;
  if (tid == 0) {
    int blk = blockIdx.x >> 2;
    int s = 0;
    for (int b = 0; b < blk; ++b) s += part[b];
    base_sh = s;
  }
  __syncthreads();
  int i = blockIdx.x * 256 + tid;
  if (i >= n) return;
  int rp = row_ptr[i] + base_sh;
  row_ptr[i] = rp;
  cursor[i] = rp;
  dinv[i] = rsqrtf((float)(cnt[i] + 1));
  if (i == 0) row_ptr[n] = total;
  if (i < N_NODES) {
    if (i == 0) { s1[0] = 0; s1[N_GRAPH] = N_NODES; }
    else if (b1[i] != b1[i - 1]) s1[b1[i]] = i;
  } else {
    int j = i - N_NODES;
    if (j == 0) { s2[0] = N_NODES; s2[N_GRAPH] = 2 * N_NODES; }
    else if (b2[j] != b2[j - 1]) s2[b2[j]] = N_NODES + j;
  }
}

// col_idx is ushort: node ids < 65536 — halves scatter write amplification
__global__ void scatter2_kernel(const int* __restrict__ e1, const int* __restrict__ e2,
                                int* __restrict__ cursor, ushort* __restrict__ col_idx,
                                int E, int npass) {
  int e = blockIdx.x * blockDim.x + threadIdx.x;
  if (e < E) {
    int p = atomicAdd(&cursor[e1[E + e]], 1);
    col_idx[p] = (ushort)e1[e];
  } else if (e < npass * E) {
    int j = e - E;
    int p = atomicAdd(&cursor[N_NODES + e2[E + j]], 1);
    col_idx[p] = (ushort)(N_NODES + e2[j]);
  }
}

// ---- x1/x2 fp32 (ld 78) -> concat bf16 buffer (ld 80, pads zeroed) ----
__global__ void tobf16_kernel(const float* __restrict__ xa, const float* __restrict__ xb,
                              int nsplit, ushort* __restrict__ dst, int total) {
  int gid = blockIdx.x * blockDim.x + threadIdx.x;
  if (gid >= total) return;
  int n = gid / 20, v = gid - n * 20;
  const float* src = (n < nsplit) ? xa + (size_t)n * 78 : xb + (size_t)(n - nsplit) * 78;
  int f0 = v * 4;
  ushort4 o;
  o.x = (f0     < 78) ? f2b(src[f0])     : 0;
  o.y = (f0 + 1 < 78) ? f2b(src[f0 + 1]) : 0;
  o.z = (f0 + 2 < 78) ? f2b(src[f0 + 2]) : 0;
  o.w = (f0 + 3 < 78) ? f2b(src[f0 + 3]) : 0;
  ((ushort4*)(dst + (size_t)n * 80))[v] = o;
}

// ---- normalized aggregation: bf16 gather, fp32 math, bf16 output ----
__global__ void aggb_flat(const ushort* __restrict__ h, const int* __restrict__ row_ptr,
                          const ushort* __restrict__ col_idx, const float* __restrict__ dinv,
                          ushort* __restrict__ out, int in_ld, int out_ld,
                          int V, int total) {
  int gid = blockIdx.x * blockDim.x + threadIdx.x;
  if (gid >= total) return;
  int n = gid / V, v = gid - n * V;
  const float din = dinv[n];
  const ushort4* hv = (const ushort4*)h;
  const int ivs = in_ld >> 2;
  float4 a;
  {
    ushort4 u = hv[(size_t)n * ivs + v];
    a.x = din * b2f(u.x); a.y = din * b2f(u.y);
    a.z = din * b2f(u.z); a.w = din * b2f(u.w);
  }
  const int beg = row_ptr[n], end = row_ptr[n + 1];
  int e = beg;
  for (; e + 3 < end; e += 4) {
    int s0 = col_idx[e], s1 = col_idx[e + 1], s2 = col_idx[e + 2], s3 = col_idx[e + 3];
    float d0 = dinv[s0], d1 = dinv[s1], d2 = dinv[s2], d3 = dinv[s3];
    ushort4 u0 = hv[(size_t)s0 * ivs + v], u1 = hv[(size_t)s1 * ivs + v];
    ushort4 u2 = hv[(size_t)s2 * ivs + v], u3 = hv[(size_t)s3 * ivs + v];
    a.x += d0 * b2f(u0.x) + d1 * b2f(u1.x) + d2 * b2f(u2.x) + d3 * b2f(u3.x);
    a.y += d0 * b2f(u0.y) + d1 * b2f(u1.y) + d2 * b2f(u2.y) + d3 * b2f(u3.y);
    a.z += d0 * b2f(u0.z) + d1 * b2f(u1.z) + d2 * b2f(u2.z) + d3 * b2f(u3.z);
    a.w += d0 * b2f(u0.w) + d1 * b2f(u1.w) + d2 * b2f(u2.w) + d3 * b2f(u3.w);
  }
  for (; e < end; ++e) {
    int s0 = col_idx[e];
    float d0 = dinv[s0];
    ushort4 u0 = hv[(size_t)s0 * ivs + v];
    a.x += d0 * b2f(u0.x); a.y += d0 * b2f(u0.y);
    a.z += d0 * b2f(u0.z); a.w += d0 * b2f(u0.w);
  }
  ushort4 o;
  o.x = f2b(din * a.x); o.y = f2b(din * a.y);
  o.z = f2b(din * a.z); o.w = f2b(din * a.w);
  ((ushort4*)(out + (size_t)n * out_ld))[v] = o;
}

// ---- two-stage max pool ----
__global__ void pool_part_kernel(const float* __restrict__ x, int xld,
                                 const int* __restrict__ s1, const int* __restrict__ s2,
                                 float* __restrict__ part, int V, int total) {
  int gid = blockIdx.x * blockDim.x + threadIdx.x;
  if (gid >= total) return;
  int v = gid % V;
  int gc = gid / V;
  int g = gc / POOL_NC, c = gc - g * POOL_NC;
  const int* st = (g < N_GRAPH) ? s1 : s2;
  int gi = g & (N_GRAPH - 1);
  int beg = st[gi], end = st[gi + 1];
  float4 m0 = make_float4(0.f, 0.f, 0.f, 0.f);
  float4 m1 = make_float4(0.f, 0.f, 0.f, 0.f);
  int nn = beg + c;
  for (; nn + POOL_NC < end; nn += 2 * POOL_NC) {
    float4 a = ((const float4*)(x + (size_t)nn * xld))[v];
    float4 b = ((const float4*)(x + (size_t)(nn + POOL_NC) * xld))[v];
    m0.x = fmaxf(m0.x, a.x); m0.y = fmaxf(m0.y, a.y);
    m0.z = fmaxf(m0.z, a.z); m0.w = fmaxf(m0.w, a.w);
    m1.x = fmaxf(m1.x, b.x); m1.y = fmaxf(m1.y, b.y);
    m1.z = fmaxf(m1.z, b.z); m1.w = fmaxf(m1.w, b.w);
  }
  if (nn < end) {
    float4 a = ((const float4*)(x + (size_t)nn * xld))[v];
    m0.x = fmaxf(m0.x, a.x); m0.y = fmaxf(m0.y, a.y);
    m0.z = fmaxf(m0.z, a.z); m0.w = fmaxf(m0.w, a.w);
  }
  float4 m;
  m.x = fmaxf(m0.x, m1.x); m.y = fmaxf(m0.y, m1.y);
  m.z = fmaxf(m0.z, m1.z); m.w = fmaxf(m0.w, m1.w);
  ((float4*)(part + (size_t)gc * (V * 4)))[v] = m;
}

__global__ void pool_combine_kernel(const float* __restrict__ part,
                                    float* __restrict__ pooled, int V, int total,
                                    int pool_base) {
  int gid = blockIdx.x * blockDim.x + threadIdx.x;
  if (gid >= total) return;
  int v = gid % V, g = gid / V;
  float4 m = make_float4(0.f, 0.f, 0.f, 0.f);
#pragma unroll
  for (int c = 0; c < POOL_NC; ++c) {
    float4 a = ((const float4*)(part + (size_t)(g * POOL_NC + c) * (V * 4)))[v];
    m.x = fmaxf(m.x, a.x); m.y = fmaxf(m.y, a.y);
    m.z = fmaxf(m.z, a.z); m.w = fmaxf(m.w, a.w);
  }
  ((float4*)(pooled + (size_t)(pool_base + g) * (V * 4)))[v] = m;
}

// row-normalize cell, write bf16 (ld out_ld, pads zeroed)
__global__ void rownorm_kernel(const float* __restrict__ cell, ushort* __restrict__ cv,
                               int F, int out_ld) {
  int g = blockIdx.x;
  __shared__ float red[256];
  int tid = threadIdx.x;
  const float* row = cell + (size_t)g * F;
  float s = 0.f;
  for (int f = tid; f < F; f += 256) { float v = row[f]; s += v * v; }
  red[tid] = s;
  __syncthreads();
  for (int off = 128; off > 0; off >>= 1) {
    if (tid < off) red[tid] += red[tid + off];
    __syncthreads();
  }
  float inv = 1.f / fmaxf(sqrtf(red[0]), 1e-12f);
  ushort* orow = cv + (size_t)g * out_ld;
  for (int f = tid; f < F; f += 256) orow[f] = f2b(row[f] * inv);
  for (int f = F + tid; f < out_ld; f += 256) orow[f] = 0;
}

// ------------------------- launcher -------------------------
extern "C" void kernel_launch(void* const* d_in, const int* in_sizes, int n_in,
                              void* d_out, int out_size, void* d_ws, size_t ws_size,
                              hipStream_t stream) {
  (void)in_sizes; (void)n_in; (void)out_size;
  const float* x1  = (const float*)d_in[0];
  const int*   ei1 = (const int*)d_in[1];
  const int*   bt1 = (const int*)d_in[2];
  const float* x2  = (const float*)d_in[3];
  const int*   ei2 = (const int*)d_in[4];
  const int*   bt2 = (const int*)d_in[5];
  const float* cell = (const float*)d_in[6];
  const float* Wc1 = (const float*)d_in[7];  const float* bc1 = (const float*)d_in[8];
  const float* Wc2 = (const float*)d_in[9];  const float* bc2 = (const float*)d_in[10];
  const float* Wc3 = (const float*)d_in[11]; const float* bc3 = (const float*)d_in[12];
  const float* Wg1 = (const float*)d_in[13]; const float* bg1 = (const float*)d_in[14];
  const float* Wg2 = (const float*)d_in[15]; const float* bg2 = (const float*)d_in[16];
  const float* Wr1 = (const float*)d_in[17]; const float* br1 = (const float*)d_in[18];
  const float* Wr2 = (const float*)d_in[19]; const float* br2 = (const float*)d_in[20];
  const float* Wr3 = (const float*)d_in[21]; const float* br3 = (const float*)d_in[22];
  const float* Wf1 = (const float*)d_in[23]; const float* bf1 = (const float*)d_in[24];
  const float* Wf2 = (const float*)d_in[25]; const float* bf2 = (const float*)d_in[26];
  const float* Wf3 = (const float*)d_in[27]; const float* bf3 = (const float*)d_in[28];
  const float* Wo  = (const float*)d_in[29]; const float* bo  = (const float*)d_in[30];
  float* out = (float*)d_out;

  const bool batched = ws_size >= (size_t)95 * 1024 * 1024;
  const int NPASS = batched ? 2 : 1;
  const int NN = NPASS * N_NODES;

  char* ws = (char*)d_ws;
  size_t off = 0;
  auto alloc_f = [&](size_t ne) { float* p = (float*)(ws + off); off += ne * 4; return p; };
  auto alloc_i = [&](size_t ne) { int* p = (int*)(ws + off); off += ne * 4; return p; };
  float* xbuf   = alloc_f((size_t)NN * 320);            // L3 fp32 out; aliases accb, xb16w
  ushort* ab16  = (ushort*)alloc_f((size_t)NN * 80);    // bf16 agg out, ld 96 / 160
  ushort* xb16s = (ushort*)alloc_f((size_t)NN * 40);    // bf16 h, ld 80 (L1-2 src)
  float* dinv   = alloc_f(NN);
  float* pooled = alloc_f((size_t)512 * 312);
  float* ppart  = alloc_f((size_t)512 * POOL_NC * 312);
  ushort* cv16  = (ushort*)alloc_f((size_t)N_GRAPH * 480);  // bf16 cell, ld 960
  float* gtmp1  = alloc_f((size_t)512 * 2048);
  float* gtmp2  = alloc_f((size_t)512 * 512);
  float* gtmp3  = alloc_f((size_t)N_GRAPH * 256);
  ushort* catbuf = (ushort*)alloc_f((size_t)N_GRAPH * 256);  // bf16, ld 512
  ushort* gt1b  = (ushort*)alloc_f((size_t)N_GRAPH * 1024);  // bf16 Wr1 out, ld 2048
  ushort* wc1t  = (ushort*)alloc_f(128 * 96 / 2);
  ushort* wc2t  = (ushort*)alloc_f(192 * 96 / 2);
  ushort* wc3t  = (ushort*)alloc_f(320 * 160 / 2);
  ushort* wr1t  = (ushort*)alloc_f(2048 * 960 / 2);
  ushort* wr2t  = (ushort*)alloc_f(512 * 2048 / 2);
  ushort* wf1t  = (ushort*)alloc_f(1024 * 512 / 2);
  int* cnt     = alloc_i(NN);
  int* row_ptr = alloc_i(NN + 1);
  int* cursor  = alloc_i(NN);
  ushort* col_idx = (ushort*)alloc_i(NPASS * N_EDGES / 2);
  int* part    = alloc_i(64);
  int* start1  = alloc_i(N_GRAPH + 1);
  int* start2  = alloc_i(N_GRAPH + 1);
  float* accb  = xbuf;                    // split-K fp32 partials (MLP runs after pooling)
  ushort* xb16w = (ushort*)xbuf;          // bf16 h, ld 160 (L3 src)

  auto gemm_small = [&](const float* A, int lda, const float* B, int ldb, float* C, int ldc,
                        const float* bias, int Nr, int K, int M, int relu) {
    dim3 grid((M + 63) / 64, (Nr + 63) / 64, 1);
    gemm_t<64, 64, 4, 4><<<grid, 256, 0, stream>>>(A, lda, B, ldb, C, ldc, 0, bias,
                                                   Nr, K, M, relu, K);
  };
  // fp32 split-K + bias/act (obf selects bf16 dst)
  auto splitk = [&](const float* A, int lda, const float* B, int M_, int K_, int S,
                    const float* bias, void* dst, int ldd, int relu, int Nr, int obf) {
    int kchunk = (((K_ + S - 1) / S) + 15) / 16 * 16;
    int Sz = (K_ + kchunk - 1) / kchunk;
    dim3 grid((M_ + 63) / 64, (Nr + 63) / 64, Sz);
    gemm_t<64, 64, 4, 4><<<grid, 256, 0, stream>>>(A, lda, B, M_, accb, M_, Nr * M_,
                                                   nullptr, Nr, K_, M_, 0, kchunk);
    int tot = Nr * M_;
    bias_sum_kernel<<<(tot + 255) / 256, 256, 0, stream>>>(accb, Nr * M_, Sz, dst, ldd,
                                                           bias, Nr, M_, relu, obf);
  };
  // MFMA direct (node layers; XCD swizzle)
  auto mfma = [&](const ushort* A, int lda, const ushort* Bt, int ldbt, void* C, int ldc,
                  const float* bias, int Nr, int Kpad, int M, int relu, int obf) {
    int Cc = (M + 63) / 64, R = (Nr + 127) / 128, RR = (R + 7) >> 3;
    dim3 grid(8 * RR * Cc, 1, 1);
    gemm_mfma<<<grid, 256, 0, stream>>>(A, lda, Bt, ldbt, C, ldc, 0, bias, Nr, Kpad, M,
                                        relu, obf, Kpad, 1);
  };
  // MFMA split-K (MLP big layers; 256 rows) + bias/act
  auto mfma_splitk = [&](const ushort* A, int lda, const ushort* Bt, int ldbt, int M_,
                         int Kpad, int kchunk, const float* bias, void* dst, int ldd,
                         int relu, int obf) {
    int Sz = (Kpad + kchunk - 1) / kchunk;
    dim3 grid((M_ + 63) / 64, 2, Sz);  // Nr=256 -> 2 row-blocks
    gemm_mfma<<<grid, 256, 0, stream>>>(A, lda, Bt, ldbt, accb, M_, N_GRAPH * M_, nullptr,
                                        N_GRAPH, Kpad, M_, 0, 0, kchunk, 0);
    int tot = N_GRAPH * M_;
    bias_sum_kernel<<<(tot + 255) / 256, 256, 0, stream>>>(accb, N_GRAPH * M_, Sz, dst, ldd,
                                                           bias, N_GRAPH, M_, relu, obf);
  };

  // one-time weight conversions (node layers + big MLP layers)
  {
    int tot = 128 * 96 + 192 * 96 + 320 * 160;
    wcvt_kernel<<<(tot + 255) / 256, 256, 0, stream>>>(Wc1, Wc2, Wc3, wc1t, wc2t, wc3t);
    int tot2 = 2048 * 960 + 512 * 2048 + 1024 * 512;
    wcvt2_kernel<<<(tot2 + 255) / 256, 256, 0, stream>>>(Wr1, Wr2, Wf1, wr1t, wr2t, wf1t);
  }

  auto drug_pass = [&](const float* xa, const float* xb, const int* eia, const int* eib,
                       const int* bta, const int* btb, int npass, int pool_base) {
    const int nn = npass * N_NODES;
    const int te = npass * N_EDGES;
    const int nb = (nn + 1023) / 1024;
    hipMemsetAsync(cnt, 0, nn * sizeof(int), stream);
    hist2_kernel<<<(te + 255) / 256, 256, 0, stream>>>(eia, eib, cnt, N_EDGES, npass);
    scan1_kernel<<<nb, 1024, 0, stream>>>(cnt, row_ptr, part, nn);
    scan23_kernel<<<(nn + 255) / 256, 256, 0, stream>>>(cnt, row_ptr, part, cursor, dinv,
                                                        nn, te, bta, btb, start1, start2);
    scatter2_kernel<<<(te + 255) / 256, 256, 0, stream>>>(eia, eib, cursor, col_idx, N_EDGES, npass);
    {
      int tot = nn * 20;
      tobf16_kernel<<<(tot + 255) / 256, 256, 0, stream>>>(
          xa, xb, (npass == 2) ? N_NODES : nn, xb16s, tot);
    }
    // layer 1: agg -> ab16 ld96 -> MFMA 78->78 (Kpad 96) -> bf16 xb16s ld80
    {
      int tot = nn * 20;
      aggb_flat<<<(tot + 255) / 256, 256, 0, stream>>>(xb16s, row_ptr, col_idx, dinv,
                                                       ab16, 80, 96, 20, tot);
    }
    mfma(ab16, 96, wc1t, 96, xb16s, 80, bc1, nn, 96, 78, 1, 1);
    // layer 2: agg -> ab16 ld96 -> MFMA 78->156 -> bf16 xb16w ld160
    {
      int tot = nn * 20;
      aggb_flat<<<(tot + 255) / 256, 256, 0, stream>>>(xb16s, row_ptr, col_idx, dinv,
                                                       ab16, 80, 96, 20, tot);
    }
    mfma(ab16, 96, wc2t, 96, xb16w, 160, bc2, nn, 96, 156, 1, 1);
    // layer 3: agg -> ab16 ld160 -> MFMA 156->312 (Kpad 160) -> fp32 xbuf ld320
    {
      int tot = nn * 40;
      aggb_flat<<<(tot + 255) / 256, 256, 0, stream>>>(xb16w, row_ptr, col_idx, dinv,
                                                       ab16, 160, 160, 40, tot);
    }
    mfma(ab16, 160, wc3t, 160, xbuf, 320, bc3, nn, 160, 312, 1, 0);
    // two-stage pool
    {
      int totp = npass * N_GRAPH * POOL_NC * 78;
      pool_part_kernel<<<(totp + 255) / 256, 256, 0, stream>>>(xbuf, 320, start1, start2,
                                                               ppart, 78, totp);
      int totc = npass * N_GRAPH * 78;
      pool_combine_kernel<<<(totc + 255) / 256, 256, 0, stream>>>(ppart, pooled, 78, totc,
                                                                  pool_base);
    }
  };

  if (batched) {
    drug_pass(x1, x2, ei1, ei2, bt1, bt2, 2, 0);
  } else {
    drug_pass(x1, x1, ei1, ei1, bt1, bt1, 1, 0);
    drug_pass(x2, x2, ei2, ei2, bt2, bt2, 1, N_GRAPH);
  }

  // drug head (512 rows, shared weights); Wg2 -> bf16 catbuf halves (ld 512)
  splitk(pooled, 312, Wg1, 156, 312, 4, bg1, gtmp1, 156, 1, 2 * N_GRAPH, 0);
  splitk(gtmp1, 156, Wg2, 128, 156, 2, bg2, catbuf, 512, 0, N_GRAPH, 1);
  splitk(gtmp1 + (size_t)N_GRAPH * 156, 156, Wg2, 128, 156, 2, bg2, catbuf + 128, 512, 0,
         N_GRAPH, 1);

  // cell branch: rownorm -> bf16; Wr1/Wr2 via MFMA split-K; Wr3 fp32 -> bf16 catbuf
  rownorm_kernel<<<N_GRAPH, 256, 0, stream>>>(cell, cv16, 954, 960);
  mfma_splitk(cv16, 960, wr1t, 960, 2048, 960, 256, br1, gt1b, 2048, 1, 1);
  mfma_splitk(gt1b, 2048, wr2t, 2048, 512, 2048, 256, br2, gtmp2, 512, 1, 0);
  splitk(gtmp2, 512, Wr3, 256, 512, 16, br3, catbuf + 256, 512, 1, N_GRAPH, 1);
  // head: Wf1 via MFMA split-K on bf16 catbuf; Wf2/Wf3/Wo fp32
  mfma_splitk(catbuf, 512, wf1t, 512, 1024, 512, 128, bf1, gtmp1, 1024, 1, 0);
  splitk(gtmp1, 1024, Wf2, 512, 1024, 32, bf2, gtmp2, 512, 1, N_GRAPH, 0);
  splitk(gtmp2, 512, Wf3, 128, 512, 32, bf3, gtmp3, 128, 1, N_GRAPH, 0);
  gemm_small(gtmp3, 128, Wo, 2, out, 2, bo, N_GRAPH, 128, 2, 0);
}

// Round 16
// 464.101 us; speedup vs baseline: 1.5575x; 1.0150x over previous
//
#include <hip/hip_runtime.h>

#define N_NODES 20000
#define N_EDGES 320000
#define N_GRAPH 256
#define POOL_NC 8
#define ECHUNK 2048

__device__ __forceinline__ ushort f2b(float f) {  // fp32 -> bf16 RNE
  unsigned u = __float_as_uint(f);
  u += 0x7FFFu + ((u >> 16) & 1u);
  return (ushort)(u >> 16);
}
__device__ __forceinline__ float b2f(ushort u) {
  return __uint_as_float(((unsigned)u) << 16);
}

typedef __attribute__((ext_vector_type(8))) short bf16x8;
typedef __attribute__((ext_vector_type(4))) float f32x4;

// ---------------- bf16 MFMA GEMM ----------------
// A[Nr][lda] bf16 row-major; Bt[M][ldbt] bf16 = B transposed (k contiguous).
// kchunk==Kpad, zstride==0: direct C = op(A@B + bias) (fp32 or bf16 via obf).
// zstride>0: split-K — block z plain-stores fp32 partial to C + z*zstride.
// swz: XCD-aware 1D-grid swizzle (R12) — use only when row-blocks >= 8.
__launch_bounds__(256)
__global__ void gemm_mfma(const ushort* __restrict__ A, int lda,
                          const ushort* __restrict__ Bt, int ldbt,
                          void* __restrict__ Cv, int ldc, int zstride,
                          const float* __restrict__ bias,
                          int Nr, int Kpad, int M, int do_relu, int obf,
                          int kchunk, int swz) {
  constexpr int BM = 128, BN = 64, BK = 32, LK = 40;
  __shared__ __align__(16) ushort Asl[BM][LK];
  __shared__ __align__(16) ushort Bsl[BN][LK];
  const int tid = threadIdx.x;
  int bx, by;
  if (swz) {
    const int Cc = (M + BN - 1) / BN;
    const int R = (Nr + BM - 1) / BM;
    const int RR = (R + 7) >> 3;
    const int xz = blockIdx.x & 7, g = blockIdx.x >> 3;
    const int q = g / Cc;
    by = xz * RR + q;
    bx = g - q * Cc;
    if (by >= R) return;
  } else {
    bx = blockIdx.x; by = blockIdx.y;
  }
  const int row0 = by * BM, col0 = bx * BN;

  const int lane = tid & 63, w = tid >> 6;
  const int a_r = tid >> 1, a_h = tid & 1;
  const int b_r = tid >> 2, b_o = (tid & 3) * 8;

  const int klo = blockIdx.z * kchunk;
  const int khi = min(klo + kchunk, Kpad);
  const int nst = (khi - klo) / BK;

  uint4 pa0, pa1, pb0;
  auto load_tile = [&](int k0) {
    if (row0 + a_r < Nr) {
      const uint4* p = (const uint4*)(A + (size_t)(row0 + a_r) * lda + k0 + a_h * 16);
      pa0 = p[0]; pa1 = p[1];
    } else {
      pa0 = make_uint4(0u, 0u, 0u, 0u); pa1 = pa0;
    }
    pb0 = *(const uint4*)(Bt + (size_t)(col0 + b_r) * ldbt + k0 + b_o);
  };
  auto commit = [&]() {
    *(uint4*)&Asl[a_r][a_h * 16] = pa0;
    *(uint4*)&Asl[a_r][a_h * 16 + 8] = pa1;
    *(uint4*)&Bsl[b_r][b_o] = pb0;
  };

  f32x4 acc[2][4] = {};
  const int mrow = w * 32;
  const int lm = lane & 15, lq = (lane >> 4) * 8;

  load_tile(klo);
  for (int t = 0; t < nst; ++t) {
    commit();
    __syncthreads();
    if (t + 1 < nst) load_tile(klo + (t + 1) * BK);
    bf16x8 af0 = *(const bf16x8*)&Asl[mrow + lm][lq];
    bf16x8 af1 = *(const bf16x8*)&Asl[mrow + 16 + lm][lq];
    bf16x8 bf0 = *(const bf16x8*)&Bsl[lm][lq];
    bf16x8 bf1 = *(const bf16x8*)&Bsl[16 + lm][lq];
    bf16x8 bf2 = *(const bf16x8*)&Bsl[32 + lm][lq];
    bf16x8 bf3 = *(const bf16x8*)&Bsl[48 + lm][lq];
    acc[0][0] = __builtin_amdgcn_mfma_f32_16x16x32_bf16(af0, bf0, acc[0][0], 0, 0, 0);
    acc[0][1] = __builtin_amdgcn_mfma_f32_16x16x32_bf16(af0, bf1, acc[0][1], 0, 0, 0);
    acc[0][2] = __builtin_amdgcn_mfma_f32_16x16x32_bf16(af0, bf2, acc[0][2], 0, 0, 0);
    acc[0][3] = __builtin_amdgcn_mfma_f32_16x16x32_bf16(af0, bf3, acc[0][3], 0, 0, 0);
    acc[1][0] = __builtin_amdgcn_mfma_f32_16x16x32_bf16(af1, bf0, acc[1][0], 0, 0, 0);
    acc[1][1] = __builtin_amdgcn_mfma_f32_16x16x32_bf16(af1, bf1, acc[1][1], 0, 0, 0);
    acc[1][2] = __builtin_amdgcn_mfma_f32_16x16x32_bf16(af1, bf2, acc[1][2], 0, 0, 0);
    acc[1][3] = __builtin_amdgcn_mfma_f32_16x16x32_bf16(af1, bf3, acc[1][3], 0, 0, 0);
    __syncthreads();
  }

  const int rquad = (lane >> 4) * 4;
  if (zstride) {
    float* Cz = (float*)Cv + (size_t)blockIdx.z * zstride;
#pragma unroll
    for (int mt = 0; mt < 2; ++mt)
#pragma unroll
      for (int nt = 0; nt < 4; ++nt) {
        const int cc = col0 + nt * 16 + lm;
        if (cc >= M) continue;
#pragma unroll
        for (int r = 0; r < 4; ++r) {
          const int rr = row0 + mrow + mt * 16 + rquad + r;
          if (rr < Nr) Cz[(size_t)rr * ldc + cc] = acc[mt][nt][r];
        }
      }
    return;
  }
#pragma unroll
  for (int mt = 0; mt < 2; ++mt) {
#pragma unroll
    for (int nt = 0; nt < 4; ++nt) {
      const int cc = col0 + nt * 16 + lm;
      if (cc >= M) continue;
      const float bv = bias ? bias[cc] : 0.f;
#pragma unroll
      for (int r = 0; r < 4; ++r) {
        const int rr = row0 + mrow + mt * 16 + rquad + r;
        if (rr >= Nr) continue;
        float v = acc[mt][nt][r] + bv;
        if (do_relu) v = fmaxf(v, 0.f);
        if (obf) ((ushort*)Cv)[(size_t)rr * ldc + cc] = f2b(v);
        else     ((float*)Cv)[(size_t)rr * ldc + cc] = v;
      }
    }
  }
}

// node-layer weights -> bf16 transposed, zero-padded
__global__ void wcvt_kernel(const float* __restrict__ W1, const float* __restrict__ W2,
                            const float* __restrict__ W3, ushort* __restrict__ T1,
                            ushort* __restrict__ T2, ushort* __restrict__ T3) {
  int gid = blockIdx.x * blockDim.x + threadIdx.x;
  if (gid < 128 * 96) {
    int n = gid / 96, k = gid - n * 96;
    T1[gid] = (n < 78 && k < 78) ? f2b(W1[k * 78 + n]) : 0;
  } else if (gid < 128 * 96 + 192 * 96) {
    int g = gid - 128 * 96;
    int n = g / 96, k = g - n * 96;
    T2[g] = (n < 156 && k < 78) ? f2b(W2[k * 156 + n]) : 0;
  } else if (gid < 128 * 96 + 192 * 96 + 320 * 160) {
    int g = gid - 128 * 96 - 192 * 96;
    int n = g / 160, k = g - n * 160;
    T3[g] = (n < 312 && k < 156) ? f2b(W3[k * 312 + n]) : 0;
  }
}

// MLP weights -> bf16 transposed
__global__ void wcvt2_kernel(const float* __restrict__ Wr1, const float* __restrict__ Wr2,
                             const float* __restrict__ Wf1, ushort* __restrict__ T1,
                             ushort* __restrict__ T2, ushort* __restrict__ T3) {
  const int S1 = 2048 * 960, S2 = 512 * 2048, S3 = 1024 * 512;
  int gid = blockIdx.x * blockDim.x + threadIdx.x;
  if (gid < S1) {
    int n = gid / 960, k = gid - n * 960;
    T1[gid] = (k < 954) ? f2b(Wr1[(size_t)k * 2048 + n]) : 0;
  } else if (gid < S1 + S2) {
    int g = gid - S1;
    int n = g / 2048, k = g - n * 2048;
    T2[g] = f2b(Wr2[(size_t)k * 512 + n]);
  } else if (gid < S1 + S2 + S3) {
    int g = gid - S1 - S2;
    int n = g / 512, k = g - n * 512;
    T3[g] = f2b(Wf1[(size_t)k * 1024 + n]);
  }
}

// ------------------- fp32 tiled GEMM (small/remaining layers; pinned) -------------------
template<int BM, int BN, int TM, int TN>
__launch_bounds__(256)
__global__ void gemm_t(const float* __restrict__ A, int lda,
                       const float* __restrict__ B, int ldb,
                       float* __restrict__ C, int ldc, int zstride,
                       const float* __restrict__ bias,
                       int Nr, int K, int M, int do_relu, int kchunk) {
  constexpr int BK = 16;
  constexpr int LDA = BM + 4;
  __shared__ __align__(16) float As[BK][LDA];
  __shared__ __align__(16) float Bs[BK][BN];
  const int tid = threadIdx.x;
  const int row0 = blockIdx.y * BM, col0 = blockIdx.x * BN;
  constexpr int NX = BN / TN;
  const int tx = tid % NX, ty = tid / NX;
  float acc[TM][TN] = {};
  const int klo = blockIdx.z * kchunk;
  const int khi = min(klo + kchunk, K);

  constexpr int AIT = BM * BK / 4 / 256;
  constexpr int BIT = BK * BN / 4 / 256;
  float4 pa[AIT], pb[BIT];

  auto load_tile = [&](int k0) {
#pragma unroll
    for (int it = 0; it < AIT; ++it) {
      const int s = it * 256 + tid;
      const int row = s >> 2, kq = (s & 3) << 2;
      float4 av = make_float4(0.f, 0.f, 0.f, 0.f);
      const int gr = row0 + row, gk = k0 + kq;
      if (gr < Nr) {
        const float* Ap = A + (size_t)gr * lda + gk;
        if (gk + 3 < khi) { av.x = Ap[0]; av.y = Ap[1]; av.z = Ap[2]; av.w = Ap[3]; }
        else {
          if (gk     < khi) av.x = Ap[0];
          if (gk + 1 < khi) av.y = Ap[1];
          if (gk + 2 < khi) av.z = Ap[2];
        }
      }
      pa[it] = av;
    }
#pragma unroll
    for (int it = 0; it < BIT; ++it) {
      const int s = it * 256 + tid;
      const int kr = s / (BN / 4), c = (s % (BN / 4)) << 2;
      float4 bv = make_float4(0.f, 0.f, 0.f, 0.f);
      const int gk = k0 + kr, gc = col0 + c;
      if (gk < khi) {
        const float* Bp = B + (size_t)gk * ldb + gc;
        if (gc + 3 < M) { bv.x = Bp[0]; bv.y = Bp[1]; bv.z = Bp[2]; bv.w = Bp[3]; }
        else {
          if (gc     < M) bv.x = Bp[0];
          if (gc + 1 < M) bv.y = Bp[1];
          if (gc + 2 < M) bv.z = Bp[2];
        }
      }
      pb[it] = bv;
    }
  };

  load_tile(klo);
  for (int k0 = klo; k0 < khi; k0 += BK) {
#pragma unroll
    for (int it = 0; it < AIT; ++it) {
      const int s = it * 256 + tid;
      const int row = s >> 2, kq = (s & 3) << 2;
      As[kq    ][row] = pa[it].x;
      As[kq + 1][row] = pa[it].y;
      As[kq + 2][row] = pa[it].z;
      As[kq + 3][row] = pa[it].w;
    }
#pragma unroll
    for (int it = 0; it < BIT; ++it) {
      const int s = it * 256 + tid;
      const int kr = s / (BN / 4), c = (s % (BN / 4)) << 2;
      *(float4*)&Bs[kr][c] = pb[it];
    }
    __syncthreads();
    if (k0 + BK < khi) load_tile(k0 + BK);
#pragma unroll
    for (int kk = 0; kk < BK; ++kk) {
      float ar[TM], br[TN];
#pragma unroll
      for (int i = 0; i < TM; i += 4)
        *(float4*)&ar[i] = *(const float4*)&As[kk][ty * TM + i];
      if constexpr (TN == 8) {
        *(float4*)&br[0] = *(const float4*)&Bs[kk][tx * 4];
        *(float4*)&br[4] = *(const float4*)&Bs[kk][BN / 2 + tx * 4];
      } else {
        *(float4*)&br[0] = *(const float4*)&Bs[kk][tx * TN];
      }
#pragma unroll
      for (int i = 0; i < TM; ++i)
#pragma unroll
        for (int j = 0; j < TN; ++j)
          acc[i][j] += ar[i] * br[j];
    }
    __syncthreads();
  }

  float* Cz = C + (size_t)blockIdx.z * zstride;
#pragma unroll
  for (int i = 0; i < TM; ++i) {
    const int r = row0 + ty * TM + i;
    if (r >= Nr) continue;
    float* Crow = Cz + (size_t)r * ldc;
#pragma unroll
    for (int g = 0; g < TN / 4; ++g) {
      const int c = col0 + (TN == 8 ? g * (BN / 2) : 0) + tx * 4;
      if (c + 3 < M) {
        float4 v;
        v.x = acc[i][g * 4 + 0]; v.y = acc[i][g * 4 + 1];
        v.z = acc[i][g * 4 + 2]; v.w = acc[i][g * 4 + 3];
        if (bias) { v.x += bias[c]; v.y += bias[c + 1]; v.z += bias[c + 2]; v.w += bias[c + 3]; }
        if (do_relu) {
          v.x = fmaxf(v.x, 0.f); v.y = fmaxf(v.y, 0.f);
          v.z = fmaxf(v.z, 0.f); v.w = fmaxf(v.w, 0.f);
        }
        *(float4*)&Crow[c] = v;
      } else {
#pragma unroll
        for (int j = 0; j < 4; ++j) {
          if (c + j >= M) continue;
          float v = acc[i][g * 4 + j];
          if (bias) v += bias[c + j];
          if (do_relu) v = fmaxf(v, 0.f);
          Crow[c + j] = v;
        }
      }
    }
  }
}

// sum Sz split-K fp32 partials + bias (+relu); write fp32 or bf16 (obf)
__global__ void bias_sum_kernel(const float* __restrict__ src, int zs, int Sz,
                                void* __restrict__ dstv, int ldd,
                                const float* __restrict__ bias,
                                int Nr, int M, int do_relu, int obf) {
  int idx = blockIdx.x * blockDim.x + threadIdx.x;
  if (idx >= Nr * M) return;
  int r = idx / M, c = idx - r * M;
  float v = bias[c];
  for (int z = 0; z < Sz; ++z) v += src[idx + (size_t)z * zs];
  if (do_relu) v = fmaxf(v, 0.f);
  if (obf) ((ushort*)dstv)[(size_t)r * ldd + c] = f2b(v);
  else     ((float*)dstv)[(size_t)r * ldd + c] = v;
}

// ------------------------- graph prep (XCD-partitioned by dst range) -------------------------
// Block b handles dst range [(b&7)*rng, ...): cursor atomics + col_idx writes for one
// range issue from one XCD (R12-verified %8 mapping) -> no cross-XCD line ping-pong.
// Correctness does NOT depend on the mapping (device-scope atomics). 8x edge re-read.
__global__ void histp_kernel(const int* __restrict__ e1, const int* __restrict__ e2,
                             int* __restrict__ cnt, int E, int npass, int rng) {
  const int xcd = blockIdx.x & 7;
  const int lo = xcd * rng, hi = lo + rng;
  const int base = (blockIdx.x >> 3) * ECHUNK;
  const int TE = npass * E;
  for (int i = threadIdx.x; i < ECHUNK; i += 256) {
    int e = base + i;
    if (e >= TE) break;
    int d = (e < E) ? e1[E + e] : N_NODES + e2[e - E + E];
    if (d >= lo && d < hi) atomicAdd(&cnt[d], 1);
  }
}

__global__ void scatterp_kernel(const int* __restrict__ e1, const int* __restrict__ e2,
                                int* __restrict__ cursor, ushort* __restrict__ col_idx,
                                int E, int npass, int rng) {
  const int xcd = blockIdx.x & 7;
  const int lo = xcd * rng, hi = lo + rng;
  const int base = (blockIdx.x >> 3) * ECHUNK;
  const int TE = npass * E;
  for (int i = threadIdx.x; i < ECHUNK; i += 256) {
    int e = base + i;
    if (e >= TE) break;
    int d, s;
    if (e < E) { d = e1[E + e]; s = e1[e]; }
    else { int j = e - E; d = N_NODES + e2[E + j]; s = N_NODES + e2[j]; }
    if (d >= lo && d < hi) {
      int p = atomicAdd(&cursor[d], 1);
      col_idx[p] = (ushort)s;
    }
  }
}

__launch_bounds__(1024)
__global__ void scan1_kernel(const int* __restrict__ cnt, int* __restrict__ row_ptr,
                             int* __restrict__ part, int n) {
  __shared__ int sh[1024];
  const int tid = threadIdx.x;
  const int i = blockIdx.x * 1024 + tid;
  const int v = (i < n) ? cnt[i] : 0;
  sh[tid] = v;
  __syncthreads();
#pragma unroll
  for (int off = 1; off < 1024; off <<= 1) {
    int t = (tid >= off) ? sh[tid - off] : 0;
    __syncthreads();
    sh[tid] += t;
    __syncthreads();
  }
  if (i < n) row_ptr[i] = sh[tid] - v;
  if (tid == 1023) part[blockIdx.x] = sh[tid];
}

__global__ void scan23_kernel(const int* __restrict__ cnt, int* __restrict__ row_ptr,
                              const int* __restrict__ part, int* __restrict__ cursor,
                              float* __restrict__ dinv, int n, int total,
                              const int* __restrict__ b1, const int* __restrict__ b2,
                              int* __restrict__ s1, int* __restrict__ s2) {
  __shared__ int base_sh;
  const int tid = threadIdx.x;
  if (tid == 0) {
    int blk = blockIdx.x >> 2;
    int s = 0;
    for (int b = 0; b < blk; ++b) s += part[b];
    base_sh = s;
  }
  __syncthreads();
  int i = blockIdx.x * 256 + tid;
  if (i >= n) return;
  int rp = row_ptr[i] + base_sh;
  row_ptr[i] = rp;
  cursor[i] = rp;
  dinv[i] = rsqrtf((float)(cnt[i] + 1));
  if (i == 0) row_ptr[n] = total;
  if (i < N_NODES) {
    if (i == 0) { s1[0] = 0; s1[N_GRAPH] = N_NODES; }
    else if (b1[i] != b1[i - 1]) s1[b1[i]] = i;
  } else {
    int j = i - N_NODES;
    if (j == 0) { s2[0] = N_NODES; s2[N_GRAPH] = 2 * N_NODES; }
    else if (b2[j] != b2[j - 1]) s2[b2[j]] = N_NODES + j;
  }
}

// ---- x1/x2 fp32 (ld 78) -> concat bf16 buffer (ld 80, pads zeroed) ----
__global__ void tobf16_kernel(const float* __restrict__ xa, const float* __restrict__ xb,
                              int nsplit, ushort* __restrict__ dst, int total) {
  int gid = blockIdx.x * blockDim.x + threadIdx.x;
  if (gid >= total) return;
  int n = gid / 20, v = gid - n * 20;
  const float* src = (n < nsplit) ? xa + (size_t)n * 78 : xb + (size_t)(n - nsplit) * 78;
  int f0 = v * 4;
  ushort4 o;
  o.x = (f0     < 78) ? f2b(src[f0])     : 0;
  o.y = (f0 + 1 < 78) ? f2b(src[f0 + 1]) : 0;
  o.z = (f0 + 2 < 78) ? f2b(src[f0 + 2]) : 0;
  o.w = (f0 + 3 < 78) ? f2b(src[f0 + 3]) : 0;
  ((ushort4*)(dst + (size_t)n * 80))[v] = o;
}

// ---- normalized aggregation: bf16 gather, fp32 math, bf16 output ----
__global__ void aggb_flat(const ushort* __restrict__ h, const int* __restrict__ row_ptr,
                          const ushort* __restrict__ col_idx, const float* __restrict__ dinv,
                          ushort* __restrict__ out, int in_ld, int out_ld,
                          int V, int total) {
  int gid = blockIdx.x * blockDim.x + threadIdx.x;
  if (gid >= total) return;
  int n = gid / V, v = gid - n * V;
  const float din = dinv[n];
  const ushort4* hv = (const ushort4*)h;
  const int ivs = in_ld >> 2;
  float4 a;
  {
    ushort4 u = hv[(size_t)n * ivs + v];
    a.x = din * b2f(u.x); a.y = din * b2f(u.y);
    a.z = din * b2f(u.z); a.w = din * b2f(u.w);
  }
  const int beg = row_ptr[n], end = row_ptr[n + 1];
  int e = beg;
  for (; e + 3 < end; e += 4) {
    int s0 = col_idx[e], s1 = col_idx[e + 1], s2 = col_idx[e + 2], s3 = col_idx[e + 3];
    float d0 = dinv[s0], d1 = dinv[s1], d2 = dinv[s2], d3 = dinv[s3];
    ushort4 u0 = hv[(size_t)s0 * ivs + v], u1 = hv[(size_t)s1 * ivs + v];
    ushort4 u2 = hv[(size_t)s2 * ivs + v], u3 = hv[(size_t)s3 * ivs + v];
    a.x += d0 * b2f(u0.x) + d1 * b2f(u1.x) + d2 * b2f(u2.x) + d3 * b2f(u3.x);
    a.y += d0 * b2f(u0.y) + d1 * b2f(u1.y) + d2 * b2f(u2.y) + d3 * b2f(u3.y);
    a.z += d0 * b2f(u0.z) + d1 * b2f(u1.z) + d2 * b2f(u2.z) + d3 * b2f(u3.z);
    a.w += d0 * b2f(u0.w) + d1 * b2f(u1.w) + d2 * b2f(u2.w) + d3 * b2f(u3.w);
  }
  for (; e < end; ++e) {
    int s0 = col_idx[e];
    float d0 = dinv[s0];
    ushort4 u0 = hv[(size_t)s0 * ivs + v];
    a.x += d0 * b2f(u0.x); a.y += d0 * b2f(u0.y);
    a.z += d0 * b2f(u0.z); a.w += d0 * b2f(u0.w);
  }
  ushort4 o;
  o.x = f2b(din * a.x); o.y = f2b(din * a.y);
  o.z = f2b(din * a.z); o.w = f2b(din * a.w);
  ((ushort4*)(out + (size_t)n * out_ld))[v] = o;
}

// ---- two-stage max pool ----
__global__ void pool_part_kernel(const float* __restrict__ x, int xld,
                                 const int* __restrict__ s1, const int* __restrict__ s2,
                                 float* __restrict__ part, int V, int total) {
  int gid = blockIdx.x * blockDim.x + threadIdx.x;
  if (gid >= total) return;
  int v = gid % V;
  int gc = gid / V;
  int g = gc / POOL_NC, c = gc - g * POOL_NC;
  const int* st = (g < N_GRAPH) ? s1 : s2;
  int gi = g & (N_GRAPH - 1);
  int beg = st[gi], end = st[gi + 1];
  float4 m0 = make_float4(0.f, 0.f, 0.f, 0.f);
  float4 m1 = make_float4(0.f, 0.f, 0.f, 0.f);
  int nn = beg + c;
  for (; nn + POOL_NC < end; nn += 2 * POOL_NC) {
    float4 a = ((const float4*)(x + (size_t)nn * xld))[v];
    float4 b = ((const float4*)(x + (size_t)(nn + POOL_NC) * xld))[v];
    m0.x = fmaxf(m0.x, a.x); m0.y = fmaxf(m0.y, a.y);
    m0.z = fmaxf(m0.z, a.z); m0.w = fmaxf(m0.w, a.w);
    m1.x = fmaxf(m1.x, b.x); m1.y = fmaxf(m1.y, b.y);
    m1.z = fmaxf(m1.z, b.z); m1.w = fmaxf(m1.w, b.w);
  }
  if (nn < end) {
    float4 a = ((const float4*)(x + (size_t)nn * xld))[v];
    m0.x = fmaxf(m0.x, a.x); m0.y = fmaxf(m0.y, a.y);
    m0.z = fmaxf(m0.z, a.z); m0.w = fmaxf(m0.w, a.w);
  }
  float4 m;
  m.x = fmaxf(m0.x, m1.x); m.y = fmaxf(m0.y, m1.y);
  m.z = fmaxf(m0.z, m1.z); m.w = fmaxf(m0.w, m1.w);
  ((float4*)(part + (size_t)gc * (V * 4)))[v] = m;
}

__global__ void pool_combine_kernel(const float* __restrict__ part,
                                    float* __restrict__ pooled, int V, int total,
                                    int pool_base) {
  int gid = blockIdx.x * blockDim.x + threadIdx.x;
  if (gid >= total) return;
  int v = gid % V, g = gid / V;
  float4 m = make_float4(0.f, 0.f, 0.f, 0.f);
#pragma unroll
  for (int c = 0; c < POOL_NC; ++c) {
    float4 a = ((const float4*)(part + (size_t)(g * POOL_NC + c) * (V * 4)))[v];
    m.x = fmaxf(m.x, a.x); m.y = fmaxf(m.y, a.y);
    m.z = fmaxf(m.z, a.z); m.w = fmaxf(m.w, a.w);
  }
  ((float4*)(pooled + (size_t)(pool_base + g) * (V * 4)))[v] = m;
}

// row-normalize cell, write bf16 (ld out_ld, pads zeroed)
__global__ void rownorm_kernel(const float* __restrict__ cell, ushort* __restrict__ cv,
                               int F, int out_ld) {
  int g = blockIdx.x;
  __shared__ float red[256];
  int tid = threadIdx.x;
  const float* row = cell + (size_t)g * F;
  float s = 0.f;
  for (int f = tid; f < F; f += 256) { float v = row[f]; s += v * v; }
  red[tid] = s;
  __syncthreads();
  for (int off = 128; off > 0; off >>= 1) {
    if (tid < off) red[tid] += red[tid + off];
    __syncthreads();
  }
  float inv = 1.f / fmaxf(sqrtf(red[0]), 1e-12f);
  ushort* orow = cv + (size_t)g * out_ld;
  for (int f = tid; f < F; f += 256) orow[f] = f2b(row[f] * inv);
  for (int f = F + tid; f < out_ld; f += 256) orow[f] = 0;
}

// ------------------------- launcher -------------------------
extern "C" void kernel_launch(void* const* d_in, const int* in_sizes, int n_in,
                              void* d_out, int out_size, void* d_ws, size_t ws_size,
                              hipStream_t stream) {
  (void)in_sizes; (void)n_in; (void)out_size;
  const float* x1  = (const float*)d_in[0];
  const int*   ei1 = (const int*)d_in[1];
  const int*   bt1 = (const int*)d_in[2];
  const float* x2  = (const float*)d_in[3];
  const int*   ei2 = (const int*)d_in[4];
  const int*   bt2 = (const int*)d_in[5];
  const float* cell = (const float*)d_in[6];
  const float* Wc1 = (const float*)d_in[7];  const float* bc1 = (const float*)d_in[8];
  const float* Wc2 = (const float*)d_in[9];  const float* bc2 = (const float*)d_in[10];
  const float* Wc3 = (const float*)d_in[11]; const float* bc3 = (const float*)d_in[12];
  const float* Wg1 = (const float*)d_in[13]; const float* bg1 = (const float*)d_in[14];
  const float* Wg2 = (const float*)d_in[15]; const float* bg2 = (const float*)d_in[16];
  const float* Wr1 = (const float*)d_in[17]; const float* br1 = (const float*)d_in[18];
  const float* Wr2 = (const float*)d_in[19]; const float* br2 = (const float*)d_in[20];
  const float* Wr3 = (const float*)d_in[21]; const float* br3 = (const float*)d_in[22];
  const float* Wf1 = (const float*)d_in[23]; const float* bf1 = (const float*)d_in[24];
  const float* Wf2 = (const float*)d_in[25]; const float* bf2 = (const float*)d_in[26];
  const float* Wf3 = (const float*)d_in[27]; const float* bf3 = (const float*)d_in[28];
  const float* Wo  = (const float*)d_in[29]; const float* bo  = (const float*)d_in[30];
  float* out = (float*)d_out;

  const bool batched = ws_size >= (size_t)95 * 1024 * 1024;
  const int NPASS = batched ? 2 : 1;
  const int NN = NPASS * N_NODES;

  char* ws = (char*)d_ws;
  size_t off = 0;
  auto alloc_f = [&](size_t ne) { float* p = (float*)(ws + off); off += ne * 4; return p; };
  auto alloc_i = [&](size_t ne) { int* p = (int*)(ws + off); off += ne * 4; return p; };
  float* xbuf   = alloc_f((size_t)NN * 320);            // L3 fp32 out; aliases accb, xb16w
  ushort* ab16  = (ushort*)alloc_f((size_t)NN * 80);    // bf16 agg out, ld 96 / 160
  ushort* xb16s = (ushort*)alloc_f((size_t)NN * 40);    // bf16 h, ld 80 (L1-2 src)
  float* dinv   = alloc_f(NN);
  float* pooled = alloc_f((size_t)512 * 312);
  float* ppart  = alloc_f((size_t)512 * POOL_NC * 312);
  ushort* cv16  = (ushort*)alloc_f((size_t)N_GRAPH * 480);  // bf16 cell, ld 960
  float* gtmp1  = alloc_f((size_t)512 * 2048);
  float* gtmp2  = alloc_f((size_t)512 * 512);
  float* gtmp3  = alloc_f((size_t)N_GRAPH * 256);
  ushort* catbuf = (ushort*)alloc_f((size_t)N_GRAPH * 256);  // bf16, ld 512
  ushort* gt1b  = (ushort*)alloc_f((size_t)N_GRAPH * 1024);  // bf16 Wr1 out, ld 2048
  ushort* wc1t  = (ushort*)alloc_f(128 * 96 / 2);
  ushort* wc2t  = (ushort*)alloc_f(192 * 96 / 2);
  ushort* wc3t  = (ushort*)alloc_f(320 * 160 / 2);
  ushort* wr1t  = (ushort*)alloc_f(2048 * 960 / 2);
  ushort* wr2t  = (ushort*)alloc_f(512 * 2048 / 2);
  ushort* wf1t  = (ushort*)alloc_f(1024 * 512 / 2);
  int* cnt     = alloc_i(NN);
  int* row_ptr = alloc_i(NN + 1);
  int* cursor  = alloc_i(NN);
  ushort* col_idx = (ushort*)alloc_i(NPASS * N_EDGES / 2);
  int* part    = alloc_i(64);
  int* start1  = alloc_i(N_GRAPH + 1);
  int* start2  = alloc_i(N_GRAPH + 1);
  float* accb  = xbuf;                    // split-K fp32 partials (MLP runs after pooling)
  ushort* xb16w = (ushort*)xbuf;          // bf16 h, ld 160 (L3 src)

  auto gemm_small = [&](const float* A, int lda, const float* B, int ldb, float* C, int ldc,
                        const float* bias, int Nr, int K, int M, int relu) {
    dim3 grid((M + 63) / 64, (Nr + 63) / 64, 1);
    gemm_t<64, 64, 4, 4><<<grid, 256, 0, stream>>>(A, lda, B, ldb, C, ldc, 0, bias,
                                                   Nr, K, M, relu, K);
  };
  auto splitk = [&](const float* A, int lda, const float* B, int M_, int K_, int S,
                    const float* bias, void* dst, int ldd, int relu, int Nr, int obf) {
    int kchunk = (((K_ + S - 1) / S) + 15) / 16 * 16;
    int Sz = (K_ + kchunk - 1) / kchunk;
    dim3 grid((M_ + 63) / 64, (Nr + 63) / 64, Sz);
    gemm_t<64, 64, 4, 4><<<grid, 256, 0, stream>>>(A, lda, B, M_, accb, M_, Nr * M_,
                                                   nullptr, Nr, K_, M_, 0, kchunk);
    int tot = Nr * M_;
    bias_sum_kernel<<<(tot + 255) / 256, 256, 0, stream>>>(accb, Nr * M_, Sz, dst, ldd,
                                                           bias, Nr, M_, relu, obf);
  };
  auto mfma = [&](const ushort* A, int lda, const ushort* Bt, int ldbt, void* C, int ldc,
                  const float* bias, int Nr, int Kpad, int M, int relu, int obf) {
    int Cc = (M + 63) / 64, R = (Nr + 127) / 128, RR = (R + 7) >> 3;
    dim3 grid(8 * RR * Cc, 1, 1);
    gemm_mfma<<<grid, 256, 0, stream>>>(A, lda, Bt, ldbt, C, ldc, 0, bias, Nr, Kpad, M,
                                        relu, obf, Kpad, 1);
  };
  auto mfma_splitk = [&](const ushort* A, int lda, const ushort* Bt, int ldbt, int M_,
                         int Kpad, int kchunk, const float* bias, void* dst, int ldd,
                         int relu, int obf) {
    int Sz = (Kpad + kchunk - 1) / kchunk;
    dim3 grid((M_ + 63) / 64, 2, Sz);  // Nr=256 -> 2 row-blocks
    gemm_mfma<<<grid, 256, 0, stream>>>(A, lda, Bt, ldbt, accb, M_, N_GRAPH * M_, nullptr,
                                        N_GRAPH, Kpad, M_, 0, 0, kchunk, 0);
    int tot = N_GRAPH * M_;
    bias_sum_kernel<<<(tot + 255) / 256, 256, 0, stream>>>(accb, N_GRAPH * M_, Sz, dst, ldd,
                                                           bias, N_GRAPH, M_, relu, obf);
  };

  // one-time weight conversions
  {
    int tot = 128 * 96 + 192 * 96 + 320 * 160;
    wcvt_kernel<<<(tot + 255) / 256, 256, 0, stream>>>(Wc1, Wc2, Wc3, wc1t, wc2t, wc3t);
    int tot2 = 2048 * 960 + 512 * 2048 + 1024 * 512;
    wcvt2_kernel<<<(tot2 + 255) / 256, 256, 0, stream>>>(Wr1, Wr2, Wf1, wr1t, wr2t, wf1t);
  }

  auto drug_pass = [&](const float* xa, const float* xb, const int* eia, const int* eib,
                       const int* bta, const int* btb, int npass, int pool_base) {
    const int nn = npass * N_NODES;
    const int te = npass * N_EDGES;
    const int nb = (nn + 1023) / 1024;
    const int rng = nn / 8;
    const int echunks = (te + ECHUNK - 1) / ECHUNK;
    hipMemsetAsync(cnt, 0, nn * sizeof(int), stream);
    histp_kernel<<<8 * echunks, 256, 0, stream>>>(eia, eib, cnt, N_EDGES, npass, rng);
    scan1_kernel<<<nb, 1024, 0, stream>>>(cnt, row_ptr, part, nn);
    scan23_kernel<<<(nn + 255) / 256, 256, 0, stream>>>(cnt, row_ptr, part, cursor, dinv,
                                                        nn, te, bta, btb, start1, start2);
    scatterp_kernel<<<8 * echunks, 256, 0, stream>>>(eia, eib, cursor, col_idx,
                                                     N_EDGES, npass, rng);
    {
      int tot = nn * 20;
      tobf16_kernel<<<(tot + 255) / 256, 256, 0, stream>>>(
          xa, xb, (npass == 2) ? N_NODES : nn, xb16s, tot);
    }
    // layer 1: agg -> ab16 ld96 -> MFMA 78->78 (Kpad 96) -> bf16 xb16s ld80
    {
      int tot = nn * 20;
      aggb_flat<<<(tot + 255) / 256, 256, 0, stream>>>(xb16s, row_ptr, col_idx, dinv,
                                                       ab16, 80, 96, 20, tot);
    }
    mfma(ab16, 96, wc1t, 96, xb16s, 80, bc1, nn, 96, 78, 1, 1);
    // layer 2: agg -> ab16 ld96 -> MFMA 78->156 -> bf16 xb16w ld160
    {
      int tot = nn * 20;
      aggb_flat<<<(tot + 255) / 256, 256, 0, stream>>>(xb16s, row_ptr, col_idx, dinv,
                                                       ab16, 80, 96, 20, tot);
    }
    mfma(ab16, 96, wc2t, 96, xb16w, 160, bc2, nn, 96, 156, 1, 1);
    // layer 3: agg -> ab16 ld160 -> MFMA 156->312 (Kpad 160) -> fp32 xbuf ld320
    {
      int tot = nn * 40;
      aggb_flat<<<(tot + 255) / 256, 256, 0, stream>>>(xb16w, row_ptr, col_idx, dinv,
                                                       ab16, 160, 160, 40, tot);
    }
    mfma(ab16, 160, wc3t, 160, xbuf, 320, bc3, nn, 160, 312, 1, 0);
    // two-stage pool
    {
      int totp = npass * N_GRAPH * POOL_NC * 78;
      pool_part_kernel<<<(totp + 255) / 256, 256, 0, stream>>>(xbuf, 320, start1, start2,
                                                               ppart, 78, totp);
      int totc = npass * N_GRAPH * 78;
      pool_combine_kernel<<<(totc + 255) / 256, 256, 0, stream>>>(ppart, pooled, 78, totc,
                                                                  pool_base);
    }
  };

  if (batched) {
    drug_pass(x1, x2, ei1, ei2, bt1, bt2, 2, 0);
  } else {
    drug_pass(x1, x1, ei1, ei1, bt1, bt1, 1, 0);
    drug_pass(x2, x2, ei2, ei2, bt2, bt2, 1, N_GRAPH);
  }

  // drug head (512 rows, shared weights); Wg2 -> bf16 catbuf halves (ld 512)
  splitk(pooled, 312, Wg1, 156, 312, 4, bg1, gtmp1, 156, 1, 2 * N_GRAPH, 0);
  splitk(gtmp1, 156, Wg2, 128, 156, 2, bg2, catbuf, 512, 0, N_GRAPH, 1);
  splitk(gtmp1 + (size_t)N_GRAPH * 156, 156, Wg2, 128, 156, 2, bg2, catbuf + 128, 512, 0,
         N_GRAPH, 1);

  // cell branch: rownorm -> bf16; Wr1/Wr2 via MFMA split-K; Wr3 fp32 -> bf16 catbuf
  rownorm_kernel<<<N_GRAPH, 256, 0, stream>>>(cell, cv16, 954, 960);
  mfma_splitk(cv16, 960, wr1t, 960, 2048, 960, 256, br1, gt1b, 2048, 1, 1);
  mfma_splitk(gt1b, 2048, wr2t, 2048, 512, 2048, 256, br2, gtmp2, 512, 1, 0);
  splitk(gtmp2, 512, Wr3, 256, 512, 16, br3, catbuf + 256, 512, 1, N_GRAPH, 1);
  // head: Wf1 via MFMA split-K on bf16 catbuf; Wf2/Wf3/Wo fp32
  mfma_splitk(catbuf, 512, wf1t, 512, 1024, 512, 128, bf1, gtmp1, 1024, 1, 0);
  splitk(gtmp1, 1024, Wf2, 512, 1024, 32, bf2, gtmp2, 512, 1, N_GRAPH, 0);
  splitk(gtmp2, 512, Wf3, 128, 512, 32, bf3, gtmp3, 128, 1, N_GRAPH, 0);
  gemm_small(gtmp3, 128, Wo, 2, out, 2, bo, N_GRAPH, 128, 2, 0);
}